// Round 2
// baseline (1555.446 us; speedup 1.0000x reference)
//
#include <hip/hip_runtime.h>
#include <hip/hip_bf16.h>
#include <math.h>

// ---------------------------------------------------------------------------
// SPNet: GCN(2x) -> masked edge attention -> encoder -> 3 MLP heads
// N=100000 nodes, E=1600000 edges, F=H=128.
// Round 1 (resubmit; round-1 bench died on infra): correctness-first fp32.
//   - CSR-by-dst built on device (count/scan/fill) -> gather-only aggregation
//   - generic tiled SGEMM (64x64 tile, 4x4 microtile) for all dense layers
//   - per-node wave kernels for GCN-aggregate (+e fused) and attention
// ---------------------------------------------------------------------------

static __device__ __forceinline__ float lrelu02(float x) { return x > 0.f ? x : 0.2f * x; }

__global__ void k_zero_i32(int* __restrict__ p, int n) {
    int i = blockIdx.x * blockDim.x + threadIdx.x;
    int stride = gridDim.x * blockDim.x;
    for (; i < n; i += stride) p[i] = 0;
}

__global__ void k_count(const int* __restrict__ dst, int* __restrict__ counts, int e) {
    int i = blockIdx.x * blockDim.x + threadIdx.x;
    int stride = gridDim.x * blockDim.x;
    for (; i < e; i += stride) atomicAdd(&counts[dst[i]], 1);
}

// Single-block scan over N counts -> indptr (exclusive), cursor copy, dinv=rsqrt(deg+1)
__global__ __launch_bounds__(1024) void k_scan(const int* __restrict__ counts,
                                               int* __restrict__ indptr,
                                               int* __restrict__ cursor,
                                               float* __restrict__ dinv, int n) {
    __shared__ int sums[1024];
    int t = threadIdx.x;
    int C = (n + 1023) >> 10;
    int lo = t * C, hi = lo + C;
    if (lo > n) lo = n;
    if (hi > n) hi = n;
    int s = 0;
    for (int i = lo; i < hi; ++i) s += counts[i];
    sums[t] = s;
    __syncthreads();
    for (int off = 1; off < 1024; off <<= 1) {
        int v = (t >= off) ? sums[t - off] : 0;
        __syncthreads();
        sums[t] += v;
        __syncthreads();
    }
    int base = sums[t] - s;  // exclusive prefix
    for (int i = lo; i < hi; ++i) {
        int c = counts[i];
        indptr[i] = base;
        cursor[i] = base;
        dinv[i] = rsqrtf((float)c + 1.0f);  // self-loop adds 1, deg >= 1
        base += c;
    }
    if (t == 1023) indptr[n] = sums[1023];
}

__global__ void k_fill(const int* __restrict__ src, const int* __restrict__ dst,
                       int* __restrict__ cursor, int* __restrict__ src_sorted, int e) {
    int i = blockIdx.x * blockDim.x + threadIdx.x;
    int stride = gridDim.x * blockDim.x;
    for (; i < e; i += stride) {
        int d = dst[i];
        int pos = atomicAdd(&cursor[d], 1);
        src_sorted[pos] = src[i];
    }
}

// Wcat[k][j] = j<128 ? W_o[k][j] : W_t[k][j-128]   (128 x 256)
__global__ void k_pack_wcat(const float* __restrict__ Wo, const float* __restrict__ Wt,
                            float* __restrict__ Wcat) {
    int i = blockIdx.x * blockDim.x + threadIdx.x;
    if (i >= 128 * 256) return;
    int k = i >> 8, j = i & 255;
    Wcat[i] = (j < 128) ? Wo[(k << 7) + j] : Wt[(k << 7) + j - 128];
}

// C[M,Ncols] = act(A[M,K] @ B[K,Ncols] + bias). act: 0 none, 1 relu, 2 lrelu(0.2)
// 64x64 tile, 256 threads, 4x4 microtile, K-chunk 16. K,Ncols multiples of 16/64.
__global__ __launch_bounds__(256) void k_gemm(const float* __restrict__ A,
                                              const float* __restrict__ B,
                                              const float* __restrict__ bias,
                                              float* __restrict__ C,
                                              int M, int K, int Ncols, int act) {
    __shared__ float As[16][64];  // transposed: As[k][m]
    __shared__ float Bs[16][64];
    int ntx = Ncols >> 6;
    int bx = blockIdx.x % ntx;
    int by = blockIdx.x / ntx;
    int row0 = by << 6, col0 = bx << 6;
    int tid = threadIdx.x;
    int tx = tid & 15, ty = tid >> 4;
    float acc[4][4] = {};
    for (int k0 = 0; k0 < K; k0 += 16) {
        {
            int r = tid >> 2, kq = tid & 3;
            int gr = row0 + r;
            float4 av = make_float4(0.f, 0.f, 0.f, 0.f);
            if (gr < M) av = *(const float4*)(A + (size_t)gr * K + k0 + (kq << 2));
            As[(kq << 2) + 0][r] = av.x;
            As[(kq << 2) + 1][r] = av.y;
            As[(kq << 2) + 2][r] = av.z;
            As[(kq << 2) + 3][r] = av.w;
        }
        {
            int kk = tid >> 4, nq = tid & 15;
            *(float4*)&Bs[kk][nq << 2] =
                *(const float4*)(B + (size_t)(k0 + kk) * Ncols + col0 + (nq << 2));
        }
        __syncthreads();
#pragma unroll
        for (int k = 0; k < 16; ++k) {
            float4 a = *(const float4*)&As[k][ty << 2];
            float4 b = *(const float4*)&Bs[k][tx << 2];
            acc[0][0] += a.x * b.x; acc[0][1] += a.x * b.y; acc[0][2] += a.x * b.z; acc[0][3] += a.x * b.w;
            acc[1][0] += a.y * b.x; acc[1][1] += a.y * b.y; acc[1][2] += a.y * b.z; acc[1][3] += a.y * b.w;
            acc[2][0] += a.z * b.x; acc[2][1] += a.z * b.y; acc[2][2] += a.z * b.z; acc[2][3] += a.z * b.w;
            acc[3][0] += a.w * b.x; acc[3][1] += a.w * b.y; acc[3][2] += a.w * b.z; acc[3][3] += a.w * b.w;
        }
        __syncthreads();
    }
    float4 bv = make_float4(0.f, 0.f, 0.f, 0.f);
    if (bias) bv = *(const float4*)(bias + col0 + (tx << 2));
#pragma unroll
    for (int i = 0; i < 4; ++i) {
        int gr = row0 + (ty << 2) + i;
        if (gr >= M) break;
        float4 o;
        o.x = acc[i][0] + bv.x; o.y = acc[i][1] + bv.y;
        o.z = acc[i][2] + bv.z; o.w = acc[i][3] + bv.w;
        if (act == 1) {
            o.x = fmaxf(o.x, 0.f); o.y = fmaxf(o.y, 0.f);
            o.z = fmaxf(o.z, 0.f); o.w = fmaxf(o.w, 0.f);
        } else if (act == 2) {
            o.x = lrelu02(o.x); o.y = lrelu02(o.y);
            o.z = lrelu02(o.z); o.w = lrelu02(o.w);
        }
        *(float4*)(C + (size_t)gr * Ncols + col0 + (tx << 2)) = o;
    }
}

// GCN aggregation for both convs at once. One wave per node; lane owns 4 of 256 cols.
// Writes r_o -> cat2[:,0:128], r_t -> rt, and e[v] = cat . a_w + a_b (fused).
__global__ __launch_bounds__(256) void k_agg(const float* __restrict__ xw,
                                             const int* __restrict__ indptr,
                                             const int* __restrict__ srcs,
                                             const float* __restrict__ dinv,
                                             const float* __restrict__ b_o,
                                             const float* __restrict__ b_t,
                                             const float* __restrict__ a_w,
                                             const float* __restrict__ a_b,
                                             float* __restrict__ cat2,
                                             float* __restrict__ rt,
                                             float* __restrict__ e, int n) {
    int wv = threadIdx.x >> 6, lane = threadIdx.x & 63;
    int v = blockIdx.x * 4 + wv;
    if (v >= n) return;
    const float4* xw4 = (const float4*)xw;
    float dv = dinv[v];
    float4 acc = make_float4(0.f, 0.f, 0.f, 0.f);
    int beg = indptr[v], end = indptr[v + 1];
    for (int i = beg; i < end; ++i) {
        int s = srcs[i];
        float nr = dinv[s] * dv;
        float4 val = xw4[(size_t)s * 64 + lane];
        acc.x += nr * val.x; acc.y += nr * val.y;
        acc.z += nr * val.z; acc.w += nr * val.w;
    }
    {  // self loop: norm = dinv[v]^2
        float4 sv = xw4[(size_t)v * 64 + lane];
        float d2 = dv * dv;
        acc.x += d2 * sv.x; acc.y += d2 * sv.y;
        acc.z += d2 * sv.z; acc.w += d2 * sv.w;
    }
    int col = lane << 2;  // 0..252
    const float* bb = (col < 128) ? (b_o + col) : (b_t + col - 128);
    acc.x = fmaxf(acc.x + bb[0], 0.f);
    acc.y = fmaxf(acc.y + bb[1], 0.f);
    acc.z = fmaxf(acc.z + bb[2], 0.f);
    acc.w = fmaxf(acc.w + bb[3], 0.f);
    if (col < 128)
        *(float4*)(cat2 + (size_t)v * 256 + col) = acc;
    else
        *(float4*)(rt + (size_t)v * 128 + col - 128) = acc;
    // e[v] = [r_o|r_t] . a_w + a_b
    float4 aw = *(const float4*)(a_w + col);
    float s = acc.x * aw.x + acc.y * aw.y + acc.z * aw.z + acc.w * aw.w;
    for (int off = 32; off; off >>= 1) s += __shfl_down(s, off);
    if (lane == 0) e[v] = s + a_b[0];
}

// Masked attention + h. One wave per node; lane owns 2 of 128 cols of h.
// h[v] = (sum_e w_e * r_t[src_e]) / (sum_e w_e + 1e-16); written to cat2[:,128:256].
__global__ __launch_bounds__(256) void k_attn(const float* __restrict__ rt,
                                              const int* __restrict__ indptr,
                                              const int* __restrict__ srcs,
                                              const float* __restrict__ e,
                                              const int* __restrict__ t,
                                              float* __restrict__ cat2, int n) {
    int wv = threadIdx.x >> 6, lane = threadIdx.x & 63;
    int v = blockIdx.x * 4 + wv;
    if (v >= n) return;
    int beg = indptr[v], end = indptr[v + 1];
    float ev = e[v];
    // pass 1: unmasked segment max of leaky_relu(e[s]+e[v])
    float m = -INFINITY;
    for (int i = beg + lane; i < end; i += 64) {
        float lg = lrelu02(ev + e[srcs[i]]);
        m = fmaxf(m, lg);
    }
    for (int off = 32; off; off >>= 1) m = fmaxf(m, __shfl_xor(m, off));
    if (beg == end) m = 0.f;  // isfinite(m) ? m : 0
    // pass 2: masked exp-weights; accumulate w-sum and weighted r_t rows
    float2 acc = make_float2(0.f, 0.f);
    float wsum = 0.f;
    const float2* rt2 = (const float2*)rt;
    for (int i = beg; i < end; ++i) {
        int s = srcs[i];
        if (t[s] > 0) {
            float lg = lrelu02(ev + e[s]);
            float wgt = __expf(lg - m);
            wsum += wgt;
            float2 rv = rt2[(size_t)s * 64 + lane];
            acc.x += wgt * rv.x;
            acc.y += wgt * rv.y;
        }
    }
    float inv = 1.f / (wsum + 1e-16f);
    *(float2*)(cat2 + (size_t)v * 256 + 128 + (lane << 1)) = make_float2(acc.x * inv, acc.y * inv);
}

// out[row] = A[row,:128] . w + b   (one wave per row)
__global__ __launch_bounds__(256) void k_gemv(const float* __restrict__ A,
                                              const float* __restrict__ w,
                                              const float* __restrict__ b,
                                              float* __restrict__ out, int M) {
    int gid = blockIdx.x * blockDim.x + threadIdx.x;
    int row = gid >> 6, lane = gid & 63;
    if (row >= M) return;
    float2 a = *(const float2*)(A + (size_t)row * 128 + (lane << 1));
    float2 ww = *(const float2*)(w + (lane << 1));
    float s = a.x * ww.x + a.y * ww.y;
    for (int off = 32; off; off >>= 1) s += __shfl_down(s, off);
    if (lane == 0) out[row] = s + b[0];
}

__global__ void k_final(const float* __restrict__ s1, const float* __restrict__ s0,
                        const float* __restrict__ sd, const int* __restrict__ t,
                        float* __restrict__ out, int n) {
    int i = blockIdx.x * blockDim.x + threadIdx.x;
    if (i >= n) return;
    out[i] = 1.f / (1.f + __expf(-sd[i]));        // pred_t
    out[n + i] = (t[i] > 0) ? s1[i] : s0[i];      // pred
}

extern "C" void kernel_launch(void* const* d_in, const int* in_sizes, int n_in,
                              void* d_out, int out_size, void* d_ws, size_t ws_size,
                              hipStream_t stream) {
    const float* x     = (const float*)d_in[0];
    const int*   t     = (const int*)d_in[1];
    // d_in[2] (z) is unused by the reference
    const int*   ei    = (const int*)d_in[3];
    const float* W_o   = (const float*)d_in[4];
    const float* b_o   = (const float*)d_in[5];
    const float* W_t   = (const float*)d_in[6];
    const float* b_t   = (const float*)d_in[7];
    const float* a_w   = (const float*)d_in[8];
    const float* a_b   = (const float*)d_in[9];
    const float* W_enc = (const float*)d_in[10];
    const float* b_enc = (const float*)d_in[11];
    const float* p1_W1 = (const float*)d_in[12]; const float* p1_b1 = (const float*)d_in[13];
    const float* p1_W2 = (const float*)d_in[14]; const float* p1_b2 = (const float*)d_in[15];
    const float* p1_W3 = (const float*)d_in[16]; const float* p1_b3 = (const float*)d_in[17];
    const float* p0_W1 = (const float*)d_in[18]; const float* p0_b1 = (const float*)d_in[19];
    const float* p0_W2 = (const float*)d_in[20]; const float* p0_b2 = (const float*)d_in[21];
    const float* p0_W3 = (const float*)d_in[22]; const float* p0_b3 = (const float*)d_in[23];
    const float* d_W1  = (const float*)d_in[24]; const float* d_b1  = (const float*)d_in[25];
    const float* d_W2  = (const float*)d_in[26]; const float* d_b2  = (const float*)d_in[27];
    const float* d_W3  = (const float*)d_in[28]; const float* d_b3  = (const float*)d_in[29];

    const int n = in_sizes[1];
    const int E = in_sizes[3] / 2;
    const int* src = ei;
    const int* dst = ei + E;

    float* out    = (float*)d_out;
    float* zenc   = out + 2 * (size_t)n;  // output order: pred_t[N], pred[N], z_enc[N,128]

    // ---- workspace layout (floats) ----
    float* ws = (float*)d_ws;
    size_t o = 0;
    float* xw   = ws + o; o += (size_t)n * 256;   // x @ [W_o|W_t]
    float* cat2 = ws + o; o += (size_t)n * 256;   // [r_o | h]
    float* rt   = ws + o; o += (size_t)n * 128;   // r_t
    float* dinv = ws + o; o += n;
    float* evec = ws + o; o += n;
    float* s1   = ws + o; o += n;
    float* s0   = ws + o; o += n;
    float* sd   = ws + o; o += n;
    float* Wcat = ws + o; o += 128 * 256;
    int* counts     = (int*)(ws + o); o += n;
    int* indptr     = (int*)(ws + o); o += (size_t)n + 1;
    int* cursor     = (int*)(ws + o); o += n;
    int* src_sorted = (int*)(ws + o); o += E;
    // xw region is dead after k_agg: reuse for head hidden buffers
    float* h1 = xw;
    float* h2 = xw + (size_t)n * 128;

    const int egrid = (E + 255) / 256 > 2048 ? 2048 : (E + 255) / 256;
    const int mt = (n + 63) / 64;  // GEMM row tiles

    // CSR build
    k_zero_i32<<<256, 256, 0, stream>>>(counts, n);
    k_count<<<egrid, 256, 0, stream>>>(dst, counts, E);
    k_scan<<<1, 1024, 0, stream>>>(counts, indptr, cursor, dinv, n);
    k_fill<<<egrid, 256, 0, stream>>>(src, dst, cursor, src_sorted, E);

    // xw = x @ [W_o | W_t]
    k_pack_wcat<<<128, 256, 0, stream>>>(W_o, W_t, Wcat);
    k_gemm<<<mt * 4, 256, 0, stream>>>(x, Wcat, nullptr, xw, n, 128, 256, 0);

    // GCN aggregate (both convs) + relu + bias + e
    k_agg<<<(n + 3) / 4, 256, 0, stream>>>(xw, indptr, src_sorted, dinv, b_o, b_t,
                                           a_w, a_b, cat2, rt, evec, n);
    // attention -> h (into cat2[:,128:256])
    k_attn<<<(n + 3) / 4, 256, 0, stream>>>(rt, indptr, src_sorted, evec, t, cat2, n);

    // z_enc = cat2 @ W_enc + b_enc  (written straight to output)
    k_gemm<<<mt * 2, 256, 0, stream>>>(cat2, W_enc, b_enc, zenc, n, 256, 128, 0);

    // predictor head t=1
    k_gemm<<<mt * 2, 256, 0, stream>>>(zenc, p1_W1, p1_b1, h1, n, 128, 128, 2);
    k_gemm<<<mt * 2, 256, 0, stream>>>(h1, p1_W2, p1_b2, h2, n, 128, 128, 2);
    k_gemv<<<(n + 3) / 4, 256, 0, stream>>>(h2, p1_W3, p1_b3, s1, n);
    // predictor head t=0
    k_gemm<<<mt * 2, 256, 0, stream>>>(zenc, p0_W1, p0_b1, h1, n, 128, 128, 2);
    k_gemm<<<mt * 2, 256, 0, stream>>>(h1, p0_W2, p0_b2, h2, n, 128, 128, 2);
    k_gemv<<<(n + 3) / 4, 256, 0, stream>>>(h2, p0_W3, p0_b3, s0, n);
    // discriminator on r_t
    k_gemm<<<mt * 2, 256, 0, stream>>>(rt, d_W1, d_b1, h1, n, 128, 128, 2);
    k_gemm<<<mt * 2, 256, 0, stream>>>(h1, d_W2, d_b2, h2, n, 128, 128, 2);
    k_gemv<<<(n + 3) / 4, 256, 0, stream>>>(h2, d_W3, d_b3, sd, n);

    k_final<<<(n + 255) / 256, 256, 0, stream>>>(s1, s0, sd, t, out, n);
}

// Round 3
// 1095.784 us; speedup vs baseline: 1.4195x; 1.4195x over previous
//
#include <hip/hip_runtime.h>
#include <hip/hip_bf16.h>
#include <math.h>

// ---------------------------------------------------------------------------
// SPNet: GCN(2x) -> masked edge attention -> encoder -> 3 MLP heads
// N=100000, E=1600000, F=H=128.
// Round 3:
//   - parallel 3-kernel CSR scan (was: 278us single-block scan = top dispatch)
//   - all dense layers on bf16 MFMA (16x16x32), weights pre-transposed bf16
//   - all activations bf16 -> gather traffic halved in k_agg / k_attn
// ---------------------------------------------------------------------------

using bf16x8 = __attribute__((ext_vector_type(8))) short;
using f32x4  = __attribute__((ext_vector_type(4))) float;

static __device__ __forceinline__ float lrelu02(float x) { return x > 0.f ? x : 0.2f * x; }

static __device__ __forceinline__ unsigned short f2bf(float f) {
    unsigned u = __float_as_uint(f);
    unsigned r = u + 0x7FFF + ((u >> 16) & 1);   // round-to-nearest-even
    return (unsigned short)(r >> 16);
}
static __device__ __forceinline__ float bf2f(unsigned short h) {
    return __uint_as_float(((unsigned)h) << 16);
}

// ---------------- CSR build ----------------

__global__ void k_zero_i32(int* __restrict__ p, int n) {
    int i = blockIdx.x * blockDim.x + threadIdx.x;
    int stride = gridDim.x * blockDim.x;
    for (; i < n; i += stride) p[i] = 0;
}

__global__ void k_count(const int* __restrict__ dst, int* __restrict__ counts, int e) {
    int i = blockIdx.x * blockDim.x + threadIdx.x;
    int stride = gridDim.x * blockDim.x;
    for (; i < e; i += stride) atomicAdd(&counts[dst[i]], 1);
}

// per-block (1024-element chunk) sum of counts
__global__ __launch_bounds__(256) void k_part(const int* __restrict__ counts,
                                              int* __restrict__ bsum, int n) {
    __shared__ int red[256];
    int b = blockIdx.x, t = threadIdx.x;
    int base = b * 1024 + t * 4;
    int s = 0;
#pragma unroll
    for (int j = 0; j < 4; ++j) {
        int i = base + j;
        if (i < n) s += counts[i];
    }
    red[t] = s;
    __syncthreads();
    for (int off = 128; off; off >>= 1) {
        if (t < off) red[t] += red[t + off];
        __syncthreads();
    }
    if (t == 0) bsum[b] = red[0];
}

// exclusive scan of <=256 block sums (single small block)
__global__ __launch_bounds__(256) void k_scanb(const int* __restrict__ bsum,
                                               int* __restrict__ boff, int nb) {
    __shared__ int s[256];
    int t = threadIdx.x;
    int v = (t < nb) ? bsum[t] : 0;
    s[t] = v;
    __syncthreads();
    for (int off = 1; off < 256; off <<= 1) {
        int u = (t >= off) ? s[t - off] : 0;
        __syncthreads();
        s[t] += u;
        __syncthreads();
    }
    if (t < nb) boff[t] = s[t] - v;
}

// per-block local exclusive scan + global base -> indptr/cursor/dinv
__global__ __launch_bounds__(256) void k_csr(const int* __restrict__ counts,
                                             const int* __restrict__ boff,
                                             int* __restrict__ indptr,
                                             int* __restrict__ cursor,
                                             float* __restrict__ dinv, int n) {
    __shared__ int tsum[256];
    int b = blockIdx.x, t = threadIdx.x;
    int base = b * 1024 + t * 4;
    int c[4];
    int s = 0;
#pragma unroll
    for (int j = 0; j < 4; ++j) {
        int i = base + j;
        c[j] = (i < n) ? counts[i] : 0;
        s += c[j];
    }
    tsum[t] = s;
    __syncthreads();
    for (int off = 1; off < 256; off <<= 1) {
        int u = (t >= off) ? tsum[t - off] : 0;
        __syncthreads();
        tsum[t] += u;
        __syncthreads();
    }
    int pre = boff[b] + tsum[t] - s;
#pragma unroll
    for (int j = 0; j < 4; ++j) {
        int i = base + j;
        if (i < n) {
            indptr[i] = pre;
            cursor[i] = pre;
            dinv[i] = rsqrtf((float)c[j] + 1.0f);  // self-loop adds 1
            pre += c[j];
            if (i == n - 1) indptr[n] = pre;
        }
    }
}

__global__ void k_fill(const int* __restrict__ src, const int* __restrict__ dst,
                       int* __restrict__ cursor, int* __restrict__ src_sorted, int e) {
    int i = blockIdx.x * blockDim.x + threadIdx.x;
    int stride = gridDim.x * blockDim.x;
    for (; i < e; i += stride) {
        int d = dst[i];
        int pos = atomicAdd(&cursor[d], 1);
        src_sorted[pos] = src[i];
    }
}

// ---------------- weight / input prep (fp32 -> bf16) ----------------

// x fp32 -> bf16, vectorized (n4 = elements/4)
__global__ void k_cvt(const float* __restrict__ in, unsigned short* __restrict__ out, int n4) {
    int i = blockIdx.x * blockDim.x + threadIdx.x;
    int stride = gridDim.x * blockDim.x;
    for (; i < n4; i += stride) {
        float4 v = ((const float4*)in)[i];
        ushort4 o;
        o.x = f2bf(v.x); o.y = f2bf(v.y); o.z = f2bf(v.z); o.w = f2bf(v.w);
        ((ushort4*)out)[i] = o;
    }
}

// generic transpose+convert: W[K][Nc] fp32 -> Wt[Nc][K] bf16
__global__ void k_wt(const float* __restrict__ W, unsigned short* __restrict__ Wt,
                     int K, int Nc) {
    int i = blockIdx.x * blockDim.x + threadIdx.x;
    if (i >= K * Nc) return;
    int k = i / Nc, j = i % Nc;
    Wt[(size_t)j * K + k] = f2bf(W[i]);
}

// Wcat_t[j][k] = j<128 ? W_o[k][j] : W_t[k][j-128]   ([256][128] bf16)
__global__ void k_wcat_t(const float* __restrict__ Wo, const float* __restrict__ Wt_in,
                         unsigned short* __restrict__ Wt) {
    int i = blockIdx.x * blockDim.x + threadIdx.x;
    if (i >= 256 * 128) return;
    int j = i >> 7, k = i & 127;
    float v = (j < 128) ? Wo[(k << 7) + j] : Wt_in[(k << 7) + j - 128];
    Wt[i] = f2bf(v);
}

// ---------------- bf16 MFMA GEMM ----------------
// C[M,Ncols] = act(A[M,K] @ B + bias), B given TRANSPOSED: Wt[Ncols][K] bf16.
// Block: 256 thr = 4 waves; tile 64 rows x 128 cols; wave w owns rows [w*16,+16).
// No LDS: A frags 16B/lane from global; B frags 16B/lane (L1/L2-resident weights).
// act: 0 none, 2 lrelu(0.2). Writes outb (bf16) and/or outf (fp32).
__global__ __launch_bounds__(256) void k_bgemm(const unsigned short* __restrict__ A,
                                               const unsigned short* __restrict__ Wt,
                                               const float* __restrict__ bias,
                                               unsigned short* __restrict__ outb,
                                               float* __restrict__ outf,
                                               int M, int K, int Ncols, int act) {
    int nct = Ncols >> 7;                  // 128-col tiles
    int mtile = blockIdx.x / nct;
    int col0 = (blockIdx.x % nct) << 7;
    int wave = threadIdx.x >> 6, lane = threadIdx.x & 63;
    int row_base = mtile * 64 + wave * 16;

    int rA = row_base + (lane & 15);
    if (rA >= M) rA = M - 1;               // clamp; stores are guarded
    const short* Ap = (const short*)A + (size_t)rA * K + ((lane >> 4) << 3);
    const short* Bp = (const short*)Wt + (size_t)(col0 + (lane & 15)) * K + ((lane >> 4) << 3);

    f32x4 acc[8];
#pragma unroll
    for (int cf = 0; cf < 8; ++cf) acc[cf] = (f32x4){0.f, 0.f, 0.f, 0.f};

    int nks = K >> 5;
    for (int ks = 0; ks < nks; ++ks) {
        bf16x8 a = *(const bf16x8*)(Ap + (ks << 5));
#pragma unroll
        for (int cf = 0; cf < 8; ++cf) {
            bf16x8 b = *(const bf16x8*)(Bp + (size_t)(cf << 4) * K + (ks << 5));
            acc[cf] = __builtin_amdgcn_mfma_f32_16x16x32_bf16(a, b, acc[cf], 0, 0, 0);
        }
    }

#pragma unroll
    for (int cf = 0; cf < 8; ++cf) {
        int col = col0 + (cf << 4) + (lane & 15);
        float bv = bias ? bias[col] : 0.f;
#pragma unroll
        for (int j = 0; j < 4; ++j) {
            int row = row_base + ((lane >> 4) << 2) + j;
            if (row >= M) continue;
            float v = acc[cf][j] + bv;
            if (act == 2) v = lrelu02(v);
            if (outb) outb[(size_t)row * Ncols + col] = f2bf(v);
            if (outf) outf[(size_t)row * Ncols + col] = v;
        }
    }
}

// ---------------- graph kernels (bf16 tables) ----------------

// GCN aggregation for both convs. One wave per node; lane owns 4 of 256 cols.
// xw bf16 [N][256]. Writes cat2[:,0:128] (r_o), rt (r_t), e[v] (fp32) fused.
__global__ __launch_bounds__(256) void k_agg(const unsigned short* __restrict__ xw,
                                             const int* __restrict__ indptr,
                                             const int* __restrict__ srcs,
                                             const float* __restrict__ dinv,
                                             const float* __restrict__ b_o,
                                             const float* __restrict__ b_t,
                                             const float* __restrict__ a_w,
                                             const float* __restrict__ a_b,
                                             unsigned short* __restrict__ cat2,
                                             unsigned short* __restrict__ rt,
                                             float* __restrict__ e, int n) {
    int wv = threadIdx.x >> 6, lane = threadIdx.x & 63;
    int v = blockIdx.x * 4 + wv;
    if (v >= n) return;
    const ushort4* xw4 = (const ushort4*)xw;   // 4 bf16 cols per lane
    float dv = dinv[v];
    float a0 = 0.f, a1 = 0.f, a2 = 0.f, a3 = 0.f;
    int beg = indptr[v], end = indptr[v + 1];
    for (int i = beg; i < end; ++i) {
        int s = srcs[i];
        float nr = dinv[s] * dv;
        ushort4 val = xw4[(size_t)s * 64 + lane];
        a0 += nr * bf2f(val.x); a1 += nr * bf2f(val.y);
        a2 += nr * bf2f(val.z); a3 += nr * bf2f(val.w);
    }
    {  // self loop: norm = dinv[v]^2
        ushort4 sv = xw4[(size_t)v * 64 + lane];
        float d2 = dv * dv;
        a0 += d2 * bf2f(sv.x); a1 += d2 * bf2f(sv.y);
        a2 += d2 * bf2f(sv.z); a3 += d2 * bf2f(sv.w);
    }
    int col = lane << 2;  // 0..252
    const float* bb = (col < 128) ? (b_o + col) : (b_t + col - 128);
    a0 = fmaxf(a0 + bb[0], 0.f);
    a1 = fmaxf(a1 + bb[1], 0.f);
    a2 = fmaxf(a2 + bb[2], 0.f);
    a3 = fmaxf(a3 + bb[3], 0.f);
    ushort4 o;
    o.x = f2bf(a0); o.y = f2bf(a1); o.z = f2bf(a2); o.w = f2bf(a3);
    if (col < 128)
        ((ushort4*)(cat2 + (size_t)v * 256))[lane] = o;
    else
        ((ushort4*)(rt + (size_t)v * 128))[lane - 32] = o;
    // e[v] = [r_o|r_t] . a_w + a_b  (fp32)
    float4 aw = *(const float4*)(a_w + col);
    float s = a0 * aw.x + a1 * aw.y + a2 * aw.z + a3 * aw.w;
    for (int off = 32; off; off >>= 1) s += __shfl_down(s, off);
    if (lane == 0) e[v] = s + a_b[0];
}

// Masked attention + h. One wave per node; lane owns 2 of 128 cols.
// rt bf16; h written to cat2[:,128:256] bf16.
__global__ __launch_bounds__(256) void k_attn(const unsigned short* __restrict__ rt,
                                              const int* __restrict__ indptr,
                                              const int* __restrict__ srcs,
                                              const float* __restrict__ e,
                                              const int* __restrict__ t,
                                              unsigned short* __restrict__ cat2, int n) {
    int wv = threadIdx.x >> 6, lane = threadIdx.x & 63;
    int v = blockIdx.x * 4 + wv;
    if (v >= n) return;
    int beg = indptr[v], end = indptr[v + 1];
    float ev = e[v];
    // pass 1: unmasked segment max of leaky_relu(e[s]+e[v])
    float m = -INFINITY;
    for (int i = beg + lane; i < end; i += 64) {
        float lg = lrelu02(ev + e[srcs[i]]);
        m = fmaxf(m, lg);
    }
    for (int off = 32; off; off >>= 1) m = fmaxf(m, __shfl_xor(m, off));
    if (beg == end) m = 0.f;  // isfinite(m) ? m : 0
    // pass 2: masked exp-weights; accumulate w-sum and weighted r_t rows
    float h0 = 0.f, h1 = 0.f, wsum = 0.f;
    const unsigned* rt2 = (const unsigned*)rt;   // 2 bf16 per lane
    for (int i = beg; i < end; ++i) {
        int s = srcs[i];
        if (t[s] > 0) {
            float lg = lrelu02(ev + e[s]);
            float wgt = __expf(lg - m);
            wsum += wgt;
            unsigned u = rt2[(size_t)s * 64 + lane];
            h0 += wgt * bf2f((unsigned short)(u & 0xFFFF));
            h1 += wgt * bf2f((unsigned short)(u >> 16));
        }
    }
    float inv = 1.f / (wsum + 1e-16f);
    unsigned o = (unsigned)f2bf(h0 * inv) | ((unsigned)f2bf(h1 * inv) << 16);
    ((unsigned*)(cat2 + (size_t)v * 256 + 128))[lane] = o;
}

// out[row] = A[row,:128] . w + b, A bf16 (one wave per row)
__global__ __launch_bounds__(256) void k_gemv(const unsigned short* __restrict__ A,
                                              const float* __restrict__ w,
                                              const float* __restrict__ b,
                                              float* __restrict__ out, int M) {
    int gid = blockIdx.x * blockDim.x + threadIdx.x;
    int row = gid >> 6, lane = gid & 63;
    if (row >= M) return;
    unsigned u = ((const unsigned*)A)[(size_t)row * 64 + lane];
    float2 ww = *(const float2*)(w + (lane << 1));
    float s = bf2f((unsigned short)(u & 0xFFFF)) * ww.x + bf2f((unsigned short)(u >> 16)) * ww.y;
    for (int off = 32; off; off >>= 1) s += __shfl_down(s, off);
    if (lane == 0) out[row] = s + b[0];
}

__global__ void k_final(const float* __restrict__ s1, const float* __restrict__ s0,
                        const float* __restrict__ sd, const int* __restrict__ t,
                        float* __restrict__ out, int n) {
    int i = blockIdx.x * blockDim.x + threadIdx.x;
    if (i >= n) return;
    out[i] = 1.f / (1.f + __expf(-sd[i]));        // pred_t
    out[n + i] = (t[i] > 0) ? s1[i] : s0[i];      // pred
}

// ---------------- launcher ----------------

extern "C" void kernel_launch(void* const* d_in, const int* in_sizes, int n_in,
                              void* d_out, int out_size, void* d_ws, size_t ws_size,
                              hipStream_t stream) {
    const float* x     = (const float*)d_in[0];
    const int*   t     = (const int*)d_in[1];
    const int*   ei    = (const int*)d_in[3];
    const float* W_o   = (const float*)d_in[4];
    const float* b_o   = (const float*)d_in[5];
    const float* W_t   = (const float*)d_in[6];
    const float* b_t   = (const float*)d_in[7];
    const float* a_w   = (const float*)d_in[8];
    const float* a_b   = (const float*)d_in[9];
    const float* W_enc = (const float*)d_in[10];
    const float* b_enc = (const float*)d_in[11];
    const float* p1_W1 = (const float*)d_in[12]; const float* p1_b1 = (const float*)d_in[13];
    const float* p1_W2 = (const float*)d_in[14]; const float* p1_b2 = (const float*)d_in[15];
    const float* p1_W3 = (const float*)d_in[16]; const float* p1_b3 = (const float*)d_in[17];
    const float* p0_W1 = (const float*)d_in[18]; const float* p0_b1 = (const float*)d_in[19];
    const float* p0_W2 = (const float*)d_in[20]; const float* p0_b2 = (const float*)d_in[21];
    const float* p0_W3 = (const float*)d_in[22]; const float* p0_b3 = (const float*)d_in[23];
    const float* d_W1  = (const float*)d_in[24]; const float* d_b1  = (const float*)d_in[25];
    const float* d_W2  = (const float*)d_in[26]; const float* d_b2  = (const float*)d_in[27];
    const float* d_W3  = (const float*)d_in[28]; const float* d_b3  = (const float*)d_in[29];

    const int n = in_sizes[1];
    const int E = in_sizes[3] / 2;
    const int* src = ei;
    const int* dst = ei + E;

    float* out  = (float*)d_out;
    float* zenc = out + 2 * (size_t)n;   // output: pred_t[N], pred[N], z_enc[N,128]

    // ---- workspace layout (bytes, 256-aligned regions) ----
    char* base = (char*)d_ws;
    size_t o = 0;
    auto alloc = [&](size_t bytes) { char* p = base + o; o += (bytes + 255) & ~(size_t)255; return p; };
    unsigned short* x_bf    = (unsigned short*)alloc((size_t)n * 128 * 2);
    unsigned short* xw_bf   = (unsigned short*)alloc((size_t)n * 256 * 2);
    unsigned short* cat2_bf = (unsigned short*)alloc((size_t)n * 256 * 2);
    unsigned short* rt_bf   = (unsigned short*)alloc((size_t)n * 128 * 2);
    unsigned short* zenc_bf = (unsigned short*)alloc((size_t)n * 128 * 2);
    float* dinv = (float*)alloc((size_t)n * 4);
    float* evec = (float*)alloc((size_t)n * 4);
    float* s1   = (float*)alloc((size_t)n * 4);
    float* s0   = (float*)alloc((size_t)n * 4);
    float* sd   = (float*)alloc((size_t)n * 4);
    unsigned short* Wcat_t = (unsigned short*)alloc(256 * 128 * 2);
    unsigned short* Wenc_t = (unsigned short*)alloc(128 * 256 * 2);
    unsigned short* Wp1a_t = (unsigned short*)alloc(128 * 128 * 2);
    unsigned short* Wp1b_t = (unsigned short*)alloc(128 * 128 * 2);
    unsigned short* Wp0a_t = (unsigned short*)alloc(128 * 128 * 2);
    unsigned short* Wp0b_t = (unsigned short*)alloc(128 * 128 * 2);
    unsigned short* Wda_t  = (unsigned short*)alloc(128 * 128 * 2);
    unsigned short* Wdb_t  = (unsigned short*)alloc(128 * 128 * 2);
    int* counts     = (int*)alloc((size_t)n * 4);
    int* indptr     = (int*)alloc(((size_t)n + 1) * 4);
    int* cursor     = (int*)alloc((size_t)n * 4);
    int* bsum       = (int*)alloc(256 * 4);
    int* boff       = (int*)alloc(256 * 4);
    int* src_sorted = (int*)alloc((size_t)E * 4);
    // xw dead after k_agg -> reuse for head hidden buffers (bf16)
    unsigned short* h1 = xw_bf;
    unsigned short* h2 = xw_bf + (size_t)n * 128;

    const int egrid = (E + 255) / 256 > 2048 ? 2048 : (E + 255) / 256;
    const int nb = (n + 1023) / 1024;          // scan chunks (<=256)
    const int mt = (n + 63) / 64;              // GEMM row tiles

    // CSR build (parallel scan)
    k_zero_i32<<<256, 256, 0, stream>>>(counts, n);
    k_count<<<egrid, 256, 0, stream>>>(dst, counts, E);
    k_part<<<nb, 256, 0, stream>>>(counts, bsum, n);
    k_scanb<<<1, 256, 0, stream>>>(bsum, boff, nb);
    k_csr<<<nb, 256, 0, stream>>>(counts, boff, indptr, cursor, dinv, n);
    k_fill<<<egrid, 256, 0, stream>>>(src, dst, cursor, src_sorted, E);

    // prep: x -> bf16; weights -> transposed bf16
    k_cvt<<<2048, 256, 0, stream>>>(x, x_bf, n * 32);
    k_wcat_t<<<128, 256, 0, stream>>>(W_o, W_t, Wcat_t);
    k_wt<<<128, 256, 0, stream>>>(W_enc, Wenc_t, 256, 128);
    k_wt<<<64, 256, 0, stream>>>(p1_W1, Wp1a_t, 128, 128);
    k_wt<<<64, 256, 0, stream>>>(p1_W2, Wp1b_t, 128, 128);
    k_wt<<<64, 256, 0, stream>>>(p0_W1, Wp0a_t, 128, 128);
    k_wt<<<64, 256, 0, stream>>>(p0_W2, Wp0b_t, 128, 128);
    k_wt<<<64, 256, 0, stream>>>(d_W1, Wda_t, 128, 128);
    k_wt<<<64, 256, 0, stream>>>(d_W2, Wdb_t, 128, 128);

    // xw = x @ [W_o | W_t]  (bf16 out)
    k_bgemm<<<mt * 2, 256, 0, stream>>>(x_bf, Wcat_t, nullptr, xw_bf, nullptr, n, 128, 256, 0);

    // GCN aggregate (both convs) + relu + bias + e
    k_agg<<<(n + 3) / 4, 256, 0, stream>>>(xw_bf, indptr, src_sorted, dinv, b_o, b_t,
                                           a_w, a_b, cat2_bf, rt_bf, evec, n);
    // attention -> h (into cat2[:,128:256])
    k_attn<<<(n + 3) / 4, 256, 0, stream>>>(rt_bf, indptr, src_sorted, evec, t, cat2_bf, n);

    // z_enc = cat2 @ W_enc + b_enc  (fp32 to d_out, bf16 for heads)
    k_bgemm<<<mt, 256, 0, stream>>>(cat2_bf, Wenc_t, b_enc, zenc_bf, zenc, n, 256, 128, 0);

    // predictor head t=1
    k_bgemm<<<mt, 256, 0, stream>>>(zenc_bf, Wp1a_t, p1_b1, h1, nullptr, n, 128, 128, 2);
    k_bgemm<<<mt, 256, 0, stream>>>(h1, Wp1b_t, p1_b2, h2, nullptr, n, 128, 128, 2);
    k_gemv<<<(n + 3) / 4, 256, 0, stream>>>(h2, p1_W3, p1_b3, s1, n);
    // predictor head t=0
    k_bgemm<<<mt, 256, 0, stream>>>(zenc_bf, Wp0a_t, p0_b1, h1, nullptr, n, 128, 128, 2);
    k_bgemm<<<mt, 256, 0, stream>>>(h1, Wp0b_t, p0_b2, h2, nullptr, n, 128, 128, 2);
    k_gemv<<<(n + 3) / 4, 256, 0, stream>>>(h2, p0_W3, p0_b3, s0, n);
    // discriminator on r_t
    k_bgemm<<<mt, 256, 0, stream>>>(rt_bf, Wda_t, d_b1, h1, nullptr, n, 128, 128, 2);
    k_bgemm<<<mt, 256, 0, stream>>>(h1, Wdb_t, d_b2, h2, nullptr, n, 128, 128, 2);
    k_gemv<<<(n + 3) / 4, 256, 0, stream>>>(h2, d_W3, d_b3, sd, n);

    k_final<<<(n + 255) / 256, 256, 0, stream>>>(s1, s0, sd, t, out, n);
}

// Round 4
// 857.487 us; speedup vs baseline: 1.8140x; 1.2779x over previous
//
#include <hip/hip_runtime.h>
#include <hip/hip_bf16.h>
#include <math.h>

// ---------------------------------------------------------------------------
// SPNet: GCN(2x) -> masked edge attention -> encoder -> 3 MLP heads
// N=100000, E=1600000, F=H=128.
// Round 4:
//   - k_agg: xw prescaled by dinv (in GEMM epilogue) + edge-loop unroll x4
//            (was latency-bound: 1.95 TB/s, VALU 22%, Mfma 0)
//   - k_attn: separate masked CSR (t[src]>0) -> branch-free unrolled pass 2
//   - k_heads: all 3 MLP heads fused in one kernel (MFMA + LDS transpose),
//              replaces 6 GEMM + 3 GEMV + k_final dispatches
// ---------------------------------------------------------------------------

using bf16x8 = __attribute__((ext_vector_type(8))) short;
using f32x4  = __attribute__((ext_vector_type(4))) float;

static __device__ __forceinline__ float lrelu02(float x) { return x > 0.f ? x : 0.2f * x; }

static __device__ __forceinline__ unsigned short f2bf(float f) {
    unsigned u = __float_as_uint(f);
    unsigned r = u + 0x7FFF + ((u >> 16) & 1);   // round-to-nearest-even
    return (unsigned short)(r >> 16);
}
static __device__ __forceinline__ float bf2f(unsigned short h) {
    return __uint_as_float(((unsigned)h) << 16);
}
static __device__ __forceinline__ float bflo(unsigned u) { return __uint_as_float(u << 16); }
static __device__ __forceinline__ float bfhi(unsigned u) { return __uint_as_float(u & 0xFFFF0000u); }

// ---------------- CSR build ----------------

__global__ void k_zero_i32(int* __restrict__ p, int n) {
    int i = blockIdx.x * blockDim.x + threadIdx.x;
    int stride = gridDim.x * blockDim.x;
    for (; i < n; i += stride) p[i] = 0;
}

// counts (all edges) + counts_m (t[src]>0 edges)
__global__ void k_count(const int* __restrict__ src, const int* __restrict__ dst,
                        const int* __restrict__ t,
                        int* __restrict__ counts, int* __restrict__ counts_m, int e) {
    int i = blockIdx.x * blockDim.x + threadIdx.x;
    int stride = gridDim.x * blockDim.x;
    for (; i < e; i += stride) {
        int d = dst[i];
        atomicAdd(&counts[d], 1);
        if (t[src[i]] > 0) atomicAdd(&counts_m[d], 1);
    }
}

// per-block (1024-element chunk) sum of counts
__global__ __launch_bounds__(256) void k_part(const int* __restrict__ counts,
                                              int* __restrict__ bsum, int n) {
    __shared__ int red[256];
    int b = blockIdx.x, t = threadIdx.x;
    int base = b * 1024 + t * 4;
    int s = 0;
#pragma unroll
    for (int j = 0; j < 4; ++j) {
        int i = base + j;
        if (i < n) s += counts[i];
    }
    red[t] = s;
    __syncthreads();
    for (int off = 128; off; off >>= 1) {
        if (t < off) red[t] += red[t + off];
        __syncthreads();
    }
    if (t == 0) bsum[b] = red[0];
}

// exclusive scan of <=256 block sums
__global__ __launch_bounds__(256) void k_scanb(const int* __restrict__ bsum,
                                               int* __restrict__ boff, int nb) {
    __shared__ int s[256];
    int t = threadIdx.x;
    int v = (t < nb) ? bsum[t] : 0;
    s[t] = v;
    __syncthreads();
    for (int off = 1; off < 256; off <<= 1) {
        int u = (t >= off) ? s[t - off] : 0;
        __syncthreads();
        s[t] += u;
        __syncthreads();
    }
    if (t < nb) boff[t] = s[t] - v;
}

// per-block local exclusive scan + global base -> indptr/cursor (+dinv if non-null)
__global__ __launch_bounds__(256) void k_csr(const int* __restrict__ counts,
                                             const int* __restrict__ boff,
                                             int* __restrict__ indptr,
                                             int* __restrict__ cursor,
                                             float* __restrict__ dinv, int n) {
    __shared__ int tsum[256];
    int b = blockIdx.x, t = threadIdx.x;
    int base = b * 1024 + t * 4;
    int c[4];
    int s = 0;
#pragma unroll
    for (int j = 0; j < 4; ++j) {
        int i = base + j;
        c[j] = (i < n) ? counts[i] : 0;
        s += c[j];
    }
    tsum[t] = s;
    __syncthreads();
    for (int off = 1; off < 256; off <<= 1) {
        int u = (t >= off) ? tsum[t - off] : 0;
        __syncthreads();
        tsum[t] += u;
        __syncthreads();
    }
    int pre = boff[b] + tsum[t] - s;
#pragma unroll
    for (int j = 0; j < 4; ++j) {
        int i = base + j;
        if (i < n) {
            indptr[i] = pre;
            cursor[i] = pre;
            if (dinv) dinv[i] = rsqrtf((float)c[j] + 1.0f);  // self-loop adds 1
            pre += c[j];
            if (i == n - 1) indptr[n] = pre;
        }
    }
}

// fill both edge lists
__global__ void k_fill(const int* __restrict__ src, const int* __restrict__ dst,
                       const int* __restrict__ t,
                       int* __restrict__ cursor, int* __restrict__ cursor_m,
                       int* __restrict__ out_all, int* __restrict__ out_m, int e) {
    int i = blockIdx.x * blockDim.x + threadIdx.x;
    int stride = gridDim.x * blockDim.x;
    for (; i < e; i += stride) {
        int d = dst[i], s = src[i];
        int pos = atomicAdd(&cursor[d], 1);
        out_all[pos] = s;
        if (t[s] > 0) {
            int pm = atomicAdd(&cursor_m[d], 1);
            out_m[pm] = s;
        }
    }
}

// ---------------- prep (fp32 -> bf16) ----------------

__global__ void k_cvt(const float* __restrict__ in, unsigned short* __restrict__ out, int n4) {
    int i = blockIdx.x * blockDim.x + threadIdx.x;
    int stride = gridDim.x * blockDim.x;
    for (; i < n4; i += stride) {
        float4 v = ((const float4*)in)[i];
        ushort4 o;
        o.x = f2bf(v.x); o.y = f2bf(v.y); o.z = f2bf(v.z); o.w = f2bf(v.w);
        ((ushort4*)out)[i] = o;
    }
}

// W[K][Nc] fp32 -> Wt[Nc][K] bf16
__global__ void k_wt(const float* __restrict__ W, unsigned short* __restrict__ Wt,
                     int K, int Nc) {
    int i = blockIdx.x * blockDim.x + threadIdx.x;
    if (i >= K * Nc) return;
    int k = i / Nc, j = i % Nc;
    Wt[(size_t)j * K + k] = f2bf(W[i]);
}

// Wcat_t[j][k] = j<128 ? W_o[k][j] : W_t[k][j-128]   ([256][128] bf16)
__global__ void k_wcat_t(const float* __restrict__ Wo, const float* __restrict__ Wt_in,
                         unsigned short* __restrict__ Wt) {
    int i = blockIdx.x * blockDim.x + threadIdx.x;
    if (i >= 256 * 128) return;
    int j = i >> 7, k = i & 127;
    float v = (j < 128) ? Wo[(k << 7) + j] : Wt_in[(k << 7) + j - 128];
    Wt[i] = f2bf(v);
}

// ---------------- bf16 MFMA GEMM ----------------
// C = act(rowscale * (A @ B) + bias), B transposed: Wt[Ncols][K] bf16.
// 256 thr = 4 waves; tile 64 rows x 128 cols; wave w owns rows [w*16,+16).
__global__ __launch_bounds__(256) void k_bgemm(const unsigned short* __restrict__ A,
                                               const unsigned short* __restrict__ Wt,
                                               const float* __restrict__ bias,
                                               const float* __restrict__ rowscale,
                                               unsigned short* __restrict__ outb,
                                               float* __restrict__ outf,
                                               int M, int K, int Ncols, int act) {
    int nct = Ncols >> 7;
    int mtile = blockIdx.x / nct;
    int col0 = (blockIdx.x % nct) << 7;
    int wave = threadIdx.x >> 6, lane = threadIdx.x & 63;
    int row_base = mtile * 64 + wave * 16;

    int rA = row_base + (lane & 15);
    if (rA >= M) rA = M - 1;
    const short* Ap = (const short*)A + (size_t)rA * K + ((lane >> 4) << 3);
    const short* Bp = (const short*)Wt + (size_t)(col0 + (lane & 15)) * K + ((lane >> 4) << 3);

    f32x4 acc[8];
#pragma unroll
    for (int cf = 0; cf < 8; ++cf) acc[cf] = (f32x4){0.f, 0.f, 0.f, 0.f};

    int nks = K >> 5;
    for (int ks = 0; ks < nks; ++ks) {
        bf16x8 a = *(const bf16x8*)(Ap + (ks << 5));
#pragma unroll
        for (int cf = 0; cf < 8; ++cf) {
            bf16x8 b = *(const bf16x8*)(Bp + (size_t)(cf << 4) * K + (ks << 5));
            acc[cf] = __builtin_amdgcn_mfma_f32_16x16x32_bf16(a, b, acc[cf], 0, 0, 0);
        }
    }

    float rs[4];
#pragma unroll
    for (int j = 0; j < 4; ++j) {
        int row = row_base + ((lane >> 4) << 2) + j;
        rs[j] = rowscale ? rowscale[row < M ? row : M - 1] : 1.f;
    }

#pragma unroll
    for (int cf = 0; cf < 8; ++cf) {
        int col = col0 + (cf << 4) + (lane & 15);
        float bv = bias ? bias[col] : 0.f;
#pragma unroll
        for (int j = 0; j < 4; ++j) {
            int row = row_base + ((lane >> 4) << 2) + j;
            if (row >= M) continue;
            float v = acc[cf][j] * rs[j] + bv;
            if (act == 2) v = lrelu02(v);
            if (outb) outb[(size_t)row * Ncols + col] = f2bf(v);
            if (outf) outf[(size_t)row * Ncols + col] = v;
        }
    }
}

// ---------------- graph kernels ----------------

// GCN aggregation, xw PRESCALED by dinv[row]. One wave per node, lane owns 4 of 256 cols.
// agg[v] = dinv[v] * (sum_{s in N(v)} xw_s[s] + xw_s[v]); + bias, relu; e fused.
__global__ __launch_bounds__(256) void k_agg(const unsigned short* __restrict__ xw,
                                             const int* __restrict__ indptr,
                                             const int* __restrict__ srcs,
                                             const float* __restrict__ dinv,
                                             const float* __restrict__ b_o,
                                             const float* __restrict__ b_t,
                                             const float* __restrict__ a_w,
                                             const float* __restrict__ a_b,
                                             unsigned short* __restrict__ cat2,
                                             unsigned short* __restrict__ rt,
                                             float* __restrict__ e, int n) {
    int wv = threadIdx.x >> 6, lane = threadIdx.x & 63;
    int v = blockIdx.x * 4 + wv;
    if (v >= n) return;
    const ushort4* xw4 = (const ushort4*)xw;
    int beg = indptr[v], end = indptr[v + 1];
    float a0, a1, a2, a3;
    {   // self loop (independent; issue first)
        ushort4 sv = xw4[(size_t)v * 64 + lane];
        a0 = bf2f(sv.x); a1 = bf2f(sv.y); a2 = bf2f(sv.z); a3 = bf2f(sv.w);
    }
    int i = beg;
    for (; i + 4 <= end; i += 4) {   // 4 gathers in flight
        int s0 = srcs[i], s1 = srcs[i + 1], s2 = srcs[i + 2], s3 = srcs[i + 3];
        ushort4 v0 = xw4[(size_t)s0 * 64 + lane];
        ushort4 v1 = xw4[(size_t)s1 * 64 + lane];
        ushort4 v2 = xw4[(size_t)s2 * 64 + lane];
        ushort4 v3 = xw4[(size_t)s3 * 64 + lane];
        a0 += bf2f(v0.x) + bf2f(v1.x) + bf2f(v2.x) + bf2f(v3.x);
        a1 += bf2f(v0.y) + bf2f(v1.y) + bf2f(v2.y) + bf2f(v3.y);
        a2 += bf2f(v0.z) + bf2f(v1.z) + bf2f(v2.z) + bf2f(v3.z);
        a3 += bf2f(v0.w) + bf2f(v1.w) + bf2f(v2.w) + bf2f(v3.w);
    }
    for (; i < end; ++i) {
        int s = srcs[i];
        ushort4 vv = xw4[(size_t)s * 64 + lane];
        a0 += bf2f(vv.x); a1 += bf2f(vv.y); a2 += bf2f(vv.z); a3 += bf2f(vv.w);
    }
    float dv = dinv[v];
    int col = lane << 2;
    const float* bb = (col < 128) ? (b_o + col) : (b_t + col - 128);
    a0 = fmaxf(a0 * dv + bb[0], 0.f);
    a1 = fmaxf(a1 * dv + bb[1], 0.f);
    a2 = fmaxf(a2 * dv + bb[2], 0.f);
    a3 = fmaxf(a3 * dv + bb[3], 0.f);
    ushort4 o;
    o.x = f2bf(a0); o.y = f2bf(a1); o.z = f2bf(a2); o.w = f2bf(a3);
    if (col < 128)
        ((ushort4*)(cat2 + (size_t)v * 256))[lane] = o;
    else
        ((ushort4*)(rt + (size_t)v * 128))[lane - 32] = o;
    float4 aw = *(const float4*)(a_w + col);
    float s = a0 * aw.x + a1 * aw.y + a2 * aw.z + a3 * aw.w;
    for (int off = 32; off; off >>= 1) s += __shfl_down(s, off);
    if (lane == 0) e[v] = s + a_b[0];
}

// Masked attention. Pass 1: max over ALL in-edges (full CSR, lane-parallel).
// Pass 2: branch-free over MASKED CSR, unrolled x4. h -> cat2[:,128:256].
__global__ __launch_bounds__(256) void k_attn(const unsigned short* __restrict__ rt,
                                              const int* __restrict__ indptr,
                                              const int* __restrict__ srcs,
                                              const int* __restrict__ indptr_m,
                                              const int* __restrict__ srcs_m,
                                              const float* __restrict__ e,
                                              unsigned short* __restrict__ cat2, int n) {
    int wv = threadIdx.x >> 6, lane = threadIdx.x & 63;
    int v = blockIdx.x * 4 + wv;
    if (v >= n) return;
    float ev = e[v];
    // pass 1: unmasked segment max of leaky_relu(e[s]+e[v])
    int beg = indptr[v], end = indptr[v + 1];
    float m = -INFINITY;
    for (int i = beg + lane; i < end; i += 64) {
        float lg = lrelu02(ev + e[srcs[i]]);
        m = fmaxf(m, lg);
    }
    for (int off = 32; off; off >>= 1) m = fmaxf(m, __shfl_xor(m, off));
    if (beg == end) m = 0.f;  // isfinite(m) ? m : 0
    // pass 2: masked edges only, branch-free
    int bm = indptr_m[v], em = indptr_m[v + 1];
    float h0 = 0.f, h1 = 0.f, wsum = 0.f;
    const unsigned* rt2 = (const unsigned*)rt;
    int i = bm;
    for (; i + 4 <= em; i += 4) {
        int s0 = srcs_m[i], s1 = srcs_m[i + 1], s2 = srcs_m[i + 2], s3 = srcs_m[i + 3];
        float w0 = __expf(lrelu02(ev + e[s0]) - m);
        float w1 = __expf(lrelu02(ev + e[s1]) - m);
        float w2 = __expf(lrelu02(ev + e[s2]) - m);
        float w3 = __expf(lrelu02(ev + e[s3]) - m);
        unsigned u0 = rt2[(size_t)s0 * 64 + lane];
        unsigned u1 = rt2[(size_t)s1 * 64 + lane];
        unsigned u2 = rt2[(size_t)s2 * 64 + lane];
        unsigned u3 = rt2[(size_t)s3 * 64 + lane];
        wsum += w0 + w1 + w2 + w3;
        h0 += w0 * bflo(u0) + w1 * bflo(u1) + w2 * bflo(u2) + w3 * bflo(u3);
        h1 += w0 * bfhi(u0) + w1 * bfhi(u1) + w2 * bfhi(u2) + w3 * bfhi(u3);
    }
    for (; i < em; ++i) {
        int s = srcs_m[i];
        float w = __expf(lrelu02(ev + e[s]) - m);
        unsigned u = rt2[(size_t)s * 64 + lane];
        wsum += w;
        h0 += w * bflo(u);
        h1 += w * bfhi(u);
    }
    float inv = 1.f / (wsum + 1e-16f);
    unsigned o = (unsigned)f2bf(h0 * inv) | ((unsigned)f2bf(h1 * inv) << 16);
    ((unsigned*)(cat2 + (size_t)v * 256 + 128))[lane] = o;
}

// ---------------- fused heads ----------------
// All 3 MLP heads (p1/p0 on zenc, d on rt) + select + sigmoid, one pass.
// 64 rows/block, wave owns 16 rows. Layer1 MFMA -> LDS transpose -> layer2
// MFMA -> W3 dot (shfl_xor reduce). LDS rows padded to 136 shorts (272 B).
__global__ __launch_bounds__(256) void k_heads(
    const unsigned short* __restrict__ zenc_bf, const unsigned short* __restrict__ rt_bf,
    const unsigned short* __restrict__ W11, const float* __restrict__ b11,
    const unsigned short* __restrict__ W12, const float* __restrict__ b12,
    const float* __restrict__ W13, const float* __restrict__ b13,
    const unsigned short* __restrict__ W01, const float* __restrict__ b01,
    const unsigned short* __restrict__ W02, const float* __restrict__ b02,
    const float* __restrict__ W03, const float* __restrict__ b03,
    const unsigned short* __restrict__ Wd1, const float* __restrict__ bd1,
    const unsigned short* __restrict__ Wd2, const float* __restrict__ bd2,
    const float* __restrict__ Wd3, const float* __restrict__ bd3,
    const int* __restrict__ t, float* __restrict__ out, int M) {
    __shared__ unsigned short hl[4][16][136];
    int wave = threadIdx.x >> 6, lane = threadIdx.x & 63;
    int row_base = blockIdx.x * 64 + wave * 16;
    int rA = row_base + (lane & 15);
    if (rA >= M) rA = M - 1;
    int koff = (lane >> 4) << 3;
    int colL = lane & 15;

    bf16x8 za[4], ra[4];
#pragma unroll
    for (int ks = 0; ks < 4; ++ks) {
        za[ks] = *(const bf16x8*)((const short*)zenc_bf + (size_t)rA * 128 + (ks << 5) + koff);
        ra[ks] = *(const bf16x8*)((const short*)rt_bf + (size_t)rA * 128 + (ks << 5) + koff);
    }

    float sp1[4], sp0[4], sdd[4];

    auto run_head = [&](const bf16x8* A0,
                        const unsigned short* W1, const float* b1,
                        const unsigned short* W2, const float* b2,
                        const float* W3, const float* b3, float* sout) {
        f32x4 acc[8];
#pragma unroll
        for (int cf = 0; cf < 8; ++cf) acc[cf] = (f32x4){0.f, 0.f, 0.f, 0.f};
#pragma unroll
        for (int ks = 0; ks < 4; ++ks)
#pragma unroll
            for (int cf = 0; cf < 8; ++cf) {
                bf16x8 b = *(const bf16x8*)((const short*)W1 + (size_t)((cf << 4) + colL) * 128 + (ks << 5) + koff);
                acc[cf] = __builtin_amdgcn_mfma_f32_16x16x32_bf16(A0[ks], b, acc[cf], 0, 0, 0);
            }
        __syncthreads();   // WAR: previous head's LDS reads done
#pragma unroll
        for (int cf = 0; cf < 8; ++cf) {
            int col = (cf << 4) + colL;
            float bv = b1[col];
#pragma unroll
            for (int j = 0; j < 4; ++j)
                hl[wave][((lane >> 4) << 2) + j][col] = f2bf(lrelu02(acc[cf][j] + bv));
        }
        __syncthreads();
        bf16x8 h1f[4];
#pragma unroll
        for (int ks = 0; ks < 4; ++ks)
            h1f[ks] = *(const bf16x8*)&hl[wave][colL][(ks << 5) + koff];
#pragma unroll
        for (int cf = 0; cf < 8; ++cf) acc[cf] = (f32x4){0.f, 0.f, 0.f, 0.f};
#pragma unroll
        for (int ks = 0; ks < 4; ++ks)
#pragma unroll
            for (int cf = 0; cf < 8; ++cf) {
                bf16x8 b = *(const bf16x8*)((const short*)W2 + (size_t)((cf << 4) + colL) * 128 + (ks << 5) + koff);
                acc[cf] = __builtin_amdgcn_mfma_f32_16x16x32_bf16(h1f[ks], b, acc[cf], 0, 0, 0);
            }
        float s0 = 0.f, s1 = 0.f, s2 = 0.f, s3 = 0.f;
#pragma unroll
        for (int cf = 0; cf < 8; ++cf) {
            int col = (cf << 4) + colL;
            float w3 = W3[col], bv = b2[col];
            s0 += lrelu02(acc[cf][0] + bv) * w3;
            s1 += lrelu02(acc[cf][1] + bv) * w3;
            s2 += lrelu02(acc[cf][2] + bv) * w3;
            s3 += lrelu02(acc[cf][3] + bv) * w3;
        }
#pragma unroll
        for (int mk = 1; mk < 16; mk <<= 1) {
            s0 += __shfl_xor(s0, mk); s1 += __shfl_xor(s1, mk);
            s2 += __shfl_xor(s2, mk); s3 += __shfl_xor(s3, mk);
        }
        float bb = b3[0];
        sout[0] = s0 + bb; sout[1] = s1 + bb; sout[2] = s2 + bb; sout[3] = s3 + bb;
    };

    run_head(za, W11, b11, W12, b12, W13, b13, sp1);
    run_head(za, W01, b01, W02, b02, W03, b03, sp0);
    run_head(ra, Wd1, bd1, Wd2, bd2, Wd3, bd3, sdd);

    if (colL == 0) {
#pragma unroll
        for (int j = 0; j < 4; ++j) {
            int row = row_base + ((lane >> 4) << 2) + j;
            if (row < M) {
                out[row] = 1.f / (1.f + __expf(-sdd[j]));           // pred_t
                out[M + row] = (t[row] > 0) ? sp1[j] : sp0[j];      // pred
            }
        }
    }
}

// ---------------- launcher ----------------

extern "C" void kernel_launch(void* const* d_in, const int* in_sizes, int n_in,
                              void* d_out, int out_size, void* d_ws, size_t ws_size,
                              hipStream_t stream) {
    const float* x     = (const float*)d_in[0];
    const int*   t     = (const int*)d_in[1];
    const int*   ei    = (const int*)d_in[3];
    const float* W_o   = (const float*)d_in[4];
    const float* b_o   = (const float*)d_in[5];
    const float* W_t   = (const float*)d_in[6];
    const float* b_t   = (const float*)d_in[7];
    const float* a_w   = (const float*)d_in[8];
    const float* a_b   = (const float*)d_in[9];
    const float* W_enc = (const float*)d_in[10];
    const float* b_enc = (const float*)d_in[11];
    const float* p1_W1 = (const float*)d_in[12]; const float* p1_b1 = (const float*)d_in[13];
    const float* p1_W2 = (const float*)d_in[14]; const float* p1_b2 = (const float*)d_in[15];
    const float* p1_W3 = (const float*)d_in[16]; const float* p1_b3 = (const float*)d_in[17];
    const float* p0_W1 = (const float*)d_in[18]; const float* p0_b1 = (const float*)d_in[19];
    const float* p0_W2 = (const float*)d_in[20]; const float* p0_b2 = (const float*)d_in[21];
    const float* p0_W3 = (const float*)d_in[22]; const float* p0_b3 = (const float*)d_in[23];
    const float* d_W1  = (const float*)d_in[24]; const float* d_b1  = (const float*)d_in[25];
    const float* d_W2  = (const float*)d_in[26]; const float* d_b2  = (const float*)d_in[27];
    const float* d_W3  = (const float*)d_in[28]; const float* d_b3  = (const float*)d_in[29];

    const int n = in_sizes[1];
    const int E = in_sizes[3] / 2;
    const int* src = ei;
    const int* dst = ei + E;

    float* out  = (float*)d_out;
    float* zenc = out + 2 * (size_t)n;   // output: pred_t[N], pred[N], z_enc[N,128]

    // ---- workspace layout ----
    char* base = (char*)d_ws;
    size_t o = 0;
    auto alloc = [&](size_t bytes) { char* p = base + o; o += (bytes + 255) & ~(size_t)255; return p; };
    unsigned short* x_bf    = (unsigned short*)alloc((size_t)n * 128 * 2);
    unsigned short* xw_bf   = (unsigned short*)alloc((size_t)n * 256 * 2);  // prescaled by dinv
    unsigned short* cat2_bf = (unsigned short*)alloc((size_t)n * 256 * 2);
    unsigned short* rt_bf   = (unsigned short*)alloc((size_t)n * 128 * 2);
    unsigned short* zenc_bf = (unsigned short*)alloc((size_t)n * 128 * 2);
    float* dinv = (float*)alloc((size_t)n * 4);
    float* evec = (float*)alloc((size_t)n * 4);
    unsigned short* Wcat_t = (unsigned short*)alloc(256 * 128 * 2);
    unsigned short* Wenc_t = (unsigned short*)alloc(128 * 256 * 2);
    unsigned short* Wp1a_t = (unsigned short*)alloc(128 * 128 * 2);
    unsigned short* Wp1b_t = (unsigned short*)alloc(128 * 128 * 2);
    unsigned short* Wp0a_t = (unsigned short*)alloc(128 * 128 * 2);
    unsigned short* Wp0b_t = (unsigned short*)alloc(128 * 128 * 2);
    unsigned short* Wda_t  = (unsigned short*)alloc(128 * 128 * 2);
    unsigned short* Wdb_t  = (unsigned short*)alloc(128 * 128 * 2);
    int* counts     = (int*)alloc((size_t)n * 2 * 4);   // [counts | counts_m]
    int* counts_m   = counts + n;
    int* indptr     = (int*)alloc(((size_t)n + 1) * 4);
    int* indptr_m   = (int*)alloc(((size_t)n + 1) * 4);
    int* cursor     = (int*)alloc((size_t)n * 4);
    int* cursor_m   = (int*)alloc((size_t)n * 4);
    int* bsum       = (int*)alloc(256 * 4);
    int* boff       = (int*)alloc(256 * 4);
    int* bsum_m     = (int*)alloc(256 * 4);
    int* boff_m     = (int*)alloc(256 * 4);
    int* src_sorted = (int*)alloc((size_t)E * 4);
    int* src_mask   = (int*)alloc((size_t)E * 4);

    const int egrid = (E + 255) / 256 > 2048 ? 2048 : (E + 255) / 256;
    const int nb = (n + 1023) / 1024;
    const int mt = (n + 63) / 64;

    // CSR build (full + masked)
    k_zero_i32<<<256, 256, 0, stream>>>(counts, 2 * n);
    k_count<<<egrid, 256, 0, stream>>>(src, dst, t, counts, counts_m, E);
    k_part<<<nb, 256, 0, stream>>>(counts, bsum, n);
    k_scanb<<<1, 256, 0, stream>>>(bsum, boff, nb);
    k_csr<<<nb, 256, 0, stream>>>(counts, boff, indptr, cursor, dinv, n);
    k_part<<<nb, 256, 0, stream>>>(counts_m, bsum_m, n);
    k_scanb<<<1, 256, 0, stream>>>(bsum_m, boff_m, nb);
    k_csr<<<nb, 256, 0, stream>>>(counts_m, boff_m, indptr_m, cursor_m, nullptr, n);
    k_fill<<<egrid, 256, 0, stream>>>(src, dst, t, cursor, cursor_m, src_sorted, src_mask, E);

    // prep
    k_cvt<<<2048, 256, 0, stream>>>(x, x_bf, n * 32);
    k_wcat_t<<<128, 256, 0, stream>>>(W_o, W_t, Wcat_t);
    k_wt<<<128, 256, 0, stream>>>(W_enc, Wenc_t, 256, 128);
    k_wt<<<64, 256, 0, stream>>>(p1_W1, Wp1a_t, 128, 128);
    k_wt<<<64, 256, 0, stream>>>(p1_W2, Wp1b_t, 128, 128);
    k_wt<<<64, 256, 0, stream>>>(p0_W1, Wp0a_t, 128, 128);
    k_wt<<<64, 256, 0, stream>>>(p0_W2, Wp0b_t, 128, 128);
    k_wt<<<64, 256, 0, stream>>>(d_W1, Wda_t, 128, 128);
    k_wt<<<64, 256, 0, stream>>>(d_W2, Wdb_t, 128, 128);

    // xw = dinv[row] * (x @ [W_o | W_t])   (prescaled, bf16)
    k_bgemm<<<mt * 2, 256, 0, stream>>>(x_bf, Wcat_t, nullptr, dinv, xw_bf, nullptr, n, 128, 256, 0);

    // GCN aggregate (both convs) + relu + bias + e
    k_agg<<<(n + 3) / 4, 256, 0, stream>>>(xw_bf, indptr, src_sorted, dinv, b_o, b_t,
                                           a_w, a_b, cat2_bf, rt_bf, evec, n);
    // attention -> h
    k_attn<<<(n + 3) / 4, 256, 0, stream>>>(rt_bf, indptr, src_sorted, indptr_m, src_mask,
                                            evec, cat2_bf, n);

    // z_enc = cat2 @ W_enc + b_enc
    k_bgemm<<<mt, 256, 0, stream>>>(cat2_bf, Wenc_t, b_enc, nullptr, zenc_bf, zenc, n, 256, 128, 0);

    // fused heads + select + sigmoid
    k_heads<<<mt, 256, 0, stream>>>(zenc_bf, rt_bf,
                                    Wp1a_t, p1_b1, Wp1b_t, p1_b2, p1_W3, p1_b3,
                                    Wp0a_t, p0_b1, Wp0b_t, p0_b2, p0_W3, p0_b3,
                                    Wda_t, d_b1, Wdb_t, d_b2, d_W3, d_b3,
                                    t, out, n);
}

// Round 5
// 668.749 us; speedup vs baseline: 2.3259x; 1.2822x over previous
//
#include <hip/hip_runtime.h>
#include <hip/hip_bf16.h>
#include <math.h>

// ---------------------------------------------------------------------------
// SPNet: GCN(2x) -> masked edge attention -> encoder -> 3 MLP heads
// N=100000, E=1600000, F=H=128.
// Round 5:
//   - k_heads: weights staged in LDS (bulk, conflict-free padded rows);
//     was latency-bound on per-lane global weight loads (Mfma 4%, 191us)
//   - CSR fill: 2-stage bucket partition (packed int payload) kills the
//     16x write amplification of the random scatter (was 196us, 157MB wr)
// ---------------------------------------------------------------------------

using bf16x8 = __attribute__((ext_vector_type(8))) short;
using f32x4  = __attribute__((ext_vector_type(4))) float;

static __device__ __forceinline__ float lrelu02(float x) { return x > 0.f ? x : 0.2f * x; }

static __device__ __forceinline__ unsigned short f2bf(float f) {
    unsigned u = __float_as_uint(f);
    unsigned r = u + 0x7FFF + ((u >> 16) & 1);   // round-to-nearest-even
    return (unsigned short)(r >> 16);
}
static __device__ __forceinline__ float bf2f(unsigned short h) {
    return __uint_as_float(((unsigned)h) << 16);
}
static __device__ __forceinline__ float bflo(unsigned u) { return __uint_as_float(u << 16); }
static __device__ __forceinline__ float bfhi(unsigned u) { return __uint_as_float(u & 0xFFFF0000u); }

// ---------------- CSR build ----------------

__global__ void k_zero_i32(int* __restrict__ p, int n) {
    int i = blockIdx.x * blockDim.x + threadIdx.x;
    int stride = gridDim.x * blockDim.x;
    for (; i < n; i += stride) p[i] = 0;
}

__global__ void k_copy_i32(const int* __restrict__ a, int* __restrict__ b, int n) {
    int i = blockIdx.x * blockDim.x + threadIdx.x;
    if (i < n) b[i] = a[i];
}

// per-dst counts (full + masked) + per-bucket histogram (LDS-aggregated)
__global__ __launch_bounds__(256) void k_count2(const int* __restrict__ src,
                                                const int* __restrict__ dst,
                                                const int* __restrict__ t,
                                                int* __restrict__ counts,
                                                int* __restrict__ counts_m,
                                                int* __restrict__ bhist,
                                                int e, int shift) {
    __shared__ int h[256];
    h[threadIdx.x] = 0;
    __syncthreads();
    int i = blockIdx.x * blockDim.x + threadIdx.x;
    int stride = gridDim.x * blockDim.x;
    for (; i < e; i += stride) {
        int d = dst[i];
        atomicAdd(&counts[d], 1);
        if (t[src[i]] > 0) atomicAdd(&counts_m[d], 1);
        atomicAdd(&h[d >> shift], 1);
    }
    __syncthreads();
    if (h[threadIdx.x] > 0) atomicAdd(&bhist[threadIdx.x], h[threadIdx.x]);
}

// per-block (1024-element chunk) sum of counts
__global__ __launch_bounds__(256) void k_part(const int* __restrict__ counts,
                                              int* __restrict__ bsum, int n) {
    __shared__ int red[256];
    int b = blockIdx.x, t = threadIdx.x;
    int base = b * 1024 + t * 4;
    int s = 0;
#pragma unroll
    for (int j = 0; j < 4; ++j) {
        int i = base + j;
        if (i < n) s += counts[i];
    }
    red[t] = s;
    __syncthreads();
    for (int off = 128; off; off >>= 1) {
        if (t < off) red[t] += red[t + off];
        __syncthreads();
    }
    if (t == 0) bsum[b] = red[0];
}

// exclusive scan of <=256 values; also writes boff[nb] = total
__global__ __launch_bounds__(256) void k_scanb(const int* __restrict__ bsum,
                                               int* __restrict__ boff, int nb) {
    __shared__ int s[256];
    int t = threadIdx.x;
    int v = (t < nb) ? bsum[t] : 0;
    s[t] = v;
    __syncthreads();
    for (int off = 1; off < 256; off <<= 1) {
        int u = (t >= off) ? s[t - off] : 0;
        __syncthreads();
        s[t] += u;
        __syncthreads();
    }
    if (t < nb) boff[t] = s[t] - v;
    if (t == nb - 1) boff[nb] = s[t];
}

// per-block local exclusive scan + global base -> indptr/cursor (+dinv if non-null)
__global__ __launch_bounds__(256) void k_csr(const int* __restrict__ counts,
                                             const int* __restrict__ boff,
                                             int* __restrict__ indptr,
                                             int* __restrict__ cursor,
                                             float* __restrict__ dinv, int n) {
    __shared__ int tsum[256];
    int b = blockIdx.x, t = threadIdx.x;
    int base = b * 1024 + t * 4;
    int c[4];
    int s = 0;
#pragma unroll
    for (int j = 0; j < 4; ++j) {
        int i = base + j;
        c[j] = (i < n) ? counts[i] : 0;
        s += c[j];
    }
    tsum[t] = s;
    __syncthreads();
    for (int off = 1; off < 256; off <<= 1) {
        int u = (t >= off) ? tsum[t - off] : 0;
        __syncthreads();
        tsum[t] += u;
        __syncthreads();
    }
    int pre = boff[b] + tsum[t] - s;
#pragma unroll
    for (int j = 0; j < 4; ++j) {
        int i = base + j;
        if (i < n) {
            indptr[i] = pre;
            cursor[i] = pre;
            if (dinv) dinv[i] = rsqrtf((float)c[j] + 1.0f);  // self-loop adds 1
            pre += c[j];
            if (i == n - 1) indptr[n] = pre;
        }
    }
}

// pass B: partition edges into dst-buckets; payload = src | (dst_lo << 20)
__global__ __launch_bounds__(256) void k_fillB(const int* __restrict__ src,
                                               const int* __restrict__ dst,
                                               int* __restrict__ bcur,
                                               int* __restrict__ ebuf,
                                               int e, int shift) {
    __shared__ int h[256];
    const int EPT = 16;
    int blk_base = blockIdx.x * 256 * EPT;
    h[threadIdx.x] = 0;
    __syncthreads();
    int pk[EPT], bk[EPT];
#pragma unroll
    for (int j = 0; j < EPT; ++j) {
        int i = blk_base + threadIdx.x + j * 256;
        if (i < e) {
            int s = src[i], d = dst[i];
            int b = d >> shift;
            bk[j] = b;
            pk[j] = s | ((d - (b << shift)) << 20);
            atomicAdd(&h[b], 1);
        } else bk[j] = -1;
    }
    __syncthreads();
    int cnt = h[threadIdx.x];
    int base = 0;
    if (cnt > 0) base = atomicAdd(&bcur[threadIdx.x], cnt);
    __syncthreads();
    h[threadIdx.x] = base;
    __syncthreads();
#pragma unroll
    for (int j = 0; j < EPT; ++j) {
        if (bk[j] >= 0) {
            int pos = atomicAdd(&h[bk[j]], 1);
            ebuf[pos] = pk[j];
        }
    }
}

// pass C: one block per bucket; scatter within L2-resident output slice
__global__ __launch_bounds__(256) void k_fillC(const int* __restrict__ ebuf,
                                               const int* __restrict__ bbase,
                                               const int* __restrict__ t,
                                               int* __restrict__ cursor,
                                               int* __restrict__ cursor_m,
                                               int* __restrict__ out_all,
                                               int* __restrict__ out_m, int shift) {
    int b = blockIdx.x;
    int lo = bbase[b], hi = bbase[b + 1];
    int dbase = b << shift;
    for (int i = lo + threadIdx.x; i < hi; i += 256) {
        int pk = ebuf[i];
        int s = pk & 0xFFFFF;
        int d = dbase + (pk >> 20);
        int pos = atomicAdd(&cursor[d], 1);
        out_all[pos] = s;
        if (t[s] > 0) {
            int pm = atomicAdd(&cursor_m[d], 1);
            out_m[pm] = s;
        }
    }
}

// ---------------- prep (fp32 -> bf16) ----------------

__global__ void k_cvt(const float* __restrict__ in, unsigned short* __restrict__ out, int n4) {
    int i = blockIdx.x * blockDim.x + threadIdx.x;
    int stride = gridDim.x * blockDim.x;
    for (; i < n4; i += stride) {
        float4 v = ((const float4*)in)[i];
        ushort4 o;
        o.x = f2bf(v.x); o.y = f2bf(v.y); o.z = f2bf(v.z); o.w = f2bf(v.w);
        ((ushort4*)out)[i] = o;
    }
}

// W[K][Nc] fp32 -> Wt[Nc][K] bf16
__global__ void k_wt(const float* __restrict__ W, unsigned short* __restrict__ Wt,
                     int K, int Nc) {
    int i = blockIdx.x * blockDim.x + threadIdx.x;
    if (i >= K * Nc) return;
    int k = i / Nc, j = i % Nc;
    Wt[(size_t)j * K + k] = f2bf(W[i]);
}

// Wcat_t[j][k] = j<128 ? W_o[k][j] : W_t[k][j-128]   ([256][128] bf16)
__global__ void k_wcat_t(const float* __restrict__ Wo, const float* __restrict__ Wt_in,
                         unsigned short* __restrict__ Wt) {
    int i = blockIdx.x * blockDim.x + threadIdx.x;
    if (i >= 256 * 128) return;
    int j = i >> 7, k = i & 127;
    float v = (j < 128) ? Wo[(k << 7) + j] : Wt_in[(k << 7) + j - 128];
    Wt[i] = f2bf(v);
}

// ---------------- bf16 MFMA GEMM (weights from global; used for xw/zenc) ----
__global__ __launch_bounds__(256) void k_bgemm(const unsigned short* __restrict__ A,
                                               const unsigned short* __restrict__ Wt,
                                               const float* __restrict__ bias,
                                               const float* __restrict__ rowscale,
                                               unsigned short* __restrict__ outb,
                                               float* __restrict__ outf,
                                               int M, int K, int Ncols, int act) {
    int nct = Ncols >> 7;
    int mtile = blockIdx.x / nct;
    int col0 = (blockIdx.x % nct) << 7;
    int wave = threadIdx.x >> 6, lane = threadIdx.x & 63;
    int row_base = mtile * 64 + wave * 16;

    int rA = row_base + (lane & 15);
    if (rA >= M) rA = M - 1;
    const short* Ap = (const short*)A + (size_t)rA * K + ((lane >> 4) << 3);
    const short* Bp = (const short*)Wt + (size_t)(col0 + (lane & 15)) * K + ((lane >> 4) << 3);

    f32x4 acc[8];
#pragma unroll
    for (int cf = 0; cf < 8; ++cf) acc[cf] = (f32x4){0.f, 0.f, 0.f, 0.f};

    int nks = K >> 5;
    for (int ks = 0; ks < nks; ++ks) {
        bf16x8 a = *(const bf16x8*)(Ap + (ks << 5));
#pragma unroll
        for (int cf = 0; cf < 8; ++cf) {
            bf16x8 b = *(const bf16x8*)(Bp + (size_t)(cf << 4) * K + (ks << 5));
            acc[cf] = __builtin_amdgcn_mfma_f32_16x16x32_bf16(a, b, acc[cf], 0, 0, 0);
        }
    }

    float rs[4];
#pragma unroll
    for (int j = 0; j < 4; ++j) {
        int row = row_base + ((lane >> 4) << 2) + j;
        rs[j] = rowscale ? rowscale[row < M ? row : M - 1] : 1.f;
    }

#pragma unroll
    for (int cf = 0; cf < 8; ++cf) {
        int col = col0 + (cf << 4) + (lane & 15);
        float bv = bias ? bias[col] : 0.f;
#pragma unroll
        for (int j = 0; j < 4; ++j) {
            int row = row_base + ((lane >> 4) << 2) + j;
            if (row >= M) continue;
            float v = acc[cf][j] * rs[j] + bv;
            if (act == 2) v = lrelu02(v);
            if (outb) outb[(size_t)row * Ncols + col] = f2bf(v);
            if (outf) outf[(size_t)row * Ncols + col] = v;
        }
    }
}

// ---------------- graph kernels ----------------

// GCN aggregation, xw PRESCALED by dinv[row]. One wave per node, lane owns 4 of 256 cols.
__global__ __launch_bounds__(256) void k_agg(const unsigned short* __restrict__ xw,
                                             const int* __restrict__ indptr,
                                             const int* __restrict__ srcs,
                                             const float* __restrict__ dinv,
                                             const float* __restrict__ b_o,
                                             const float* __restrict__ b_t,
                                             const float* __restrict__ a_w,
                                             const float* __restrict__ a_b,
                                             unsigned short* __restrict__ cat2,
                                             unsigned short* __restrict__ rt,
                                             float* __restrict__ e, int n) {
    int wv = threadIdx.x >> 6, lane = threadIdx.x & 63;
    int v = blockIdx.x * 4 + wv;
    if (v >= n) return;
    const ushort4* xw4 = (const ushort4*)xw;
    int beg = indptr[v], end = indptr[v + 1];
    float a0, a1, a2, a3;
    {   // self loop
        ushort4 sv = xw4[(size_t)v * 64 + lane];
        a0 = bf2f(sv.x); a1 = bf2f(sv.y); a2 = bf2f(sv.z); a3 = bf2f(sv.w);
    }
    int i = beg;
    for (; i + 4 <= end; i += 4) {
        int s0 = srcs[i], s1 = srcs[i + 1], s2 = srcs[i + 2], s3 = srcs[i + 3];
        ushort4 v0 = xw4[(size_t)s0 * 64 + lane];
        ushort4 v1 = xw4[(size_t)s1 * 64 + lane];
        ushort4 v2 = xw4[(size_t)s2 * 64 + lane];
        ushort4 v3 = xw4[(size_t)s3 * 64 + lane];
        a0 += bf2f(v0.x) + bf2f(v1.x) + bf2f(v2.x) + bf2f(v3.x);
        a1 += bf2f(v0.y) + bf2f(v1.y) + bf2f(v2.y) + bf2f(v3.y);
        a2 += bf2f(v0.z) + bf2f(v1.z) + bf2f(v2.z) + bf2f(v3.z);
        a3 += bf2f(v0.w) + bf2f(v1.w) + bf2f(v2.w) + bf2f(v3.w);
    }
    for (; i < end; ++i) {
        int s = srcs[i];
        ushort4 vv = xw4[(size_t)s * 64 + lane];
        a0 += bf2f(vv.x); a1 += bf2f(vv.y); a2 += bf2f(vv.z); a3 += bf2f(vv.w);
    }
    float dv = dinv[v];
    int col = lane << 2;
    const float* bb = (col < 128) ? (b_o + col) : (b_t + col - 128);
    a0 = fmaxf(a0 * dv + bb[0], 0.f);
    a1 = fmaxf(a1 * dv + bb[1], 0.f);
    a2 = fmaxf(a2 * dv + bb[2], 0.f);
    a3 = fmaxf(a3 * dv + bb[3], 0.f);
    ushort4 o;
    o.x = f2bf(a0); o.y = f2bf(a1); o.z = f2bf(a2); o.w = f2bf(a3);
    if (col < 128)
        ((ushort4*)(cat2 + (size_t)v * 256))[lane] = o;
    else
        ((ushort4*)(rt + (size_t)v * 128))[lane - 32] = o;
    float4 aw = *(const float4*)(a_w + col);
    float s = a0 * aw.x + a1 * aw.y + a2 * aw.z + a3 * aw.w;
    for (int off = 32; off; off >>= 1) s += __shfl_down(s, off);
    if (lane == 0) e[v] = s + a_b[0];
}

// Masked attention. Pass 1: max over ALL in-edges. Pass 2: masked CSR, unrolled.
__global__ __launch_bounds__(256) void k_attn(const unsigned short* __restrict__ rt,
                                              const int* __restrict__ indptr,
                                              const int* __restrict__ srcs,
                                              const int* __restrict__ indptr_m,
                                              const int* __restrict__ srcs_m,
                                              const float* __restrict__ e,
                                              unsigned short* __restrict__ cat2, int n) {
    int wv = threadIdx.x >> 6, lane = threadIdx.x & 63;
    int v = blockIdx.x * 4 + wv;
    if (v >= n) return;
    float ev = e[v];
    int beg = indptr[v], end = indptr[v + 1];
    float m = -INFINITY;
    for (int i = beg + lane; i < end; i += 64) {
        float lg = lrelu02(ev + e[srcs[i]]);
        m = fmaxf(m, lg);
    }
    for (int off = 32; off; off >>= 1) m = fmaxf(m, __shfl_xor(m, off));
    if (beg == end) m = 0.f;
    int bm = indptr_m[v], em = indptr_m[v + 1];
    float h0 = 0.f, h1 = 0.f, wsum = 0.f;
    const unsigned* rt2 = (const unsigned*)rt;
    int i = bm;
    for (; i + 4 <= em; i += 4) {
        int s0 = srcs_m[i], s1 = srcs_m[i + 1], s2 = srcs_m[i + 2], s3 = srcs_m[i + 3];
        float w0 = __expf(lrelu02(ev + e[s0]) - m);
        float w1 = __expf(lrelu02(ev + e[s1]) - m);
        float w2 = __expf(lrelu02(ev + e[s2]) - m);
        float w3 = __expf(lrelu02(ev + e[s3]) - m);
        unsigned u0 = rt2[(size_t)s0 * 64 + lane];
        unsigned u1 = rt2[(size_t)s1 * 64 + lane];
        unsigned u2 = rt2[(size_t)s2 * 64 + lane];
        unsigned u3 = rt2[(size_t)s3 * 64 + lane];
        wsum += w0 + w1 + w2 + w3;
        h0 += w0 * bflo(u0) + w1 * bflo(u1) + w2 * bflo(u2) + w3 * bflo(u3);
        h1 += w0 * bfhi(u0) + w1 * bfhi(u1) + w2 * bfhi(u2) + w3 * bfhi(u3);
    }
    for (; i < em; ++i) {
        int s = srcs_m[i];
        float w = __expf(lrelu02(ev + e[s]) - m);
        unsigned u = rt2[(size_t)s * 64 + lane];
        wsum += w;
        h0 += w * bflo(u);
        h1 += w * bfhi(u);
    }
    float inv = 1.f / (wsum + 1e-16f);
    unsigned o = (unsigned)f2bf(h0 * inv) | ((unsigned)f2bf(h1 * inv) << 16);
    ((unsigned*)(cat2 + (size_t)v * 256 + 128))[lane] = o;
}

// ---------------- fused heads (LDS-staged weights) ----------------
// All 3 MLP heads + select + sigmoid. 64 rows/block, wave owns 16 rows.
// W1/W2 staged per head into padded LDS (rows of 136 shorts -> 2-way banks);
// layer1->layer2 transpose reuses W1's buffer.
__global__ __launch_bounds__(256) void k_heads(
    const unsigned short* __restrict__ zenc_bf, const unsigned short* __restrict__ rt_bf,
    const unsigned short* __restrict__ W11, const float* __restrict__ b11,
    const unsigned short* __restrict__ W12, const float* __restrict__ b12,
    const float* __restrict__ W13, const float* __restrict__ b13,
    const unsigned short* __restrict__ W01, const float* __restrict__ b01,
    const unsigned short* __restrict__ W02, const float* __restrict__ b02,
    const float* __restrict__ W03, const float* __restrict__ b03,
    const unsigned short* __restrict__ Wd1, const float* __restrict__ bd1,
    const unsigned short* __restrict__ Wd2, const float* __restrict__ bd2,
    const float* __restrict__ Wd3, const float* __restrict__ bd3,
    const int* __restrict__ t, float* __restrict__ out, int M) {
    __shared__ short Wa[128 * 136];   // 34816 B; also hosts the transpose buffer
    __shared__ short Wb[128 * 136];   // 34816 B
    int wave = threadIdx.x >> 6, lane = threadIdx.x & 63;
    int row_base = blockIdx.x * 64 + wave * 16;
    int rA = row_base + (lane & 15);
    if (rA >= M) rA = M - 1;
    int koff = (lane >> 4) << 3;   // in shorts
    int colL = lane & 15;

    bf16x8 za[4], ra[4];
#pragma unroll
    for (int ks = 0; ks < 4; ++ks) {
        za[ks] = *(const bf16x8*)((const short*)zenc_bf + (size_t)rA * 128 + (ks << 5) + koff);
        ra[ks] = *(const bf16x8*)((const short*)rt_bf + (size_t)rA * 128 + (ks << 5) + koff);
    }

    float sp1[4], sp0[4], sdd[4];

    auto stage = [&](const unsigned short* W, short* L) {
        // 128 rows x 128 shorts, in 16B chunks: 2048 chunks / 256 thr = 8 each
        for (int i = threadIdx.x; i < 2048; i += 256) {
            int r = i >> 4, c = (i & 15) << 3;
            bf16x8 v = *(const bf16x8*)((const short*)W + (r << 7) + c);
            *(bf16x8*)(L + r * 136 + c) = v;
        }
    };

    auto run_head = [&](const bf16x8* A0,
                        const unsigned short* W1, const float* b1,
                        const unsigned short* W2, const float* b2,
                        const float* W3, const float* b3, float* sout) {
        __syncthreads();   // previous head's Wa/Wb reads complete
        stage(W1, Wa);
        stage(W2, Wb);
        __syncthreads();
        f32x4 acc[8];
#pragma unroll
        for (int cf = 0; cf < 8; ++cf) acc[cf] = (f32x4){0.f, 0.f, 0.f, 0.f};
#pragma unroll
        for (int ks = 0; ks < 4; ++ks)
#pragma unroll
            for (int cf = 0; cf < 8; ++cf) {
                bf16x8 b = *(const bf16x8*)(Wa + ((cf << 4) + colL) * 136 + (ks << 5) + koff);
                acc[cf] = __builtin_amdgcn_mfma_f32_16x16x32_bf16(A0[ks], b, acc[cf], 0, 0, 0);
            }
        __syncthreads();   // all waves done reading Wa (layer1)
        short* hw = Wa + wave * 2176;   // 16 rows x 136 shorts per wave
#pragma unroll
        for (int cf = 0; cf < 8; ++cf) {
            int col = (cf << 4) + colL;
            float bv = b1[col];
#pragma unroll
            for (int j = 0; j < 4; ++j)
                hw[(((lane >> 4) << 2) + j) * 136 + col] = (short)f2bf(lrelu02(acc[cf][j] + bv));
        }
        __syncthreads();
        bf16x8 h1f[4];
#pragma unroll
        for (int ks = 0; ks < 4; ++ks)
            h1f[ks] = *(const bf16x8*)(hw + colL * 136 + (ks << 5) + koff);
#pragma unroll
        for (int cf = 0; cf < 8; ++cf) acc[cf] = (f32x4){0.f, 0.f, 0.f, 0.f};
#pragma unroll
        for (int ks = 0; ks < 4; ++ks)
#pragma unroll
            for (int cf = 0; cf < 8; ++cf) {
                bf16x8 b = *(const bf16x8*)(Wb + ((cf << 4) + colL) * 136 + (ks << 5) + koff);
                acc[cf] = __builtin_amdgcn_mfma_f32_16x16x32_bf16(h1f[ks], b, acc[cf], 0, 0, 0);
            }
        float s0 = 0.f, s1 = 0.f, s2 = 0.f, s3 = 0.f;
#pragma unroll
        for (int cf = 0; cf < 8; ++cf) {
            int col = (cf << 4) + colL;
            float w3 = W3[col], bv = b2[col];
            s0 += lrelu02(acc[cf][0] + bv) * w3;
            s1 += lrelu02(acc[cf][1] + bv) * w3;
            s2 += lrelu02(acc[cf][2] + bv) * w3;
            s3 += lrelu02(acc[cf][3] + bv) * w3;
        }
#pragma unroll
        for (int mk = 1; mk < 16; mk <<= 1) {
            s0 += __shfl_xor(s0, mk); s1 += __shfl_xor(s1, mk);
            s2 += __shfl_xor(s2, mk); s3 += __shfl_xor(s3, mk);
        }
        float bb = b3[0];
        sout[0] = s0 + bb; sout[1] = s1 + bb; sout[2] = s2 + bb; sout[3] = s3 + bb;
    };

    run_head(za, W11, b11, W12, b12, W13, b13, sp1);
    run_head(za, W01, b01, W02, b02, W03, b03, sp0);
    run_head(ra, Wd1, bd1, Wd2, bd2, Wd3, bd3, sdd);

    if (colL == 0) {
#pragma unroll
        for (int j = 0; j < 4; ++j) {
            int row = row_base + ((lane >> 4) << 2) + j;
            if (row < M) {
                out[row] = 1.f / (1.f + __expf(-sdd[j]));           // pred_t
                out[M + row] = (t[row] > 0) ? sp1[j] : sp0[j];      // pred
            }
        }
    }
}

// ---------------- launcher ----------------

extern "C" void kernel_launch(void* const* d_in, const int* in_sizes, int n_in,
                              void* d_out, int out_size, void* d_ws, size_t ws_size,
                              hipStream_t stream) {
    const float* x     = (const float*)d_in[0];
    const int*   t     = (const int*)d_in[1];
    const int*   ei    = (const int*)d_in[3];
    const float* W_o   = (const float*)d_in[4];
    const float* b_o   = (const float*)d_in[5];
    const float* W_t   = (const float*)d_in[6];
    const float* b_t   = (const float*)d_in[7];
    const float* a_w   = (const float*)d_in[8];
    const float* a_b   = (const float*)d_in[9];
    const float* W_enc = (const float*)d_in[10];
    const float* b_enc = (const float*)d_in[11];
    const float* p1_W1 = (const float*)d_in[12]; const float* p1_b1 = (const float*)d_in[13];
    const float* p1_W2 = (const float*)d_in[14]; const float* p1_b2 = (const float*)d_in[15];
    const float* p1_W3 = (const float*)d_in[16]; const float* p1_b3 = (const float*)d_in[17];
    const float* p0_W1 = (const float*)d_in[18]; const float* p0_b1 = (const float*)d_in[19];
    const float* p0_W2 = (const float*)d_in[20]; const float* p0_b2 = (const float*)d_in[21];
    const float* p0_W3 = (const float*)d_in[22]; const float* p0_b3 = (const float*)d_in[23];
    const float* d_W1  = (const float*)d_in[24]; const float* d_b1  = (const float*)d_in[25];
    const float* d_W2  = (const float*)d_in[26]; const float* d_b2  = (const float*)d_in[27];
    const float* d_W3  = (const float*)d_in[28]; const float* d_b3  = (const float*)d_in[29];

    const int n = in_sizes[1];
    const int E = in_sizes[3] / 2;
    const int* src = ei;
    const int* dst = ei + E;

    float* out  = (float*)d_out;
    float* zenc = out + 2 * (size_t)n;   // output: pred_t[N], pred[N], z_enc[N,128]

    // bucket geometry (dst >> shift), NB <= 256; payload packs src in 20 bits
    int shift = 9;
    while (((n + (1 << shift) - 1) >> shift) > 256) ++shift;
    const int NB = (n + (1 << shift) - 1) >> shift;

    // ---- workspace layout ----
    char* base = (char*)d_ws;
    size_t o = 0;
    auto alloc = [&](size_t bytes) { char* p = base + o; o += (bytes + 255) & ~(size_t)255; return p; };
    unsigned short* x_bf    = (unsigned short*)alloc((size_t)n * 128 * 2);
    unsigned short* xw_bf   = (unsigned short*)alloc((size_t)n * 256 * 2);  // prescaled by dinv
    unsigned short* cat2_bf = (unsigned short*)alloc((size_t)n * 256 * 2);
    unsigned short* rt_bf   = (unsigned short*)alloc((size_t)n * 128 * 2);
    unsigned short* zenc_bf = (unsigned short*)alloc((size_t)n * 128 * 2);
    float* dinv = (float*)alloc((size_t)n * 4);
    float* evec = (float*)alloc((size_t)n * 4);
    unsigned short* Wcat_t = (unsigned short*)alloc(256 * 128 * 2);
    unsigned short* Wenc_t = (unsigned short*)alloc(128 * 256 * 2);
    unsigned short* Wp1a_t = (unsigned short*)alloc(128 * 128 * 2);
    unsigned short* Wp1b_t = (unsigned short*)alloc(128 * 128 * 2);
    unsigned short* Wp0a_t = (unsigned short*)alloc(128 * 128 * 2);
    unsigned short* Wp0b_t = (unsigned short*)alloc(128 * 128 * 2);
    unsigned short* Wda_t  = (unsigned short*)alloc(128 * 128 * 2);
    unsigned short* Wdb_t  = (unsigned short*)alloc(128 * 128 * 2);
    int* counts     = (int*)alloc((size_t)n * 2 * 4);   // [counts | counts_m]
    int* counts_m   = counts + n;
    int* indptr     = (int*)alloc(((size_t)n + 1) * 4);
    int* indptr_m   = (int*)alloc(((size_t)n + 1) * 4);
    int* cursor     = (int*)alloc((size_t)n * 4);
    int* cursor_m   = (int*)alloc((size_t)n * 4);
    int* bsum       = (int*)alloc(257 * 4);
    int* boff       = (int*)alloc(257 * 4);
    int* bsum_m     = (int*)alloc(257 * 4);
    int* boff_m     = (int*)alloc(257 * 4);
    int* bhist      = (int*)alloc(257 * 4);
    int* bbase      = (int*)alloc(257 * 4);
    int* bcur       = (int*)alloc(257 * 4);
    int* src_sorted = (int*)alloc((size_t)E * 4);
    int* src_mask   = (int*)alloc((size_t)E * 4);
    int* ebuf       = (int*)alloc((size_t)E * 4);

    const int nb = (n + 1023) / 1024;
    const int mt = (n + 63) / 64;

    // ---- CSR build (bucketed 2-stage fill) ----
    k_zero_i32<<<256, 256, 0, stream>>>(counts, 2 * n);
    k_zero_i32<<<1, 256, 0, stream>>>(bhist, 257);
    k_count2<<<256, 256, 0, stream>>>(src, dst, t, counts, counts_m, bhist, E, shift);
    k_part<<<nb, 256, 0, stream>>>(counts, bsum, n);
    k_scanb<<<1, 256, 0, stream>>>(bsum, boff, nb);
    k_csr<<<nb, 256, 0, stream>>>(counts, boff, indptr, cursor, dinv, n);
    k_part<<<nb, 256, 0, stream>>>(counts_m, bsum_m, n);
    k_scanb<<<1, 256, 0, stream>>>(bsum_m, boff_m, nb);
    k_csr<<<nb, 256, 0, stream>>>(counts_m, boff_m, indptr_m, cursor_m, nullptr, n);
    k_scanb<<<1, 256, 0, stream>>>(bhist, bbase, NB);
    k_copy_i32<<<1, 256, 0, stream>>>(bbase, bcur, NB);
    k_fillB<<<(E + 4095) / 4096, 256, 0, stream>>>(src, dst, bcur, ebuf, E, shift);
    k_fillC<<<NB, 256, 0, stream>>>(ebuf, bbase, t, cursor, cursor_m, src_sorted, src_mask, shift);

    // ---- prep ----
    k_cvt<<<2048, 256, 0, stream>>>(x, x_bf, n * 32);
    k_wcat_t<<<128, 256, 0, stream>>>(W_o, W_t, Wcat_t);
    k_wt<<<128, 256, 0, stream>>>(W_enc, Wenc_t, 256, 128);
    k_wt<<<64, 256, 0, stream>>>(p1_W1, Wp1a_t, 128, 128);
    k_wt<<<64, 256, 0, stream>>>(p1_W2, Wp1b_t, 128, 128);
    k_wt<<<64, 256, 0, stream>>>(p0_W1, Wp0a_t, 128, 128);
    k_wt<<<64, 256, 0, stream>>>(p0_W2, Wp0b_t, 128, 128);
    k_wt<<<64, 256, 0, stream>>>(d_W1, Wda_t, 128, 128);
    k_wt<<<64, 256, 0, stream>>>(d_W2, Wdb_t, 128, 128);

    // xw = dinv[row] * (x @ [W_o | W_t])   (prescaled, bf16)
    k_bgemm<<<mt * 2, 256, 0, stream>>>(x_bf, Wcat_t, nullptr, dinv, xw_bf, nullptr, n, 128, 256, 0);

    // GCN aggregate (both convs) + relu + bias + e
    k_agg<<<(n + 3) / 4, 256, 0, stream>>>(xw_bf, indptr, src_sorted, dinv, b_o, b_t,
                                           a_w, a_b, cat2_bf, rt_bf, evec, n);
    // attention -> h
    k_attn<<<(n + 3) / 4, 256, 0, stream>>>(rt_bf, indptr, src_sorted, indptr_m, src_mask,
                                            evec, cat2_bf, n);

    // z_enc = cat2 @ W_enc + b_enc
    k_bgemm<<<mt, 256, 0, stream>>>(cat2_bf, Wenc_t, b_enc, nullptr, zenc_bf, zenc, n, 256, 128, 0);

    // fused heads + select + sigmoid
    k_heads<<<mt, 256, 0, stream>>>(zenc_bf, rt_bf,
                                    Wp1a_t, p1_b1, Wp1b_t, p1_b2, p1_W3, p1_b3,
                                    Wp0a_t, p0_b1, Wp0b_t, p0_b2, p0_W3, p0_b3,
                                    Wda_t, d_b1, Wdb_t, d_b2, d_W3, d_b3,
                                    t, out, n);
}

// Round 7
// 608.889 us; speedup vs baseline: 2.5546x; 1.0983x over previous
//
#include <hip/hip_runtime.h>
#include <hip/hip_bf16.h>
#include <math.h>

// ---------------------------------------------------------------------------
// SPNet: GCN(2x) -> masked edge attention -> encoder -> 3 MLP heads
// N=100000, E=1600000, F=H=128.
// Round 6 resubmit (round-6 bench died on infra, same as round 1):
//   - aggregate x (128 cols) instead of xw (256 cols): matmul commutes with
//     segment-sum. Gather bytes/edge halve; table 25.6MB fits aggregate L2.
//     GCN gemm moves after aggregation; epilogue fuses bias+relu+e.
//   - k_attn: masked-only max (alpha invariant to max shift) -> full-CSR
//     pass deleted; unroll 8.
//   - k_aggx: unroll 8 (was 4) for deeper memory pipeline.
// ---------------------------------------------------------------------------

using bf16x8 = __attribute__((ext_vector_type(8))) short;
using f32x4  = __attribute__((ext_vector_type(4))) float;

static __device__ __forceinline__ float lrelu02(float x) { return x > 0.f ? x : 0.2f * x; }

static __device__ __forceinline__ unsigned short f2bf(float f) {
    unsigned u = __float_as_uint(f);
    unsigned r = u + 0x7FFF + ((u >> 16) & 1);   // round-to-nearest-even
    return (unsigned short)(r >> 16);
}
static __device__ __forceinline__ float bf2f(unsigned short h) {
    return __uint_as_float(((unsigned)h) << 16);
}
static __device__ __forceinline__ float bflo(unsigned u) { return __uint_as_float(u << 16); }
static __device__ __forceinline__ float bfhi(unsigned u) { return __uint_as_float(u & 0xFFFF0000u); }

// ---------------- CSR build ----------------

__global__ void k_zero_i32(int* __restrict__ p, int n) {
    int i = blockIdx.x * blockDim.x + threadIdx.x;
    int stride = gridDim.x * blockDim.x;
    for (; i < n; i += stride) p[i] = 0;
}

__global__ void k_copy_i32(const int* __restrict__ a, int* __restrict__ b, int n) {
    int i = blockIdx.x * blockDim.x + threadIdx.x;
    if (i < n) b[i] = a[i];
}

// per-dst counts (full + masked) + per-bucket histogram (LDS-aggregated)
__global__ __launch_bounds__(256) void k_count2(const int* __restrict__ src,
                                                const int* __restrict__ dst,
                                                const int* __restrict__ t,
                                                int* __restrict__ counts,
                                                int* __restrict__ counts_m,
                                                int* __restrict__ bhist,
                                                int e, int shift) {
    __shared__ int h[256];
    h[threadIdx.x] = 0;
    __syncthreads();
    int i = blockIdx.x * blockDim.x + threadIdx.x;
    int stride = gridDim.x * blockDim.x;
    for (; i < e; i += stride) {
        int d = dst[i];
        atomicAdd(&counts[d], 1);
        if (t[src[i]] > 0) atomicAdd(&counts_m[d], 1);
        atomicAdd(&h[d >> shift], 1);
    }
    __syncthreads();
    if (h[threadIdx.x] > 0) atomicAdd(&bhist[threadIdx.x], h[threadIdx.x]);
}

// per-block (1024-element chunk) sum of counts
__global__ __launch_bounds__(256) void k_part(const int* __restrict__ counts,
                                              int* __restrict__ bsum, int n) {
    __shared__ int red[256];
    int b = blockIdx.x, t = threadIdx.x;
    int base = b * 1024 + t * 4;
    int s = 0;
#pragma unroll
    for (int j = 0; j < 4; ++j) {
        int i = base + j;
        if (i < n) s += counts[i];
    }
    red[t] = s;
    __syncthreads();
    for (int off = 128; off; off >>= 1) {
        if (t < off) red[t] += red[t + off];
        __syncthreads();
    }
    if (t == 0) bsum[b] = red[0];
}

// exclusive scan of <=256 values; also writes boff[nb] = total
__global__ __launch_bounds__(256) void k_scanb(const int* __restrict__ bsum,
                                               int* __restrict__ boff, int nb) {
    __shared__ int s[256];
    int t = threadIdx.x;
    int v = (t < nb) ? bsum[t] : 0;
    s[t] = v;
    __syncthreads();
    for (int off = 1; off < 256; off <<= 1) {
        int u = (t >= off) ? s[t - off] : 0;
        __syncthreads();
        s[t] += u;
        __syncthreads();
    }
    if (t < nb) boff[t] = s[t] - v;
    if (t == nb - 1) boff[nb] = s[t];
}

// per-block local exclusive scan + global base -> indptr/cursor (+dinv if non-null)
__global__ __launch_bounds__(256) void k_csr(const int* __restrict__ counts,
                                             const int* __restrict__ boff,
                                             int* __restrict__ indptr,
                                             int* __restrict__ cursor,
                                             float* __restrict__ dinv, int n) {
    __shared__ int tsum[256];
    int b = blockIdx.x, t = threadIdx.x;
    int base = b * 1024 + t * 4;
    int c[4];
    int s = 0;
#pragma unroll
    for (int j = 0; j < 4; ++j) {
        int i = base + j;
        c[j] = (i < n) ? counts[i] : 0;
        s += c[j];
    }
    tsum[t] = s;
    __syncthreads();
    for (int off = 1; off < 256; off <<= 1) {
        int u = (t >= off) ? tsum[t - off] : 0;
        __syncthreads();
        tsum[t] += u;
        __syncthreads();
    }
    int pre = boff[b] + tsum[t] - s;
#pragma unroll
    for (int j = 0; j < 4; ++j) {
        int i = base + j;
        if (i < n) {
            indptr[i] = pre;
            cursor[i] = pre;
            if (dinv) dinv[i] = rsqrtf((float)c[j] + 1.0f);  // self-loop adds 1
            pre += c[j];
            if (i == n - 1) indptr[n] = pre;
        }
    }
}

// pass B: partition edges into dst-buckets; payload = src | (dst_lo << 20)
__global__ __launch_bounds__(256) void k_fillB(const int* __restrict__ src,
                                               const int* __restrict__ dst,
                                               int* __restrict__ bcur,
                                               int* __restrict__ ebuf,
                                               int e, int shift) {
    __shared__ int h[256];
    const int EPT = 16;
    int blk_base = blockIdx.x * 256 * EPT;
    h[threadIdx.x] = 0;
    __syncthreads();
    int pk[EPT], bk[EPT];
#pragma unroll
    for (int j = 0; j < EPT; ++j) {
        int i = blk_base + threadIdx.x + j * 256;
        if (i < e) {
            int s = src[i], d = dst[i];
            int b = d >> shift;
            bk[j] = b;
            pk[j] = s | ((d - (b << shift)) << 20);
            atomicAdd(&h[b], 1);
        } else bk[j] = -1;
    }
    __syncthreads();
    int cnt = h[threadIdx.x];
    int base = 0;
    if (cnt > 0) base = atomicAdd(&bcur[threadIdx.x], cnt);
    __syncthreads();
    h[threadIdx.x] = base;
    __syncthreads();
#pragma unroll
    for (int j = 0; j < EPT; ++j) {
        if (bk[j] >= 0) {
            int pos = atomicAdd(&h[bk[j]], 1);
            ebuf[pos] = pk[j];
        }
    }
}

// pass C: one block per bucket; scatter within L2-resident output slice
__global__ __launch_bounds__(256) void k_fillC(const int* __restrict__ ebuf,
                                               const int* __restrict__ bbase,
                                               const int* __restrict__ t,
                                               int* __restrict__ cursor,
                                               int* __restrict__ cursor_m,
                                               int* __restrict__ out_all,
                                               int* __restrict__ out_m, int shift) {
    int b = blockIdx.x;
    int lo = bbase[b], hi = bbase[b + 1];
    int dbase = b << shift;
    for (int i = lo + threadIdx.x; i < hi; i += 256) {
        int pk = ebuf[i];
        int s = pk & 0xFFFFF;
        int d = dbase + (pk >> 20);
        int pos = atomicAdd(&cursor[d], 1);
        out_all[pos] = s;
        if (t[s] > 0) {
            int pm = atomicAdd(&cursor_m[d], 1);
            out_m[pm] = s;
        }
    }
}

// ---------------- prep ----------------

// x fp32 -> x_pre bf16 = dinv[row] * x   (128 cols; float4 chunk i -> row i>>5)
__global__ void k_cvt_pre(const float* __restrict__ x, const float* __restrict__ dinv,
                          unsigned short* __restrict__ xp, int total4) {
    int i = blockIdx.x * blockDim.x + threadIdx.x;
    int stride = gridDim.x * blockDim.x;
    for (; i < total4; i += stride) {
        float dv = dinv[i >> 5];
        float4 v = ((const float4*)x)[i];
        ushort4 o;
        o.x = f2bf(v.x * dv); o.y = f2bf(v.y * dv);
        o.z = f2bf(v.z * dv); o.w = f2bf(v.w * dv);
        ((ushort4*)xp)[i] = o;
    }
}

// W[K][Nc] fp32 -> Wt[Nc][K] bf16
__global__ void k_wt(const float* __restrict__ W, unsigned short* __restrict__ Wt,
                     int K, int Nc) {
    int i = blockIdx.x * blockDim.x + threadIdx.x;
    if (i >= K * Nc) return;
    int k = i / Nc, j = i % Nc;
    Wt[(size_t)j * K + k] = f2bf(W[i]);
}

// Wcat_t[j][k] = j<128 ? W_o[k][j] : W_t[k][j-128]   ([256][128] bf16)
__global__ void k_wcat_t(const float* __restrict__ Wo, const float* __restrict__ Wt_in,
                         unsigned short* __restrict__ Wt) {
    int i = blockIdx.x * blockDim.x + threadIdx.x;
    if (i >= 256 * 128) return;
    int j = i >> 7, k = i & 127;
    float v = (j < 128) ? Wo[(k << 7) + j] : Wt_in[(k << 7) + j - 128];
    Wt[i] = f2bf(v);
}

// ---------------- graph: aggregate x_pre ----------------
// aggx[v] = dinv[v] * (sum_{s in N(v)} x_pre[s] + x_pre[v]),  x_pre = dinv*x.
// One wave per node; lane owns 2 of 128 cols (4B); unroll 8.
__global__ __launch_bounds__(256) void k_aggx(const unsigned short* __restrict__ xp,
                                              const int* __restrict__ indptr,
                                              const int* __restrict__ srcs,
                                              const float* __restrict__ dinv,
                                              unsigned short* __restrict__ aggx, int n) {
    int wv = threadIdx.x >> 6, lane = threadIdx.x & 63;
    int v = blockIdx.x * 4 + wv;
    if (v >= n) return;
    const unsigned* xp2 = (const unsigned*)xp;
    int beg = indptr[v], end = indptr[v + 1];
    unsigned sv = xp2[(size_t)v * 64 + lane];
    float a0 = bflo(sv), a1 = bfhi(sv);
    int i = beg;
    for (; i + 8 <= end; i += 8) {
        int s0 = srcs[i], s1 = srcs[i + 1], s2 = srcs[i + 2], s3 = srcs[i + 3];
        int s4 = srcs[i + 4], s5 = srcs[i + 5], s6 = srcs[i + 6], s7 = srcs[i + 7];
        unsigned u0 = xp2[(size_t)s0 * 64 + lane];
        unsigned u1 = xp2[(size_t)s1 * 64 + lane];
        unsigned u2 = xp2[(size_t)s2 * 64 + lane];
        unsigned u3 = xp2[(size_t)s3 * 64 + lane];
        unsigned u4 = xp2[(size_t)s4 * 64 + lane];
        unsigned u5 = xp2[(size_t)s5 * 64 + lane];
        unsigned u6 = xp2[(size_t)s6 * 64 + lane];
        unsigned u7 = xp2[(size_t)s7 * 64 + lane];
        a0 += bflo(u0) + bflo(u1) + bflo(u2) + bflo(u3)
            + bflo(u4) + bflo(u5) + bflo(u6) + bflo(u7);
        a1 += bfhi(u0) + bfhi(u1) + bfhi(u2) + bfhi(u3)
            + bfhi(u4) + bfhi(u5) + bfhi(u6) + bfhi(u7);
    }
    for (; i + 4 <= end; i += 4) {
        int s0 = srcs[i], s1 = srcs[i + 1], s2 = srcs[i + 2], s3 = srcs[i + 3];
        unsigned u0 = xp2[(size_t)s0 * 64 + lane];
        unsigned u1 = xp2[(size_t)s1 * 64 + lane];
        unsigned u2 = xp2[(size_t)s2 * 64 + lane];
        unsigned u3 = xp2[(size_t)s3 * 64 + lane];
        a0 += bflo(u0) + bflo(u1) + bflo(u2) + bflo(u3);
        a1 += bfhi(u0) + bfhi(u1) + bfhi(u2) + bfhi(u3);
    }
    for (; i < end; ++i) {
        unsigned u = xp2[(size_t)srcs[i] * 64 + lane];
        a0 += bflo(u); a1 += bfhi(u);
    }
    float dv = dinv[v];
    a0 *= dv; a1 *= dv;
    unsigned o = (unsigned)f2bf(a0) | ((unsigned)f2bf(a1) << 16);
    ((unsigned*)aggx)[(size_t)v * 64 + lane] = o;
}

// ---------------- GCN gemm: [r_o|r_t] = relu(aggx @ Wcat + [b_o|b_t]), e fused
// 256 thr = 4 waves; 64 rows x 256 cols per block; wave owns 16 rows.
__global__ __launch_bounds__(256) void k_gcn(const unsigned short* __restrict__ aggx,
                                             const unsigned short* __restrict__ Wcat,
                                             const float* __restrict__ b_o,
                                             const float* __restrict__ b_t,
                                             const float* __restrict__ a_w,
                                             const float* __restrict__ a_b,
                                             unsigned short* __restrict__ cat2,
                                             unsigned short* __restrict__ rt,
                                             float* __restrict__ e, int M) {
    int wave = threadIdx.x >> 6, lane = threadIdx.x & 63;
    int row_base = blockIdx.x * 64 + wave * 16;
    int rA = row_base + (lane & 15);
    if (rA >= M) rA = M - 1;
    int koff = (lane >> 4) << 3;
    int colL = lane & 15;

    bf16x8 a[4];
#pragma unroll
    for (int ks = 0; ks < 4; ++ks)
        a[ks] = *(const bf16x8*)((const short*)aggx + (size_t)rA * 128 + (ks << 5) + koff);

    f32x4 acc[16];
#pragma unroll
    for (int cf = 0; cf < 16; ++cf) acc[cf] = (f32x4){0.f, 0.f, 0.f, 0.f};
#pragma unroll
    for (int ks = 0; ks < 4; ++ks)
#pragma unroll
        for (int cf = 0; cf < 16; ++cf) {
            bf16x8 b = *(const bf16x8*)((const short*)Wcat + (size_t)((cf << 4) + colL) * 128 + (ks << 5) + koff);
            acc[cf] = __builtin_amdgcn_mfma_f32_16x16x32_bf16(a[ks], b, acc[cf], 0, 0, 0);
        }

    float ep0 = 0.f, ep1 = 0.f, ep2 = 0.f, ep3 = 0.f;
#pragma unroll
    for (int cf = 0; cf < 16; ++cf) {
        int col = (cf << 4) + colL;
        float bv = (col < 128) ? b_o[col] : b_t[col - 128];
        float aw = a_w[col];
#pragma unroll
        for (int j = 0; j < 4; ++j) {
            int row = row_base + ((lane >> 4) << 2) + j;
            float v = fmaxf(acc[cf][j] + bv, 0.f);
            if (j == 0) ep0 += v * aw;
            else if (j == 1) ep1 += v * aw;
            else if (j == 2) ep2 += v * aw;
            else ep3 += v * aw;
            if (row < M) {
                if (col < 128) cat2[(size_t)row * 256 + col] = f2bf(v);
                else rt[(size_t)row * 128 + col - 128] = f2bf(v);
            }
        }
    }
#pragma unroll
    for (int mk = 1; mk < 16; mk <<= 1) {
        ep0 += __shfl_xor(ep0, mk); ep1 += __shfl_xor(ep1, mk);
        ep2 += __shfl_xor(ep2, mk); ep3 += __shfl_xor(ep3, mk);
    }
    if (colL == 0) {
        float ab = a_b[0];
        int r0 = row_base + ((lane >> 4) << 2);
        if (r0 + 0 < M) e[r0 + 0] = ep0 + ab;
        if (r0 + 1 < M) e[r0 + 1] = ep1 + ab;
        if (r0 + 2 < M) e[r0 + 2] = ep2 + ab;
        if (r0 + 3 < M) e[r0 + 3] = ep3 + ab;
    }
}

// ---------------- masked attention (masked CSR only; max shift cancels) ----
__global__ __launch_bounds__(256) void k_attn(const unsigned short* __restrict__ rt,
                                              const int* __restrict__ indptr_m,
                                              const int* __restrict__ srcs_m,
                                              const float* __restrict__ e,
                                              unsigned short* __restrict__ cat2, int n) {
    int wv = threadIdx.x >> 6, lane = threadIdx.x & 63;
    int v = blockIdx.x * 4 + wv;
    if (v >= n) return;
    float ev = e[v];
    int bm = indptr_m[v], em = indptr_m[v + 1];
    // masked max (lane-parallel)
    float m = -INFINITY;
    for (int i = bm + lane; i < em; i += 64)
        m = fmaxf(m, lrelu02(ev + e[srcs_m[i]]));
    for (int off = 32; off; off >>= 1) m = fmaxf(m, __shfl_xor(m, off));
    if (bm == em) m = 0.f;
    // weighted gather, unroll 8
    float h0 = 0.f, h1 = 0.f, wsum = 0.f;
    const unsigned* rt2 = (const unsigned*)rt;
    int i = bm;
    for (; i + 8 <= em; i += 8) {
        int s0 = srcs_m[i], s1 = srcs_m[i + 1], s2 = srcs_m[i + 2], s3 = srcs_m[i + 3];
        int s4 = srcs_m[i + 4], s5 = srcs_m[i + 5], s6 = srcs_m[i + 6], s7 = srcs_m[i + 7];
        float w0 = __expf(lrelu02(ev + e[s0]) - m);
        float w1 = __expf(lrelu02(ev + e[s1]) - m);
        float w2 = __expf(lrelu02(ev + e[s2]) - m);
        float w3 = __expf(lrelu02(ev + e[s3]) - m);
        float w4 = __expf(lrelu02(ev + e[s4]) - m);
        float w5 = __expf(lrelu02(ev + e[s5]) - m);
        float w6 = __expf(lrelu02(ev + e[s6]) - m);
        float w7 = __expf(lrelu02(ev + e[s7]) - m);
        unsigned u0 = rt2[(size_t)s0 * 64 + lane];
        unsigned u1 = rt2[(size_t)s1 * 64 + lane];
        unsigned u2 = rt2[(size_t)s2 * 64 + lane];
        unsigned u3 = rt2[(size_t)s3 * 64 + lane];
        unsigned u4 = rt2[(size_t)s4 * 64 + lane];
        unsigned u5 = rt2[(size_t)s5 * 64 + lane];
        unsigned u6 = rt2[(size_t)s6 * 64 + lane];
        unsigned u7 = rt2[(size_t)s7 * 64 + lane];
        wsum += w0 + w1 + w2 + w3 + w4 + w5 + w6 + w7;
        h0 += w0 * bflo(u0) + w1 * bflo(u1) + w2 * bflo(u2) + w3 * bflo(u3)
            + w4 * bflo(u4) + w5 * bflo(u5) + w6 * bflo(u6) + w7 * bflo(u7);
        h1 += w0 * bfhi(u0) + w1 * bfhi(u1) + w2 * bfhi(u2) + w3 * bfhi(u3)
            + w4 * bfhi(u4) + w5 * bfhi(u5) + w6 * bfhi(u6) + w7 * bfhi(u7);
    }
    for (; i < em; ++i) {
        int s = srcs_m[i];
        float w = __expf(lrelu02(ev + e[s]) - m);
        unsigned u = rt2[(size_t)s * 64 + lane];
        wsum += w;
        h0 += w * bflo(u);
        h1 += w * bfhi(u);
    }
    float inv = 1.f / (wsum + 1e-16f);
    unsigned o = (unsigned)f2bf(h0 * inv) | ((unsigned)f2bf(h1 * inv) << 16);
    ((unsigned*)(cat2 + (size_t)v * 256 + 128))[lane] = o;
}

// ---------------- bf16 MFMA GEMM (for z_enc) ----------------
__global__ __launch_bounds__(256) void k_bgemm(const unsigned short* __restrict__ A,
                                               const unsigned short* __restrict__ Wt,
                                               const float* __restrict__ bias,
                                               unsigned short* __restrict__ outb,
                                               float* __restrict__ outf,
                                               int M, int K, int Ncols) {
    int nct = Ncols >> 7;
    int mtile = blockIdx.x / nct;
    int col0 = (blockIdx.x % nct) << 7;
    int wave = threadIdx.x >> 6, lane = threadIdx.x & 63;
    int row_base = mtile * 64 + wave * 16;

    int rA = row_base + (lane & 15);
    if (rA >= M) rA = M - 1;
    const short* Ap = (const short*)A + (size_t)rA * K + ((lane >> 4) << 3);
    const short* Bp = (const short*)Wt + (size_t)(col0 + (lane & 15)) * K + ((lane >> 4) << 3);

    f32x4 acc[8];
#pragma unroll
    for (int cf = 0; cf < 8; ++cf) acc[cf] = (f32x4){0.f, 0.f, 0.f, 0.f};

    int nks = K >> 5;
    for (int ks = 0; ks < nks; ++ks) {
        bf16x8 a = *(const bf16x8*)(Ap + (ks << 5));
#pragma unroll
        for (int cf = 0; cf < 8; ++cf) {
            bf16x8 b = *(const bf16x8*)(Bp + (size_t)(cf << 4) * K + (ks << 5));
            acc[cf] = __builtin_amdgcn_mfma_f32_16x16x32_bf16(a, b, acc[cf], 0, 0, 0);
        }
    }

#pragma unroll
    for (int cf = 0; cf < 8; ++cf) {
        int col = col0 + (cf << 4) + (lane & 15);
        float bv = bias ? bias[col] : 0.f;
#pragma unroll
        for (int j = 0; j < 4; ++j) {
            int row = row_base + ((lane >> 4) << 2) + j;
            if (row >= M) continue;
            float v = acc[cf][j] + bv;
            if (outb) outb[(size_t)row * Ncols + col] = f2bf(v);
            if (outf) outf[(size_t)row * Ncols + col] = v;
        }
    }
}

// ---------------- fused heads (LDS-staged weights) ----------------
__global__ __launch_bounds__(256) void k_heads(
    const unsigned short* __restrict__ zenc_bf, const unsigned short* __restrict__ rt_bf,
    const unsigned short* __restrict__ W11, const float* __restrict__ b11,
    const unsigned short* __restrict__ W12, const float* __restrict__ b12,
    const float* __restrict__ W13, const float* __restrict__ b13,
    const unsigned short* __restrict__ W01, const float* __restrict__ b01,
    const unsigned short* __restrict__ W02, const float* __restrict__ b02,
    const float* __restrict__ W03, const float* __restrict__ b03,
    const unsigned short* __restrict__ Wd1, const float* __restrict__ bd1,
    const unsigned short* __restrict__ Wd2, const float* __restrict__ bd2,
    const float* __restrict__ Wd3, const float* __restrict__ bd3,
    const int* __restrict__ t, float* __restrict__ out, int M) {
    __shared__ short Wa[128 * 136];
    __shared__ short Wb[128 * 136];
    int wave = threadIdx.x >> 6, lane = threadIdx.x & 63;
    int row_base = blockIdx.x * 64 + wave * 16;
    int rA = row_base + (lane & 15);
    if (rA >= M) rA = M - 1;
    int koff = (lane >> 4) << 3;
    int colL = lane & 15;

    bf16x8 za[4], ra[4];
#pragma unroll
    for (int ks = 0; ks < 4; ++ks) {
        za[ks] = *(const bf16x8*)((const short*)zenc_bf + (size_t)rA * 128 + (ks << 5) + koff);
        ra[ks] = *(const bf16x8*)((const short*)rt_bf + (size_t)rA * 128 + (ks << 5) + koff);
    }

    float sp1[4], sp0[4], sdd[4];

    auto stage = [&](const unsigned short* W, short* L) {
        for (int i = threadIdx.x; i < 2048; i += 256) {
            int r = i >> 4, c = (i & 15) << 3;
            bf16x8 v = *(const bf16x8*)((const short*)W + (r << 7) + c);
            *(bf16x8*)(L + r * 136 + c) = v;
        }
    };

    auto run_head = [&](const bf16x8* A0,
                        const unsigned short* W1, const float* b1,
                        const unsigned short* W2, const float* b2,
                        const float* W3, const float* b3, float* sout) {
        __syncthreads();
        stage(W1, Wa);
        stage(W2, Wb);
        __syncthreads();
        f32x4 acc[8];
#pragma unroll
        for (int cf = 0; cf < 8; ++cf) acc[cf] = (f32x4){0.f, 0.f, 0.f, 0.f};
#pragma unroll
        for (int ks = 0; ks < 4; ++ks)
#pragma unroll
            for (int cf = 0; cf < 8; ++cf) {
                bf16x8 b = *(const bf16x8*)(Wa + ((cf << 4) + colL) * 136 + (ks << 5) + koff);
                acc[cf] = __builtin_amdgcn_mfma_f32_16x16x32_bf16(A0[ks], b, acc[cf], 0, 0, 0);
            }
        __syncthreads();
        short* hw = Wa + wave * 2176;
#pragma unroll
        for (int cf = 0; cf < 8; ++cf) {
            int col = (cf << 4) + colL;
            float bv = b1[col];
#pragma unroll
            for (int j = 0; j < 4; ++j)
                hw[(((lane >> 4) << 2) + j) * 136 + col] = (short)f2bf(lrelu02(acc[cf][j] + bv));
        }
        __syncthreads();
        bf16x8 h1f[4];
#pragma unroll
        for (int ks = 0; ks < 4; ++ks)
            h1f[ks] = *(const bf16x8*)(hw + colL * 136 + (ks << 5) + koff);
#pragma unroll
        for (int cf = 0; cf < 8; ++cf) acc[cf] = (f32x4){0.f, 0.f, 0.f, 0.f};
#pragma unroll
        for (int ks = 0; ks < 4; ++ks)
#pragma unroll
            for (int cf = 0; cf < 8; ++cf) {
                bf16x8 b = *(const bf16x8*)(Wb + ((cf << 4) + colL) * 136 + (ks << 5) + koff);
                acc[cf] = __builtin_amdgcn_mfma_f32_16x16x32_bf16(h1f[ks], b, acc[cf], 0, 0, 0);
            }
        float s0 = 0.f, s1 = 0.f, s2 = 0.f, s3 = 0.f;
#pragma unroll
        for (int cf = 0; cf < 8; ++cf) {
            int col = (cf << 4) + colL;
            float w3 = W3[col], bv = b2[col];
            s0 += lrelu02(acc[cf][0] + bv) * w3;
            s1 += lrelu02(acc[cf][1] + bv) * w3;
            s2 += lrelu02(acc[cf][2] + bv) * w3;
            s3 += lrelu02(acc[cf][3] + bv) * w3;
        }
#pragma unroll
        for (int mk = 1; mk < 16; mk <<= 1) {
            s0 += __shfl_xor(s0, mk); s1 += __shfl_xor(s1, mk);
            s2 += __shfl_xor(s2, mk); s3 += __shfl_xor(s3, mk);
        }
        float bb = b3[0];
        sout[0] = s0 + bb; sout[1] = s1 + bb; sout[2] = s2 + bb; sout[3] = s3 + bb;
    };

    run_head(za, W11, b11, W12, b12, W13, b13, sp1);
    run_head(za, W01, b01, W02, b02, W03, b03, sp0);
    run_head(ra, Wd1, bd1, Wd2, bd2, Wd3, bd3, sdd);

    if (colL == 0) {
#pragma unroll
        for (int j = 0; j < 4; ++j) {
            int row = row_base + ((lane >> 4) << 2) + j;
            if (row < M) {
                out[row] = 1.f / (1.f + __expf(-sdd[j]));           // pred_t
                out[M + row] = (t[row] > 0) ? sp1[j] : sp0[j];      // pred
            }
        }
    }
}

// ---------------- launcher ----------------

extern "C" void kernel_launch(void* const* d_in, const int* in_sizes, int n_in,
                              void* d_out, int out_size, void* d_ws, size_t ws_size,
                              hipStream_t stream) {
    const float* x     = (const float*)d_in[0];
    const int*   t     = (const int*)d_in[1];
    const int*   ei    = (const int*)d_in[3];
    const float* W_o   = (const float*)d_in[4];
    const float* b_o   = (const float*)d_in[5];
    const float* W_t   = (const float*)d_in[6];
    const float* b_t   = (const float*)d_in[7];
    const float* a_w   = (const float*)d_in[8];
    const float* a_b   = (const float*)d_in[9];
    const float* W_enc = (const float*)d_in[10];
    const float* b_enc = (const float*)d_in[11];
    const float* p1_W1 = (const float*)d_in[12]; const float* p1_b1 = (const float*)d_in[13];
    const float* p1_W2 = (const float*)d_in[14]; const float* p1_b2 = (const float*)d_in[15];
    const float* p1_W3 = (const float*)d_in[16]; const float* p1_b3 = (const float*)d_in[17];
    const float* p0_W1 = (const float*)d_in[18]; const float* p0_b1 = (const float*)d_in[19];
    const float* p0_W2 = (const float*)d_in[20]; const float* p0_b2 = (const float*)d_in[21];
    const float* p0_W3 = (const float*)d_in[22]; const float* p0_b3 = (const float*)d_in[23];
    const float* d_W1  = (const float*)d_in[24]; const float* d_b1  = (const float*)d_in[25];
    const float* d_W2  = (const float*)d_in[26]; const float* d_b2  = (const float*)d_in[27];
    const float* d_W3  = (const float*)d_in[28]; const float* d_b3  = (const float*)d_in[29];

    const int n = in_sizes[1];
    const int E = in_sizes[3] / 2;
    const int* src = ei;
    const int* dst = ei + E;

    float* out  = (float*)d_out;
    float* zenc = out + 2 * (size_t)n;   // output: pred_t[N], pred[N], z_enc[N,128]

    int shift = 9;
    while (((n + (1 << shift) - 1) >> shift) > 256) ++shift;
    const int NB = (n + (1 << shift) - 1) >> shift;

    // ---- workspace layout ----
    char* base = (char*)d_ws;
    size_t o = 0;
    auto alloc = [&](size_t bytes) { char* p = base + o; o += (bytes + 255) & ~(size_t)255; return p; };
    unsigned short* xp_bf   = (unsigned short*)alloc((size_t)n * 128 * 2);  // dinv*x
    unsigned short* aggx_bf = (unsigned short*)alloc((size_t)n * 128 * 2);
    unsigned short* cat2_bf = (unsigned short*)alloc((size_t)n * 256 * 2);
    unsigned short* rt_bf   = (unsigned short*)alloc((size_t)n * 128 * 2);
    unsigned short* zenc_bf = (unsigned short*)alloc((size_t)n * 128 * 2);
    float* dinv = (float*)alloc((size_t)n * 4);
    float* evec = (float*)alloc((size_t)n * 4);
    unsigned short* Wcat_t = (unsigned short*)alloc(256 * 128 * 2);
    unsigned short* Wenc_t = (unsigned short*)alloc(128 * 256 * 2);
    unsigned short* Wp1a_t = (unsigned short*)alloc(128 * 128 * 2);
    unsigned short* Wp1b_t = (unsigned short*)alloc(128 * 128 * 2);
    unsigned short* Wp0a_t = (unsigned short*)alloc(128 * 128 * 2);
    unsigned short* Wp0b_t = (unsigned short*)alloc(128 * 128 * 2);
    unsigned short* Wda_t  = (unsigned short*)alloc(128 * 128 * 2);
    unsigned short* Wdb_t  = (unsigned short*)alloc(128 * 128 * 2);
    int* counts     = (int*)alloc((size_t)n * 2 * 4);
    int* counts_m   = counts + n;
    int* indptr     = (int*)alloc(((size_t)n + 1) * 4);
    int* indptr_m   = (int*)alloc(((size_t)n + 1) * 4);
    int* cursor     = (int*)alloc((size_t)n * 4);
    int* cursor_m   = (int*)alloc((size_t)n * 4);
    int* bsum       = (int*)alloc(257 * 4);
    int* boff       = (int*)alloc(257 * 4);
    int* bsum_m     = (int*)alloc(257 * 4);
    int* boff_m     = (int*)alloc(257 * 4);
    int* bhist      = (int*)alloc(257 * 4);
    int* bbase      = (int*)alloc(257 * 4);
    int* bcur       = (int*)alloc(257 * 4);
    int* src_sorted = (int*)alloc((size_t)E * 4);
    int* src_mask   = (int*)alloc((size_t)E * 4);
    int* ebuf       = (int*)alloc((size_t)E * 4);

    const int nb = (n + 1023) / 1024;
    const int mt = (n + 63) / 64;

    // ---- CSR build (bucketed 2-stage fill) ----
    k_zero_i32<<<256, 256, 0, stream>>>(counts, 2 * n);
    k_zero_i32<<<1, 256, 0, stream>>>(bhist, 257);
    k_count2<<<256, 256, 0, stream>>>(src, dst, t, counts, counts_m, bhist, E, shift);
    k_part<<<nb, 256, 0, stream>>>(counts, bsum, n);
    k_scanb<<<1, 256, 0, stream>>>(bsum, boff, nb);
    k_csr<<<nb, 256, 0, stream>>>(counts, boff, indptr, cursor, dinv, n);
    k_part<<<nb, 256, 0, stream>>>(counts_m, bsum_m, n);
    k_scanb<<<1, 256, 0, stream>>>(bsum_m, boff_m, nb);
    k_csr<<<nb, 256, 0, stream>>>(counts_m, boff_m, indptr_m, cursor_m, nullptr, n);
    k_scanb<<<1, 256, 0, stream>>>(bhist, bbase, NB);
    k_copy_i32<<<1, 256, 0, stream>>>(bbase, bcur, NB);
    k_fillB<<<(E + 4095) / 4096, 256, 0, stream>>>(src, dst, bcur, ebuf, E, shift);
    k_fillC<<<NB, 256, 0, stream>>>(ebuf, bbase, t, cursor, cursor_m, src_sorted, src_mask, shift);

    // ---- prep ----
    k_cvt_pre<<<2048, 256, 0, stream>>>(x, dinv, xp_bf, n * 32);
    k_wcat_t<<<128, 256, 0, stream>>>(W_o, W_t, Wcat_t);
    k_wt<<<128, 256, 0, stream>>>(W_enc, Wenc_t, 256, 128);
    k_wt<<<64, 256, 0, stream>>>(p1_W1, Wp1a_t, 128, 128);
    k_wt<<<64, 256, 0, stream>>>(p1_W2, Wp1b_t, 128, 128);
    k_wt<<<64, 256, 0, stream>>>(p0_W1, Wp0a_t, 128, 128);
    k_wt<<<64, 256, 0, stream>>>(p0_W2, Wp0b_t, 128, 128);
    k_wt<<<64, 256, 0, stream>>>(d_W1, Wda_t, 128, 128);
    k_wt<<<64, 256, 0, stream>>>(d_W2, Wdb_t, 128, 128);

    // aggregate prescaled x over full CSR
    k_aggx<<<(n + 3) / 4, 256, 0, stream>>>(xp_bf, indptr, src_sorted, dinv, aggx_bf, n);

    // [r_o|r_t] = relu(aggx @ Wcat + bias); e fused
    k_gcn<<<mt, 256, 0, stream>>>(aggx_bf, Wcat_t, b_o, b_t, a_w, a_b,
                                  cat2_bf, rt_bf, evec, n);

    // attention -> h (masked CSR only)
    k_attn<<<(n + 3) / 4, 256, 0, stream>>>(rt_bf, indptr_m, src_mask, evec, cat2_bf, n);

    // z_enc = cat2 @ W_enc + b_enc
    k_bgemm<<<mt, 256, 0, stream>>>(cat2_bf, Wenc_t, b_enc, zenc_bf, zenc, n, 256, 128);

    // fused heads + select + sigmoid
    k_heads<<<mt, 256, 0, stream>>>(zenc_bf, rt_bf,
                                    Wp1a_t, p1_b1, Wp1b_t, p1_b2, p1_W3, p1_b3,
                                    Wp0a_t, p0_b1, Wp0b_t, p0_b2, p0_W3, p0_b3,
                                    Wda_t, d_b1, Wdb_t, d_b2, d_W3, d_b3,
                                    t, out, n);
}

// Round 9
// 495.236 us; speedup vs baseline: 3.1408x; 1.2295x over previous
//
#include <hip/hip_runtime.h>
#include <hip/hip_bf16.h>
#include <math.h>

// ---------------------------------------------------------------------------
// SPNet: GCN(2x) -> masked edge attention -> encoder -> 3 MLP heads
// N=100000, E=1600000, F=H=128.
// Round 8 resubmit (round-8 bench died on infra, same signature as r1/r6):
//   - CSR build without per-dst global atomics (k_count2 was 101us at 9.9%
//     occupancy, 75MB atomic write-amp): bucket-local LDS counting sort.
//     k_bhist (256-bin LDS hist) -> k_fillB (partition, t-bit packed) ->
//     k_sortC (per-bucket LDS count+scan+scatter -> indptr/indptr_m/dinv/
//     src lists). Replaces 7 dispatches with 3.
//   - everything else unchanged from round 6/7.
// Requires: n <= 2^20 (src packed in 20 bits), bucket = 512 dst ids (shift 9).
// ---------------------------------------------------------------------------

using bf16x8 = __attribute__((ext_vector_type(8))) short;
using f32x4  = __attribute__((ext_vector_type(4))) float;

static __device__ __forceinline__ float lrelu02(float x) { return x > 0.f ? x : 0.2f * x; }

static __device__ __forceinline__ unsigned short f2bf(float f) {
    unsigned u = __float_as_uint(f);
    unsigned r = u + 0x7FFF + ((u >> 16) & 1);   // round-to-nearest-even
    return (unsigned short)(r >> 16);
}
static __device__ __forceinline__ float bf2f(unsigned short h) {
    return __uint_as_float(((unsigned)h) << 16);
}
static __device__ __forceinline__ float bflo(unsigned u) { return __uint_as_float(u << 16); }
static __device__ __forceinline__ float bfhi(unsigned u) { return __uint_as_float(u & 0xFFFF0000u); }

// ---------------- CSR build ----------------

__global__ void k_zero_i32(int* __restrict__ p, int n) {
    int i = blockIdx.x * blockDim.x + threadIdx.x;
    int stride = gridDim.x * blockDim.x;
    for (; i < n; i += stride) p[i] = 0;
}

__global__ void k_copy_i32(const int* __restrict__ a, int* __restrict__ b, int n) {
    int i = blockIdx.x * blockDim.x + threadIdx.x;
    if (i < n) b[i] = a[i];
}

// bucket histograms only (256 bins, LDS-aggregated) — no per-dst atomics
__global__ __launch_bounds__(256) void k_bhist(const int* __restrict__ src,
                                               const int* __restrict__ dst,
                                               const int* __restrict__ t,
                                               int* __restrict__ bhist,
                                               int* __restrict__ bhist_m,
                                               int e, int shift) {
    __shared__ int h[256], hm[256];
    h[threadIdx.x] = 0; hm[threadIdx.x] = 0;
    __syncthreads();
    int i = blockIdx.x * blockDim.x + threadIdx.x;
    int stride = gridDim.x * blockDim.x;
    for (; i < e; i += stride) {
        int b = dst[i] >> shift;
        atomicAdd(&h[b], 1);
        if (t[src[i]] > 0) atomicAdd(&hm[b], 1);
    }
    __syncthreads();
    if (h[threadIdx.x]) atomicAdd(&bhist[threadIdx.x], h[threadIdx.x]);
    if (hm[threadIdx.x]) atomicAdd(&bhist_m[threadIdx.x], hm[threadIdx.x]);
}

// exclusive scan of <=256 values; also writes boff[nb] = total
__global__ __launch_bounds__(256) void k_scanb(const int* __restrict__ bsum,
                                               int* __restrict__ boff, int nb) {
    __shared__ int s[256];
    int t = threadIdx.x;
    int v = (t < nb) ? bsum[t] : 0;
    s[t] = v;
    __syncthreads();
    for (int off = 1; off < 256; off <<= 1) {
        int u = (t >= off) ? s[t - off] : 0;
        __syncthreads();
        s[t] += u;
        __syncthreads();
    }
    if (t < nb) boff[t] = s[t] - v;
    if (t == nb - 1) boff[nb] = s[t];
}

// pass B: partition edges into dst-buckets; payload = src | dlo<<20 | tbit<<29
__global__ __launch_bounds__(256) void k_fillB(const int* __restrict__ src,
                                               const int* __restrict__ dst,
                                               const int* __restrict__ t,
                                               int* __restrict__ bcur,
                                               int* __restrict__ ebuf,
                                               int e, int shift) {
    __shared__ int h[256];
    const int EPT = 16;
    int blk_base = blockIdx.x * 256 * EPT;
    h[threadIdx.x] = 0;
    __syncthreads();
    int pk[EPT], bk[EPT];
#pragma unroll
    for (int j = 0; j < EPT; ++j) {
        int i = blk_base + threadIdx.x + j * 256;
        if (i < e) {
            int s = src[i], d = dst[i];
            int b = d >> shift;
            bk[j] = b;
            int tb = (t[s] > 0) ? 1 : 0;
            pk[j] = s | ((d - (b << shift)) << 20) | (tb << 29);
            atomicAdd(&h[b], 1);
        } else bk[j] = -1;
    }
    __syncthreads();
    int cnt = h[threadIdx.x];
    int base = 0;
    if (cnt > 0) base = atomicAdd(&bcur[threadIdx.x], cnt);
    __syncthreads();
    h[threadIdx.x] = base;
    __syncthreads();
#pragma unroll
    for (int j = 0; j < EPT; ++j) {
        if (bk[j] >= 0) {
            int pos = atomicAdd(&h[bk[j]], 1);
            ebuf[pos] = pk[j];
        }
    }
}

// pass C: one block per bucket. LDS counting sort of the bucket slice:
// per-dst counts -> block scan -> indptr/indptr_m/dinv writes -> LDS-cursor
// scatter into src_sorted / src_mask. No global atomics at all.
__global__ __launch_bounds__(256) void k_sortC(const int* __restrict__ ebuf,
                                               const int* __restrict__ bbase,
                                               const int* __restrict__ bbase_m,
                                               int* __restrict__ indptr,
                                               int* __restrict__ indptr_m,
                                               float* __restrict__ dinv,
                                               int* __restrict__ out_all,
                                               int* __restrict__ out_m,
                                               int n, int shift, int NB) {
    __shared__ int cnt[512], cnt_m[512];
    __shared__ int cur[512], cur_m[512];
    __shared__ int tmp[256];
    int tid = threadIdx.x;
    int b = blockIdx.x;
    int lo = bbase[b], hi = bbase[b + 1];
    int lom = bbase_m[b];
    int dbase = b << shift;
    for (int j = tid; j < 512; j += 256) { cnt[j] = 0; cnt_m[j] = 0; }
    __syncthreads();
    // histogram over bucket slice
    for (int i = lo + tid; i < hi; i += 256) {
        int pk = ebuf[i];
        int dlo = (pk >> 20) & 511;
        atomicAdd(&cnt[dlo], 1);
        if (pk >> 29) atomicAdd(&cnt_m[dlo], 1);
    }
    __syncthreads();
    // exclusive scan of 512 bins (thread owns bins 2t, 2t+1)
    int c0 = cnt[2 * tid], c1 = cnt[2 * tid + 1];
    int ps = c0 + c1;
    tmp[tid] = ps;
    __syncthreads();
    for (int off = 1; off < 256; off <<= 1) {
        int u = (tid >= off) ? tmp[tid - off] : 0;
        __syncthreads();
        tmp[tid] += u;
        __syncthreads();
    }
    int pre = tmp[tid] - ps;
    cur[2 * tid] = pre;
    cur[2 * tid + 1] = pre + c0;
    __syncthreads();
    int m0 = cnt_m[2 * tid], m1 = cnt_m[2 * tid + 1];
    int psm = m0 + m1;
    tmp[tid] = psm;
    __syncthreads();
    for (int off = 1; off < 256; off <<= 1) {
        int u = (tid >= off) ? tmp[tid - off] : 0;
        __syncthreads();
        tmp[tid] += u;
        __syncthreads();
    }
    int prem = tmp[tid] - psm;
    cur_m[2 * tid] = prem;
    cur_m[2 * tid + 1] = prem + m0;
    __syncthreads();
    // indptr / indptr_m / dinv (coalesced)
    int nd = n - dbase; if (nd > 512) nd = 512;
    for (int j = tid; j < nd; j += 256) {
        indptr[dbase + j] = lo + cur[j];
        indptr_m[dbase + j] = lom + cur_m[j];
        dinv[dbase + j] = rsqrtf((float)cnt[j] + 1.0f);   // self-loop adds 1
    }
    if (b == 0 && tid == 0) {
        indptr[n] = bbase[NB];
        indptr_m[n] = bbase_m[NB];
    }
    __syncthreads();
    // scatter with LDS cursors
    for (int i = lo + tid; i < hi; i += 256) {
        int pk = ebuf[i];
        int s = pk & 0xFFFFF;
        int dlo = (pk >> 20) & 511;
        int pos = lo + atomicAdd(&cur[dlo], 1);
        out_all[pos] = s;
        if (pk >> 29) {
            int pm = lom + atomicAdd(&cur_m[dlo], 1);
            out_m[pm] = s;
        }
    }
}

// ---------------- prep ----------------

// x fp32 -> x_pre bf16 = dinv[row] * x   (128 cols; float4 chunk i -> row i>>5)
__global__ void k_cvt_pre(const float* __restrict__ x, const float* __restrict__ dinv,
                          unsigned short* __restrict__ xp, int total4) {
    int i = blockIdx.x * blockDim.x + threadIdx.x;
    int stride = gridDim.x * blockDim.x;
    for (; i < total4; i += stride) {
        float dv = dinv[i >> 5];
        float4 v = ((const float4*)x)[i];
        ushort4 o;
        o.x = f2bf(v.x * dv); o.y = f2bf(v.y * dv);
        o.z = f2bf(v.z * dv); o.w = f2bf(v.w * dv);
        ((ushort4*)xp)[i] = o;
    }
}

// W[K][Nc] fp32 -> Wt[Nc][K] bf16
__global__ void k_wt(const float* __restrict__ W, unsigned short* __restrict__ Wt,
                     int K, int Nc) {
    int i = blockIdx.x * blockDim.x + threadIdx.x;
    if (i >= K * Nc) return;
    int k = i / Nc, j = i % Nc;
    Wt[(size_t)j * K + k] = f2bf(W[i]);
}

// Wcat_t[j][k] = j<128 ? W_o[k][j] : W_t[k][j-128]   ([256][128] bf16)
__global__ void k_wcat_t(const float* __restrict__ Wo, const float* __restrict__ Wt_in,
                         unsigned short* __restrict__ Wt) {
    int i = blockIdx.x * blockDim.x + threadIdx.x;
    if (i >= 256 * 128) return;
    int j = i >> 7, k = i & 127;
    float v = (j < 128) ? Wo[(k << 7) + j] : Wt_in[(k << 7) + j - 128];
    Wt[i] = f2bf(v);
}

// ---------------- graph: aggregate x_pre ----------------
// aggx[v] = dinv[v] * (sum_{s in N(v)} x_pre[s] + x_pre[v]),  x_pre = dinv*x.
__global__ __launch_bounds__(256) void k_aggx(const unsigned short* __restrict__ xp,
                                              const int* __restrict__ indptr,
                                              const int* __restrict__ srcs,
                                              const float* __restrict__ dinv,
                                              unsigned short* __restrict__ aggx, int n) {
    int wv = threadIdx.x >> 6, lane = threadIdx.x & 63;
    int v = blockIdx.x * 4 + wv;
    if (v >= n) return;
    const unsigned* xp2 = (const unsigned*)xp;
    int beg = indptr[v], end = indptr[v + 1];
    unsigned sv = xp2[(size_t)v * 64 + lane];
    float a0 = bflo(sv), a1 = bfhi(sv);
    int i = beg;
    for (; i + 8 <= end; i += 8) {
        int s0 = srcs[i], s1 = srcs[i + 1], s2 = srcs[i + 2], s3 = srcs[i + 3];
        int s4 = srcs[i + 4], s5 = srcs[i + 5], s6 = srcs[i + 6], s7 = srcs[i + 7];
        unsigned u0 = xp2[(size_t)s0 * 64 + lane];
        unsigned u1 = xp2[(size_t)s1 * 64 + lane];
        unsigned u2 = xp2[(size_t)s2 * 64 + lane];
        unsigned u3 = xp2[(size_t)s3 * 64 + lane];
        unsigned u4 = xp2[(size_t)s4 * 64 + lane];
        unsigned u5 = xp2[(size_t)s5 * 64 + lane];
        unsigned u6 = xp2[(size_t)s6 * 64 + lane];
        unsigned u7 = xp2[(size_t)s7 * 64 + lane];
        a0 += bflo(u0) + bflo(u1) + bflo(u2) + bflo(u3)
            + bflo(u4) + bflo(u5) + bflo(u6) + bflo(u7);
        a1 += bfhi(u0) + bfhi(u1) + bfhi(u2) + bfhi(u3)
            + bfhi(u4) + bfhi(u5) + bfhi(u6) + bfhi(u7);
    }
    for (; i + 4 <= end; i += 4) {
        int s0 = srcs[i], s1 = srcs[i + 1], s2 = srcs[i + 2], s3 = srcs[i + 3];
        unsigned u0 = xp2[(size_t)s0 * 64 + lane];
        unsigned u1 = xp2[(size_t)s1 * 64 + lane];
        unsigned u2 = xp2[(size_t)s2 * 64 + lane];
        unsigned u3 = xp2[(size_t)s3 * 64 + lane];
        a0 += bflo(u0) + bflo(u1) + bflo(u2) + bflo(u3);
        a1 += bfhi(u0) + bfhi(u1) + bfhi(u2) + bfhi(u3);
    }
    for (; i < end; ++i) {
        unsigned u = xp2[(size_t)srcs[i] * 64 + lane];
        a0 += bflo(u); a1 += bfhi(u);
    }
    float dv = dinv[v];
    a0 *= dv; a1 *= dv;
    unsigned o = (unsigned)f2bf(a0) | ((unsigned)f2bf(a1) << 16);
    ((unsigned*)aggx)[(size_t)v * 64 + lane] = o;
}

// ---------------- GCN gemm: [r_o|r_t] = relu(aggx @ Wcat + [b_o|b_t]), e fused
__global__ __launch_bounds__(256) void k_gcn(const unsigned short* __restrict__ aggx,
                                             const unsigned short* __restrict__ Wcat,
                                             const float* __restrict__ b_o,
                                             const float* __restrict__ b_t,
                                             const float* __restrict__ a_w,
                                             const float* __restrict__ a_b,
                                             unsigned short* __restrict__ cat2,
                                             unsigned short* __restrict__ rt,
                                             float* __restrict__ e, int M) {
    int wave = threadIdx.x >> 6, lane = threadIdx.x & 63;
    int row_base = blockIdx.x * 64 + wave * 16;
    int rA = row_base + (lane & 15);
    if (rA >= M) rA = M - 1;
    int koff = (lane >> 4) << 3;
    int colL = lane & 15;

    bf16x8 a[4];
#pragma unroll
    for (int ks = 0; ks < 4; ++ks)
        a[ks] = *(const bf16x8*)((const short*)aggx + (size_t)rA * 128 + (ks << 5) + koff);

    f32x4 acc[16];
#pragma unroll
    for (int cf = 0; cf < 16; ++cf) acc[cf] = (f32x4){0.f, 0.f, 0.f, 0.f};
#pragma unroll
    for (int ks = 0; ks < 4; ++ks)
#pragma unroll
        for (int cf = 0; cf < 16; ++cf) {
            bf16x8 b = *(const bf16x8*)((const short*)Wcat + (size_t)((cf << 4) + colL) * 128 + (ks << 5) + koff);
            acc[cf] = __builtin_amdgcn_mfma_f32_16x16x32_bf16(a[ks], b, acc[cf], 0, 0, 0);
        }

    float ep0 = 0.f, ep1 = 0.f, ep2 = 0.f, ep3 = 0.f;
#pragma unroll
    for (int cf = 0; cf < 16; ++cf) {
        int col = (cf << 4) + colL;
        float bv = (col < 128) ? b_o[col] : b_t[col - 128];
        float aw = a_w[col];
#pragma unroll
        for (int j = 0; j < 4; ++j) {
            int row = row_base + ((lane >> 4) << 2) + j;
            float v = fmaxf(acc[cf][j] + bv, 0.f);
            if (j == 0) ep0 += v * aw;
            else if (j == 1) ep1 += v * aw;
            else if (j == 2) ep2 += v * aw;
            else ep3 += v * aw;
            if (row < M) {
                if (col < 128) cat2[(size_t)row * 256 + col] = f2bf(v);
                else rt[(size_t)row * 128 + col - 128] = f2bf(v);
            }
        }
    }
#pragma unroll
    for (int mk = 1; mk < 16; mk <<= 1) {
        ep0 += __shfl_xor(ep0, mk); ep1 += __shfl_xor(ep1, mk);
        ep2 += __shfl_xor(ep2, mk); ep3 += __shfl_xor(ep3, mk);
    }
    if (colL == 0) {
        float ab = a_b[0];
        int r0 = row_base + ((lane >> 4) << 2);
        if (r0 + 0 < M) e[r0 + 0] = ep0 + ab;
        if (r0 + 1 < M) e[r0 + 1] = ep1 + ab;
        if (r0 + 2 < M) e[r0 + 2] = ep2 + ab;
        if (r0 + 3 < M) e[r0 + 3] = ep3 + ab;
    }
}

// ---------------- masked attention (masked CSR only; max shift cancels) ----
__global__ __launch_bounds__(256) void k_attn(const unsigned short* __restrict__ rt,
                                              const int* __restrict__ indptr_m,
                                              const int* __restrict__ srcs_m,
                                              const float* __restrict__ e,
                                              unsigned short* __restrict__ cat2, int n) {
    int wv = threadIdx.x >> 6, lane = threadIdx.x & 63;
    int v = blockIdx.x * 4 + wv;
    if (v >= n) return;
    float ev = e[v];
    int bm = indptr_m[v], em = indptr_m[v + 1];
    // masked max (lane-parallel)
    float m = -INFINITY;
    for (int i = bm + lane; i < em; i += 64)
        m = fmaxf(m, lrelu02(ev + e[srcs_m[i]]));
    for (int off = 32; off; off >>= 1) m = fmaxf(m, __shfl_xor(m, off));
    if (bm == em) m = 0.f;
    // weighted gather, unroll 8
    float h0 = 0.f, h1 = 0.f, wsum = 0.f;
    const unsigned* rt2 = (const unsigned*)rt;
    int i = bm;
    for (; i + 8 <= em; i += 8) {
        int s0 = srcs_m[i], s1 = srcs_m[i + 1], s2 = srcs_m[i + 2], s3 = srcs_m[i + 3];
        int s4 = srcs_m[i + 4], s5 = srcs_m[i + 5], s6 = srcs_m[i + 6], s7 = srcs_m[i + 7];
        float w0 = __expf(lrelu02(ev + e[s0]) - m);
        float w1 = __expf(lrelu02(ev + e[s1]) - m);
        float w2 = __expf(lrelu02(ev + e[s2]) - m);
        float w3 = __expf(lrelu02(ev + e[s3]) - m);
        float w4 = __expf(lrelu02(ev + e[s4]) - m);
        float w5 = __expf(lrelu02(ev + e[s5]) - m);
        float w6 = __expf(lrelu02(ev + e[s6]) - m);
        float w7 = __expf(lrelu02(ev + e[s7]) - m);
        unsigned u0 = rt2[(size_t)s0 * 64 + lane];
        unsigned u1 = rt2[(size_t)s1 * 64 + lane];
        unsigned u2 = rt2[(size_t)s2 * 64 + lane];
        unsigned u3 = rt2[(size_t)s3 * 64 + lane];
        unsigned u4 = rt2[(size_t)s4 * 64 + lane];
        unsigned u5 = rt2[(size_t)s5 * 64 + lane];
        unsigned u6 = rt2[(size_t)s6 * 64 + lane];
        unsigned u7 = rt2[(size_t)s7 * 64 + lane];
        wsum += w0 + w1 + w2 + w3 + w4 + w5 + w6 + w7;
        h0 += w0 * bflo(u0) + w1 * bflo(u1) + w2 * bflo(u2) + w3 * bflo(u3)
            + w4 * bflo(u4) + w5 * bflo(u5) + w6 * bflo(u6) + w7 * bflo(u7);
        h1 += w0 * bfhi(u0) + w1 * bfhi(u1) + w2 * bfhi(u2) + w3 * bfhi(u3)
            + w4 * bfhi(u4) + w5 * bfhi(u5) + w6 * bfhi(u6) + w7 * bfhi(u7);
    }
    for (; i < em; ++i) {
        int s = srcs_m[i];
        float w = __expf(lrelu02(ev + e[s]) - m);
        unsigned u = rt2[(size_t)s * 64 + lane];
        wsum += w;
        h0 += w * bflo(u);
        h1 += w * bfhi(u);
    }
    float inv = 1.f / (wsum + 1e-16f);
    unsigned o = (unsigned)f2bf(h0 * inv) | ((unsigned)f2bf(h1 * inv) << 16);
    ((unsigned*)(cat2 + (size_t)v * 256 + 128))[lane] = o;
}

// ---------------- bf16 MFMA GEMM (for z_enc) ----------------
__global__ __launch_bounds__(256) void k_bgemm(const unsigned short* __restrict__ A,
                                               const unsigned short* __restrict__ Wt,
                                               const float* __restrict__ bias,
                                               unsigned short* __restrict__ outb,
                                               float* __restrict__ outf,
                                               int M, int K, int Ncols) {
    int nct = Ncols >> 7;
    int mtile = blockIdx.x / nct;
    int col0 = (blockIdx.x % nct) << 7;
    int wave = threadIdx.x >> 6, lane = threadIdx.x & 63;
    int row_base = mtile * 64 + wave * 16;

    int rA = row_base + (lane & 15);
    if (rA >= M) rA = M - 1;
    const short* Ap = (const short*)A + (size_t)rA * K + ((lane >> 4) << 3);
    const short* Bp = (const short*)Wt + (size_t)(col0 + (lane & 15)) * K + ((lane >> 4) << 3);

    f32x4 acc[8];
#pragma unroll
    for (int cf = 0; cf < 8; ++cf) acc[cf] = (f32x4){0.f, 0.f, 0.f, 0.f};

    int nks = K >> 5;
    for (int ks = 0; ks < nks; ++ks) {
        bf16x8 a = *(const bf16x8*)(Ap + (ks << 5));
#pragma unroll
        for (int cf = 0; cf < 8; ++cf) {
            bf16x8 b = *(const bf16x8*)(Bp + (size_t)(cf << 4) * K + (ks << 5));
            acc[cf] = __builtin_amdgcn_mfma_f32_16x16x32_bf16(a, b, acc[cf], 0, 0, 0);
        }
    }

#pragma unroll
    for (int cf = 0; cf < 8; ++cf) {
        int col = col0 + (cf << 4) + (lane & 15);
        float bv = bias ? bias[col] : 0.f;
#pragma unroll
        for (int j = 0; j < 4; ++j) {
            int row = row_base + ((lane >> 4) << 2) + j;
            if (row >= M) continue;
            float v = acc[cf][j] + bv;
            if (outb) outb[(size_t)row * Ncols + col] = f2bf(v);
            if (outf) outf[(size_t)row * Ncols + col] = v;
        }
    }
}

// ---------------- fused heads (LDS-staged weights) ----------------
__global__ __launch_bounds__(256) void k_heads(
    const unsigned short* __restrict__ zenc_bf, const unsigned short* __restrict__ rt_bf,
    const unsigned short* __restrict__ W11, const float* __restrict__ b11,
    const unsigned short* __restrict__ W12, const float* __restrict__ b12,
    const float* __restrict__ W13, const float* __restrict__ b13,
    const unsigned short* __restrict__ W01, const float* __restrict__ b01,
    const unsigned short* __restrict__ W02, const float* __restrict__ b02,
    const float* __restrict__ W03, const float* __restrict__ b03,
    const unsigned short* __restrict__ Wd1, const float* __restrict__ bd1,
    const unsigned short* __restrict__ Wd2, const float* __restrict__ bd2,
    const float* __restrict__ Wd3, const float* __restrict__ bd3,
    const int* __restrict__ t, float* __restrict__ out, int M) {
    __shared__ short Wa[128 * 136];
    __shared__ short Wb[128 * 136];
    int wave = threadIdx.x >> 6, lane = threadIdx.x & 63;
    int row_base = blockIdx.x * 64 + wave * 16;
    int rA = row_base + (lane & 15);
    if (rA >= M) rA = M - 1;
    int koff = (lane >> 4) << 3;
    int colL = lane & 15;

    bf16x8 za[4], ra[4];
#pragma unroll
    for (int ks = 0; ks < 4; ++ks) {
        za[ks] = *(const bf16x8*)((const short*)zenc_bf + (size_t)rA * 128 + (ks << 5) + koff);
        ra[ks] = *(const bf16x8*)((const short*)rt_bf + (size_t)rA * 128 + (ks << 5) + koff);
    }

    float sp1[4], sp0[4], sdd[4];

    auto stage = [&](const unsigned short* W, short* L) {
        for (int i = threadIdx.x; i < 2048; i += 256) {
            int r = i >> 4, c = (i & 15) << 3;
            bf16x8 v = *(const bf16x8*)((const short*)W + (r << 7) + c);
            *(bf16x8*)(L + r * 136 + c) = v;
        }
    };

    auto run_head = [&](const bf16x8* A0,
                        const unsigned short* W1, const float* b1,
                        const unsigned short* W2, const float* b2,
                        const float* W3, const float* b3, float* sout) {
        __syncthreads();
        stage(W1, Wa);
        stage(W2, Wb);
        __syncthreads();
        f32x4 acc[8];
#pragma unroll
        for (int cf = 0; cf < 8; ++cf) acc[cf] = (f32x4){0.f, 0.f, 0.f, 0.f};
#pragma unroll
        for (int ks = 0; ks < 4; ++ks)
#pragma unroll
            for (int cf = 0; cf < 8; ++cf) {
                bf16x8 b = *(const bf16x8*)(Wa + ((cf << 4) + colL) * 136 + (ks << 5) + koff);
                acc[cf] = __builtin_amdgcn_mfma_f32_16x16x32_bf16(A0[ks], b, acc[cf], 0, 0, 0);
            }
        __syncthreads();
        short* hw = Wa + wave * 2176;
#pragma unroll
        for (int cf = 0; cf < 8; ++cf) {
            int col = (cf << 4) + colL;
            float bv = b1[col];
#pragma unroll
            for (int j = 0; j < 4; ++j)
                hw[(((lane >> 4) << 2) + j) * 136 + col] = (short)f2bf(lrelu02(acc[cf][j] + bv));
        }
        __syncthreads();
        bf16x8 h1f[4];
#pragma unroll
        for (int ks = 0; ks < 4; ++ks)
            h1f[ks] = *(const bf16x8*)(hw + colL * 136 + (ks << 5) + koff);
#pragma unroll
        for (int cf = 0; cf < 8; ++cf) acc[cf] = (f32x4){0.f, 0.f, 0.f, 0.f};
#pragma unroll
        for (int ks = 0; ks < 4; ++ks)
#pragma unroll
            for (int cf = 0; cf < 8; ++cf) {
                bf16x8 b = *(const bf16x8*)(Wb + ((cf << 4) + colL) * 136 + (ks << 5) + koff);
                acc[cf] = __builtin_amdgcn_mfma_f32_16x16x32_bf16(h1f[ks], b, acc[cf], 0, 0, 0);
            }
        float s0 = 0.f, s1 = 0.f, s2 = 0.f, s3 = 0.f;
#pragma unroll
        for (int cf = 0; cf < 8; ++cf) {
            int col = (cf << 4) + colL;
            float w3 = W3[col], bv = b2[col];
            s0 += lrelu02(acc[cf][0] + bv) * w3;
            s1 += lrelu02(acc[cf][1] + bv) * w3;
            s2 += lrelu02(acc[cf][2] + bv) * w3;
            s3 += lrelu02(acc[cf][3] + bv) * w3;
        }
#pragma unroll
        for (int mk = 1; mk < 16; mk <<= 1) {
            s0 += __shfl_xor(s0, mk); s1 += __shfl_xor(s1, mk);
            s2 += __shfl_xor(s2, mk); s3 += __shfl_xor(s3, mk);
        }
        float bb = b3[0];
        sout[0] = s0 + bb; sout[1] = s1 + bb; sout[2] = s2 + bb; sout[3] = s3 + bb;
    };

    run_head(za, W11, b11, W12, b12, W13, b13, sp1);
    run_head(za, W01, b01, W02, b02, W03, b03, sp0);
    run_head(ra, Wd1, bd1, Wd2, bd2, Wd3, bd3, sdd);

    if (colL == 0) {
#pragma unroll
        for (int j = 0; j < 4; ++j) {
            int row = row_base + ((lane >> 4) << 2) + j;
            if (row < M) {
                out[row] = 1.f / (1.f + __expf(-sdd[j]));           // pred_t
                out[M + row] = (t[row] > 0) ? sp1[j] : sp0[j];      // pred
            }
        }
    }
}

// ---------------- launcher ----------------

extern "C" void kernel_launch(void* const* d_in, const int* in_sizes, int n_in,
                              void* d_out, int out_size, void* d_ws, size_t ws_size,
                              hipStream_t stream) {
    const float* x     = (const float*)d_in[0];
    const int*   t     = (const int*)d_in[1];
    const int*   ei    = (const int*)d_in[3];
    const float* W_o   = (const float*)d_in[4];
    const float* b_o   = (const float*)d_in[5];
    const float* W_t   = (const float*)d_in[6];
    const float* b_t   = (const float*)d_in[7];
    const float* a_w   = (const float*)d_in[8];
    const float* a_b   = (const float*)d_in[9];
    const float* W_enc = (const float*)d_in[10];
    const float* b_enc = (const float*)d_in[11];
    const float* p1_W1 = (const float*)d_in[12]; const float* p1_b1 = (const float*)d_in[13];
    const float* p1_W2 = (const float*)d_in[14]; const float* p1_b2 = (const float*)d_in[15];
    const float* p1_W3 = (const float*)d_in[16]; const float* p1_b3 = (const float*)d_in[17];
    const float* p0_W1 = (const float*)d_in[18]; const float* p0_b1 = (const float*)d_in[19];
    const float* p0_W2 = (const float*)d_in[20]; const float* p0_b2 = (const float*)d_in[21];
    const float* p0_W3 = (const float*)d_in[22]; const float* p0_b3 = (const float*)d_in[23];
    const float* d_W1  = (const float*)d_in[24]; const float* d_b1  = (const float*)d_in[25];
    const float* d_W2  = (const float*)d_in[26]; const float* d_b2  = (const float*)d_in[27];
    const float* d_W3  = (const float*)d_in[28]; const float* d_b3  = (const float*)d_in[29];

    const int n = in_sizes[1];
    const int E = in_sizes[3] / 2;
    const int* src = ei;
    const int* dst = ei + E;

    float* out  = (float*)d_out;
    float* zenc = out + 2 * (size_t)n;   // output: pred_t[N], pred[N], z_enc[N,128]

    const int shift = 9;                               // 512 dst ids per bucket
    const int NB = (n + (1 << shift) - 1) >> shift;    // 196 for n=100000 (<=256)

    // ---- workspace layout ----
    char* base = (char*)d_ws;
    size_t o = 0;
    auto alloc = [&](size_t bytes) { char* p = base + o; o += (bytes + 255) & ~(size_t)255; return p; };
    unsigned short* xp_bf   = (unsigned short*)alloc((size_t)n * 128 * 2);  // dinv*x
    unsigned short* aggx_bf = (unsigned short*)alloc((size_t)n * 128 * 2);
    unsigned short* cat2_bf = (unsigned short*)alloc((size_t)n * 256 * 2);
    unsigned short* rt_bf   = (unsigned short*)alloc((size_t)n * 128 * 2);
    unsigned short* zenc_bf = (unsigned short*)alloc((size_t)n * 128 * 2);
    float* dinv = (float*)alloc((size_t)n * 4);
    float* evec = (float*)alloc((size_t)n * 4);
    unsigned short* Wcat_t = (unsigned short*)alloc(256 * 128 * 2);
    unsigned short* Wenc_t = (unsigned short*)alloc(128 * 256 * 2);
    unsigned short* Wp1a_t = (unsigned short*)alloc(128 * 128 * 2);
    unsigned short* Wp1b_t = (unsigned short*)alloc(128 * 128 * 2);
    unsigned short* Wp0a_t = (unsigned short*)alloc(128 * 128 * 2);
    unsigned short* Wp0b_t = (unsigned short*)alloc(128 * 128 * 2);
    unsigned short* Wda_t  = (unsigned short*)alloc(128 * 128 * 2);
    unsigned short* Wdb_t  = (unsigned short*)alloc(128 * 128 * 2);
    int* indptr     = (int*)alloc(((size_t)n + 1) * 4);
    int* indptr_m   = (int*)alloc(((size_t)n + 1) * 4);
    int* bhist      = (int*)alloc(257 * 4);
    int* bhist_m    = (int*)alloc(257 * 4);
    int* bbase      = (int*)alloc(257 * 4);
    int* bbase_m    = (int*)alloc(257 * 4);
    int* bcur       = (int*)alloc(257 * 4);
    int* src_sorted = (int*)alloc((size_t)E * 4);
    int* src_mask   = (int*)alloc((size_t)E * 4);
    int* ebuf       = (int*)alloc((size_t)E * 4);

    const int mt = (n + 63) / 64;

    // ---- CSR build: bucket hist -> partition -> per-bucket LDS counting sort
    k_zero_i32<<<1, 256, 0, stream>>>(bhist, 257);
    k_zero_i32<<<1, 256, 0, stream>>>(bhist_m, 257);
    k_bhist<<<1024, 256, 0, stream>>>(src, dst, t, bhist, bhist_m, E, shift);
    k_scanb<<<1, 256, 0, stream>>>(bhist, bbase, NB);
    k_scanb<<<1, 256, 0, stream>>>(bhist_m, bbase_m, NB);
    k_copy_i32<<<1, 256, 0, stream>>>(bbase, bcur, NB);
    k_fillB<<<(E + 4095) / 4096, 256, 0, stream>>>(src, dst, t, bcur, ebuf, E, shift);
    k_sortC<<<NB, 256, 0, stream>>>(ebuf, bbase, bbase_m, indptr, indptr_m, dinv,
                                    src_sorted, src_mask, n, shift, NB);

    // ---- prep ----
    k_cvt_pre<<<2048, 256, 0, stream>>>(x, dinv, xp_bf, n * 32);
    k_wcat_t<<<128, 256, 0, stream>>>(W_o, W_t, Wcat_t);
    k_wt<<<128, 256, 0, stream>>>(W_enc, Wenc_t, 256, 128);
    k_wt<<<64, 256, 0, stream>>>(p1_W1, Wp1a_t, 128, 128);
    k_wt<<<64, 256, 0, stream>>>(p1_W2, Wp1b_t, 128, 128);
    k_wt<<<64, 256, 0, stream>>>(p0_W1, Wp0a_t, 128, 128);
    k_wt<<<64, 256, 0, stream>>>(p0_W2, Wp0b_t, 128, 128);
    k_wt<<<64, 256, 0, stream>>>(d_W1, Wda_t, 128, 128);
    k_wt<<<64, 256, 0, stream>>>(d_W2, Wdb_t, 128, 128);

    // aggregate prescaled x over full CSR
    k_aggx<<<(n + 3) / 4, 256, 0, stream>>>(xp_bf, indptr, src_sorted, dinv, aggx_bf, n);

    // [r_o|r_t] = relu(aggx @ Wcat + bias); e fused
    k_gcn<<<mt, 256, 0, stream>>>(aggx_bf, Wcat_t, b_o, b_t, a_w, a_b,
                                  cat2_bf, rt_bf, evec, n);

    // attention -> h (masked CSR only)
    k_attn<<<(n + 3) / 4, 256, 0, stream>>>(rt_bf, indptr_m, src_mask, evec, cat2_bf, n);

    // z_enc = cat2 @ W_enc + b_enc
    k_bgemm<<<mt, 256, 0, stream>>>(cat2_bf, Wenc_t, b_enc, zenc_bf, zenc, n, 256, 128);

    // fused heads + select + sigmoid
    k_heads<<<mt, 256, 0, stream>>>(zenc_bf, rt_bf,
                                    Wp1a_t, p1_b1, Wp1b_t, p1_b2, p1_W3, p1_b3,
                                    Wp0a_t, p0_b1, Wp0b_t, p0_b2, p0_W3, p0_b3,
                                    Wda_t, d_b1, Wdb_t, d_b2, d_W3, d_b3,
                                    t, out, n);
}

// Round 10
// 481.751 us; speedup vs baseline: 3.2287x; 1.0280x over previous
//
#include <hip/hip_runtime.h>
#include <hip/hip_bf16.h>
#include <math.h>

// ---------------------------------------------------------------------------
// SPNet: GCN(2x) -> masked edge attention -> encoder -> 3 MLP heads
// N=100000, E=1600000, F=H=128.
// Round 10:
//   - k_enc (z_enc GEMM) + k_gcn: LDS-transpose epilogues -> coalesced
//     float4/short8 row-major stores. (k_bgemm showed 132MB WRITE vs 77MB
//     logical: scalar scattered stores -> partial-line RMW amplification.)
//   - everything else unchanged from round 8/9.
// ---------------------------------------------------------------------------

using bf16x8 = __attribute__((ext_vector_type(8))) short;
using s16x8  = __attribute__((ext_vector_type(8))) short;
using f32x4  = __attribute__((ext_vector_type(4))) float;

static __device__ __forceinline__ float lrelu02(float x) { return x > 0.f ? x : 0.2f * x; }

static __device__ __forceinline__ unsigned short f2bf(float f) {
    unsigned u = __float_as_uint(f);
    unsigned r = u + 0x7FFF + ((u >> 16) & 1);   // round-to-nearest-even
    return (unsigned short)(r >> 16);
}
static __device__ __forceinline__ float bf2f(unsigned short h) {
    return __uint_as_float(((unsigned)h) << 16);
}
static __device__ __forceinline__ float bflo(unsigned u) { return __uint_as_float(u << 16); }
static __device__ __forceinline__ float bfhi(unsigned u) { return __uint_as_float(u & 0xFFFF0000u); }

// ---------------- CSR build ----------------

__global__ void k_zero_i32(int* __restrict__ p, int n) {
    int i = blockIdx.x * blockDim.x + threadIdx.x;
    int stride = gridDim.x * blockDim.x;
    for (; i < n; i += stride) p[i] = 0;
}

__global__ void k_copy_i32(const int* __restrict__ a, int* __restrict__ b, int n) {
    int i = blockIdx.x * blockDim.x + threadIdx.x;
    if (i < n) b[i] = a[i];
}

// bucket histograms only (256 bins, LDS-aggregated) — no per-dst atomics
__global__ __launch_bounds__(256) void k_bhist(const int* __restrict__ src,
                                               const int* __restrict__ dst,
                                               const int* __restrict__ t,
                                               int* __restrict__ bhist,
                                               int* __restrict__ bhist_m,
                                               int e, int shift) {
    __shared__ int h[256], hm[256];
    h[threadIdx.x] = 0; hm[threadIdx.x] = 0;
    __syncthreads();
    int i = blockIdx.x * blockDim.x + threadIdx.x;
    int stride = gridDim.x * blockDim.x;
    for (; i < e; i += stride) {
        int b = dst[i] >> shift;
        atomicAdd(&h[b], 1);
        if (t[src[i]] > 0) atomicAdd(&hm[b], 1);
    }
    __syncthreads();
    if (h[threadIdx.x]) atomicAdd(&bhist[threadIdx.x], h[threadIdx.x]);
    if (hm[threadIdx.x]) atomicAdd(&bhist_m[threadIdx.x], hm[threadIdx.x]);
}

// exclusive scan of <=256 values; also writes boff[nb] = total
__global__ __launch_bounds__(256) void k_scanb(const int* __restrict__ bsum,
                                               int* __restrict__ boff, int nb) {
    __shared__ int s[256];
    int t = threadIdx.x;
    int v = (t < nb) ? bsum[t] : 0;
    s[t] = v;
    __syncthreads();
    for (int off = 1; off < 256; off <<= 1) {
        int u = (t >= off) ? s[t - off] : 0;
        __syncthreads();
        s[t] += u;
        __syncthreads();
    }
    if (t < nb) boff[t] = s[t] - v;
    if (t == nb - 1) boff[nb] = s[t];
}

// pass B: partition edges into dst-buckets; payload = src | dlo<<20 | tbit<<29
__global__ __launch_bounds__(256) void k_fillB(const int* __restrict__ src,
                                               const int* __restrict__ dst,
                                               const int* __restrict__ t,
                                               int* __restrict__ bcur,
                                               int* __restrict__ ebuf,
                                               int e, int shift) {
    __shared__ int h[256];
    const int EPT = 16;
    int blk_base = blockIdx.x * 256 * EPT;
    h[threadIdx.x] = 0;
    __syncthreads();
    int pk[EPT], bk[EPT];
#pragma unroll
    for (int j = 0; j < EPT; ++j) {
        int i = blk_base + threadIdx.x + j * 256;
        if (i < e) {
            int s = src[i], d = dst[i];
            int b = d >> shift;
            bk[j] = b;
            int tb = (t[s] > 0) ? 1 : 0;
            pk[j] = s | ((d - (b << shift)) << 20) | (tb << 29);
            atomicAdd(&h[b], 1);
        } else bk[j] = -1;
    }
    __syncthreads();
    int cnt = h[threadIdx.x];
    int base = 0;
    if (cnt > 0) base = atomicAdd(&bcur[threadIdx.x], cnt);
    __syncthreads();
    h[threadIdx.x] = base;
    __syncthreads();
#pragma unroll
    for (int j = 0; j < EPT; ++j) {
        if (bk[j] >= 0) {
            int pos = atomicAdd(&h[bk[j]], 1);
            ebuf[pos] = pk[j];
        }
    }
}

// pass C: one block per bucket. LDS counting sort of the bucket slice.
__global__ __launch_bounds__(256) void k_sortC(const int* __restrict__ ebuf,
                                               const int* __restrict__ bbase,
                                               const int* __restrict__ bbase_m,
                                               int* __restrict__ indptr,
                                               int* __restrict__ indptr_m,
                                               float* __restrict__ dinv,
                                               int* __restrict__ out_all,
                                               int* __restrict__ out_m,
                                               int n, int shift, int NB) {
    __shared__ int cnt[512], cnt_m[512];
    __shared__ int cur[512], cur_m[512];
    __shared__ int tmp[256];
    int tid = threadIdx.x;
    int b = blockIdx.x;
    int lo = bbase[b], hi = bbase[b + 1];
    int lom = bbase_m[b];
    int dbase = b << shift;
    for (int j = tid; j < 512; j += 256) { cnt[j] = 0; cnt_m[j] = 0; }
    __syncthreads();
    for (int i = lo + tid; i < hi; i += 256) {
        int pk = ebuf[i];
        int dlo = (pk >> 20) & 511;
        atomicAdd(&cnt[dlo], 1);
        if (pk >> 29) atomicAdd(&cnt_m[dlo], 1);
    }
    __syncthreads();
    int c0 = cnt[2 * tid], c1 = cnt[2 * tid + 1];
    int ps = c0 + c1;
    tmp[tid] = ps;
    __syncthreads();
    for (int off = 1; off < 256; off <<= 1) {
        int u = (tid >= off) ? tmp[tid - off] : 0;
        __syncthreads();
        tmp[tid] += u;
        __syncthreads();
    }
    int pre = tmp[tid] - ps;
    cur[2 * tid] = pre;
    cur[2 * tid + 1] = pre + c0;
    __syncthreads();
    int m0 = cnt_m[2 * tid], m1 = cnt_m[2 * tid + 1];
    int psm = m0 + m1;
    tmp[tid] = psm;
    __syncthreads();
    for (int off = 1; off < 256; off <<= 1) {
        int u = (tid >= off) ? tmp[tid - off] : 0;
        __syncthreads();
        tmp[tid] += u;
        __syncthreads();
    }
    int prem = tmp[tid] - psm;
    cur_m[2 * tid] = prem;
    cur_m[2 * tid + 1] = prem + m0;
    __syncthreads();
    int nd = n - dbase; if (nd > 512) nd = 512;
    for (int j = tid; j < nd; j += 256) {
        indptr[dbase + j] = lo + cur[j];
        indptr_m[dbase + j] = lom + cur_m[j];
        dinv[dbase + j] = rsqrtf((float)cnt[j] + 1.0f);   // self-loop adds 1
    }
    if (b == 0 && tid == 0) {
        indptr[n] = bbase[NB];
        indptr_m[n] = bbase_m[NB];
    }
    __syncthreads();
    for (int i = lo + tid; i < hi; i += 256) {
        int pk = ebuf[i];
        int s = pk & 0xFFFFF;
        int dlo = (pk >> 20) & 511;
        int pos = lo + atomicAdd(&cur[dlo], 1);
        out_all[pos] = s;
        if (pk >> 29) {
            int pm = lom + atomicAdd(&cur_m[dlo], 1);
            out_m[pm] = s;
        }
    }
}

// ---------------- prep ----------------

__global__ void k_cvt_pre(const float* __restrict__ x, const float* __restrict__ dinv,
                          unsigned short* __restrict__ xp, int total4) {
    int i = blockIdx.x * blockDim.x + threadIdx.x;
    int stride = gridDim.x * blockDim.x;
    for (; i < total4; i += stride) {
        float dv = dinv[i >> 5];
        float4 v = ((const float4*)x)[i];
        ushort4 o;
        o.x = f2bf(v.x * dv); o.y = f2bf(v.y * dv);
        o.z = f2bf(v.z * dv); o.w = f2bf(v.w * dv);
        ((ushort4*)xp)[i] = o;
    }
}

__global__ void k_wt(const float* __restrict__ W, unsigned short* __restrict__ Wt,
                     int K, int Nc) {
    int i = blockIdx.x * blockDim.x + threadIdx.x;
    if (i >= K * Nc) return;
    int k = i / Nc, j = i % Nc;
    Wt[(size_t)j * K + k] = f2bf(W[i]);
}

__global__ void k_wcat_t(const float* __restrict__ Wo, const float* __restrict__ Wt_in,
                         unsigned short* __restrict__ Wt) {
    int i = blockIdx.x * blockDim.x + threadIdx.x;
    if (i >= 256 * 128) return;
    int j = i >> 7, k = i & 127;
    float v = (j < 128) ? Wo[(k << 7) + j] : Wt_in[(k << 7) + j - 128];
    Wt[i] = f2bf(v);
}

// ---------------- graph: aggregate x_pre ----------------
__global__ __launch_bounds__(256) void k_aggx(const unsigned short* __restrict__ xp,
                                              const int* __restrict__ indptr,
                                              const int* __restrict__ srcs,
                                              const float* __restrict__ dinv,
                                              unsigned short* __restrict__ aggx, int n) {
    int wv = threadIdx.x >> 6, lane = threadIdx.x & 63;
    int v = blockIdx.x * 4 + wv;
    if (v >= n) return;
    const unsigned* xp2 = (const unsigned*)xp;
    int beg = indptr[v], end = indptr[v + 1];
    unsigned sv = xp2[(size_t)v * 64 + lane];
    float a0 = bflo(sv), a1 = bfhi(sv);
    int i = beg;
    for (; i + 8 <= end; i += 8) {
        int s0 = srcs[i], s1 = srcs[i + 1], s2 = srcs[i + 2], s3 = srcs[i + 3];
        int s4 = srcs[i + 4], s5 = srcs[i + 5], s6 = srcs[i + 6], s7 = srcs[i + 7];
        unsigned u0 = xp2[(size_t)s0 * 64 + lane];
        unsigned u1 = xp2[(size_t)s1 * 64 + lane];
        unsigned u2 = xp2[(size_t)s2 * 64 + lane];
        unsigned u3 = xp2[(size_t)s3 * 64 + lane];
        unsigned u4 = xp2[(size_t)s4 * 64 + lane];
        unsigned u5 = xp2[(size_t)s5 * 64 + lane];
        unsigned u6 = xp2[(size_t)s6 * 64 + lane];
        unsigned u7 = xp2[(size_t)s7 * 64 + lane];
        a0 += bflo(u0) + bflo(u1) + bflo(u2) + bflo(u3)
            + bflo(u4) + bflo(u5) + bflo(u6) + bflo(u7);
        a1 += bfhi(u0) + bfhi(u1) + bfhi(u2) + bfhi(u3)
            + bfhi(u4) + bfhi(u5) + bfhi(u6) + bfhi(u7);
    }
    for (; i + 4 <= end; i += 4) {
        int s0 = srcs[i], s1 = srcs[i + 1], s2 = srcs[i + 2], s3 = srcs[i + 3];
        unsigned u0 = xp2[(size_t)s0 * 64 + lane];
        unsigned u1 = xp2[(size_t)s1 * 64 + lane];
        unsigned u2 = xp2[(size_t)s2 * 64 + lane];
        unsigned u3 = xp2[(size_t)s3 * 64 + lane];
        a0 += bflo(u0) + bflo(u1) + bflo(u2) + bflo(u3);
        a1 += bfhi(u0) + bfhi(u1) + bfhi(u2) + bfhi(u3);
    }
    for (; i < end; ++i) {
        unsigned u = xp2[(size_t)srcs[i] * 64 + lane];
        a0 += bflo(u); a1 += bfhi(u);
    }
    float dv = dinv[v];
    a0 *= dv; a1 *= dv;
    unsigned o = (unsigned)f2bf(a0) | ((unsigned)f2bf(a1) << 16);
    ((unsigned*)aggx)[(size_t)v * 64 + lane] = o;
}

// ---------------- GCN gemm: [r_o|r_t] = relu(aggx @ Wcat + [b_o|b_t]), e fused
// Epilogue via LDS transpose -> coalesced short8 stores.
__global__ __launch_bounds__(256) void k_gcn(const unsigned short* __restrict__ aggx,
                                             const unsigned short* __restrict__ Wcat,
                                             const float* __restrict__ b_o,
                                             const float* __restrict__ b_t,
                                             const float* __restrict__ a_w,
                                             const float* __restrict__ a_b,
                                             unsigned short* __restrict__ cat2,
                                             unsigned short* __restrict__ rt,
                                             float* __restrict__ e, int M) {
    __shared__ short ct[64][264];   // 64 rows x 256 cols bf16 (+8 pad)
    int wave = threadIdx.x >> 6, lane = threadIdx.x & 63;
    int row_base = blockIdx.x * 64 + wave * 16;
    int rA = row_base + (lane & 15);
    if (rA >= M) rA = M - 1;
    int koff = (lane >> 4) << 3;
    int colL = lane & 15;

    bf16x8 a[4];
#pragma unroll
    for (int ks = 0; ks < 4; ++ks)
        a[ks] = *(const bf16x8*)((const short*)aggx + (size_t)rA * 128 + (ks << 5) + koff);

    f32x4 acc[16];
#pragma unroll
    for (int cf = 0; cf < 16; ++cf) acc[cf] = (f32x4){0.f, 0.f, 0.f, 0.f};
#pragma unroll
    for (int ks = 0; ks < 4; ++ks)
#pragma unroll
        for (int cf = 0; cf < 16; ++cf) {
            bf16x8 b = *(const bf16x8*)((const short*)Wcat + (size_t)((cf << 4) + colL) * 128 + (ks << 5) + koff);
            acc[cf] = __builtin_amdgcn_mfma_f32_16x16x32_bf16(a[ks], b, acc[cf], 0, 0, 0);
        }

    float ep0 = 0.f, ep1 = 0.f, ep2 = 0.f, ep3 = 0.f;
    int rl0 = wave * 16 + ((lane >> 4) << 2);
#pragma unroll
    for (int cf = 0; cf < 16; ++cf) {
        int col = (cf << 4) + colL;
        float bv = (col < 128) ? b_o[col] : b_t[col - 128];
        float aw = a_w[col];
#pragma unroll
        for (int j = 0; j < 4; ++j) {
            float v = fmaxf(acc[cf][j] + bv, 0.f);
            if (j == 0) ep0 += v * aw;
            else if (j == 1) ep1 += v * aw;
            else if (j == 2) ep2 += v * aw;
            else ep3 += v * aw;
            ct[rl0 + j][col] = (short)f2bf(v);
        }
    }
#pragma unroll
    for (int mk = 1; mk < 16; mk <<= 1) {
        ep0 += __shfl_xor(ep0, mk); ep1 += __shfl_xor(ep1, mk);
        ep2 += __shfl_xor(ep2, mk); ep3 += __shfl_xor(ep3, mk);
    }
    if (colL == 0) {
        float ab = a_b[0];
        int r0 = row_base + ((lane >> 4) << 2);
        if (r0 + 0 < M) e[r0 + 0] = ep0 + ab;
        if (r0 + 1 < M) e[r0 + 1] = ep1 + ab;
        if (r0 + 2 < M) e[r0 + 2] = ep2 + ab;
        if (r0 + 3 < M) e[r0 + 3] = ep3 + ab;
    }
    __syncthreads();
    // coalesced readout: 4 threads per row, 64 cols each (8x short8)
    int row = threadIdx.x >> 2;
    int c0 = (threadIdx.x & 3) << 6;
    int grow = blockIdx.x * 64 + row;
    if (grow < M) {
        if (c0 < 128) {
            short* dstp = (short*)cat2 + (size_t)grow * 256 + c0;
#pragma unroll
            for (int q = 0; q < 8; ++q)
                *(s16x8*)(dstp + (q << 3)) = *(const s16x8*)&ct[row][c0 + (q << 3)];
        } else {
            short* dstp = (short*)rt + (size_t)grow * 128 + (c0 - 128);
#pragma unroll
            for (int q = 0; q < 8; ++q)
                *(s16x8*)(dstp + (q << 3)) = *(const s16x8*)&ct[row][c0 + (q << 3)];
        }
    }
}

// ---------------- masked attention (masked CSR only) ----------------
__global__ __launch_bounds__(256) void k_attn(const unsigned short* __restrict__ rt,
                                              const int* __restrict__ indptr_m,
                                              const int* __restrict__ srcs_m,
                                              const float* __restrict__ e,
                                              unsigned short* __restrict__ cat2, int n) {
    int wv = threadIdx.x >> 6, lane = threadIdx.x & 63;
    int v = blockIdx.x * 4 + wv;
    if (v >= n) return;
    float ev = e[v];
    int bm = indptr_m[v], em = indptr_m[v + 1];
    float m = -INFINITY;
    for (int i = bm + lane; i < em; i += 64)
        m = fmaxf(m, lrelu02(ev + e[srcs_m[i]]));
    for (int off = 32; off; off >>= 1) m = fmaxf(m, __shfl_xor(m, off));
    if (bm == em) m = 0.f;
    float h0 = 0.f, h1 = 0.f, wsum = 0.f;
    const unsigned* rt2 = (const unsigned*)rt;
    int i = bm;
    for (; i + 8 <= em; i += 8) {
        int s0 = srcs_m[i], s1 = srcs_m[i + 1], s2 = srcs_m[i + 2], s3 = srcs_m[i + 3];
        int s4 = srcs_m[i + 4], s5 = srcs_m[i + 5], s6 = srcs_m[i + 6], s7 = srcs_m[i + 7];
        float w0 = __expf(lrelu02(ev + e[s0]) - m);
        float w1 = __expf(lrelu02(ev + e[s1]) - m);
        float w2 = __expf(lrelu02(ev + e[s2]) - m);
        float w3 = __expf(lrelu02(ev + e[s3]) - m);
        float w4 = __expf(lrelu02(ev + e[s4]) - m);
        float w5 = __expf(lrelu02(ev + e[s5]) - m);
        float w6 = __expf(lrelu02(ev + e[s6]) - m);
        float w7 = __expf(lrelu02(ev + e[s7]) - m);
        unsigned u0 = rt2[(size_t)s0 * 64 + lane];
        unsigned u1 = rt2[(size_t)s1 * 64 + lane];
        unsigned u2 = rt2[(size_t)s2 * 64 + lane];
        unsigned u3 = rt2[(size_t)s3 * 64 + lane];
        unsigned u4 = rt2[(size_t)s4 * 64 + lane];
        unsigned u5 = rt2[(size_t)s5 * 64 + lane];
        unsigned u6 = rt2[(size_t)s6 * 64 + lane];
        unsigned u7 = rt2[(size_t)s7 * 64 + lane];
        wsum += w0 + w1 + w2 + w3 + w4 + w5 + w6 + w7;
        h0 += w0 * bflo(u0) + w1 * bflo(u1) + w2 * bflo(u2) + w3 * bflo(u3)
            + w4 * bflo(u4) + w5 * bflo(u5) + w6 * bflo(u6) + w7 * bflo(u7);
        h1 += w0 * bfhi(u0) + w1 * bfhi(u1) + w2 * bfhi(u2) + w3 * bfhi(u3)
            + w4 * bfhi(u4) + w5 * bfhi(u5) + w6 * bfhi(u6) + w7 * bfhi(u7);
    }
    for (; i < em; ++i) {
        int s = srcs_m[i];
        float w = __expf(lrelu02(ev + e[s]) - m);
        unsigned u = rt2[(size_t)s * 64 + lane];
        wsum += w;
        h0 += w * bflo(u);
        h1 += w * bfhi(u);
    }
    float inv = 1.f / (wsum + 1e-16f);
    unsigned o = (unsigned)f2bf(h0 * inv) | ((unsigned)f2bf(h1 * inv) << 16);
    ((unsigned*)(cat2 + (size_t)v * 256 + 128))[lane] = o;
}

// ---------------- z_enc GEMM (K=256, Ncols=128), LDS-transpose epilogue ----
__global__ __launch_bounds__(256) void k_enc(const unsigned short* __restrict__ A,
                                             const unsigned short* __restrict__ Wt,
                                             const float* __restrict__ bias,
                                             unsigned short* __restrict__ outb,
                                             float* __restrict__ outf, int M) {
    __shared__ float zt[64][132];   // 64 rows x 128 fp32 (+4 pad)
    const int K = 256;
    int wave = threadIdx.x >> 6, lane = threadIdx.x & 63;
    int row_base = blockIdx.x * 64 + wave * 16;
    int rA = row_base + (lane & 15);
    if (rA >= M) rA = M - 1;
    const short* Ap = (const short*)A + (size_t)rA * K + ((lane >> 4) << 3);
    const short* Bp = (const short*)Wt + (size_t)(lane & 15) * K + ((lane >> 4) << 3);
    int colL = lane & 15;

    f32x4 acc[8];
#pragma unroll
    for (int cf = 0; cf < 8; ++cf) acc[cf] = (f32x4){0.f, 0.f, 0.f, 0.f};
#pragma unroll
    for (int ks = 0; ks < 8; ++ks) {
        bf16x8 a = *(const bf16x8*)(Ap + (ks << 5));
#pragma unroll
        for (int cf = 0; cf < 8; ++cf) {
            bf16x8 b = *(const bf16x8*)(Bp + (size_t)(cf << 4) * K + (ks << 5));
            acc[cf] = __builtin_amdgcn_mfma_f32_16x16x32_bf16(a, b, acc[cf], 0, 0, 0);
        }
    }

    int rl0 = wave * 16 + ((lane >> 4) << 2);
#pragma unroll
    for (int cf = 0; cf < 8; ++cf) {
        int col = (cf << 4) + colL;
        float bv = bias[col];
#pragma unroll
        for (int j = 0; j < 4; ++j)
            zt[rl0 + j][col] = acc[cf][j] + bv;
    }
    __syncthreads();
    // coalesced readout: 4 threads per row, 32 cols each
    int row = threadIdx.x >> 2;
    int c0 = (threadIdx.x & 3) << 5;
    int grow = blockIdx.x * 64 + row;
    if (grow < M) {
        float* fp = outf + (size_t)grow * 128 + c0;
        short* bp = (short*)outb + (size_t)grow * 128 + c0;
#pragma unroll
        for (int q = 0; q < 8; ++q) {
            float4 v = *(const float4*)&zt[row][c0 + (q << 2)];
            *(float4*)(fp + (q << 2)) = v;
            if ((q & 1) == 0) {
                float4 v2 = *(const float4*)&zt[row][c0 + (q << 2) + 4];
                s16x8 w;
                w[0] = (short)f2bf(v.x);  w[1] = (short)f2bf(v.y);
                w[2] = (short)f2bf(v.z);  w[3] = (short)f2bf(v.w);
                w[4] = (short)f2bf(v2.x); w[5] = (short)f2bf(v2.y);
                w[6] = (short)f2bf(v2.z); w[7] = (short)f2bf(v2.w);
                *(s16x8*)(bp + (q << 2)) = w;
            }
        }
    }
}

// ---------------- fused heads (LDS-staged weights) ----------------
__global__ __launch_bounds__(256) void k_heads(
    const unsigned short* __restrict__ zenc_bf, const unsigned short* __restrict__ rt_bf,
    const unsigned short* __restrict__ W11, const float* __restrict__ b11,
    const unsigned short* __restrict__ W12, const float* __restrict__ b12,
    const float* __restrict__ W13, const float* __restrict__ b13,
    const unsigned short* __restrict__ W01, const float* __restrict__ b01,
    const unsigned short* __restrict__ W02, const float* __restrict__ b02,
    const float* __restrict__ W03, const float* __restrict__ b03,
    const unsigned short* __restrict__ Wd1, const float* __restrict__ bd1,
    const unsigned short* __restrict__ Wd2, const float* __restrict__ bd2,
    const float* __restrict__ Wd3, const float* __restrict__ bd3,
    const int* __restrict__ t, float* __restrict__ out, int M) {
    __shared__ short Wa[128 * 136];
    __shared__ short Wb[128 * 136];
    int wave = threadIdx.x >> 6, lane = threadIdx.x & 63;
    int row_base = blockIdx.x * 64 + wave * 16;
    int rA = row_base + (lane & 15);
    if (rA >= M) rA = M - 1;
    int koff = (lane >> 4) << 3;
    int colL = lane & 15;

    bf16x8 za[4], ra[4];
#pragma unroll
    for (int ks = 0; ks < 4; ++ks) {
        za[ks] = *(const bf16x8*)((const short*)zenc_bf + (size_t)rA * 128 + (ks << 5) + koff);
        ra[ks] = *(const bf16x8*)((const short*)rt_bf + (size_t)rA * 128 + (ks << 5) + koff);
    }

    float sp1[4], sp0[4], sdd[4];

    auto stage = [&](const unsigned short* W, short* L) {
        for (int i = threadIdx.x; i < 2048; i += 256) {
            int r = i >> 4, c = (i & 15) << 3;
            bf16x8 v = *(const bf16x8*)((const short*)W + (r << 7) + c);
            *(bf16x8*)(L + r * 136 + c) = v;
        }
    };

    auto run_head = [&](const bf16x8* A0,
                        const unsigned short* W1, const float* b1,
                        const unsigned short* W2, const float* b2,
                        const float* W3, const float* b3, float* sout) {
        __syncthreads();
        stage(W1, Wa);
        stage(W2, Wb);
        __syncthreads();
        f32x4 acc[8];
#pragma unroll
        for (int cf = 0; cf < 8; ++cf) acc[cf] = (f32x4){0.f, 0.f, 0.f, 0.f};
#pragma unroll
        for (int ks = 0; ks < 4; ++ks)
#pragma unroll
            for (int cf = 0; cf < 8; ++cf) {
                bf16x8 b = *(const bf16x8*)(Wa + ((cf << 4) + colL) * 136 + (ks << 5) + koff);
                acc[cf] = __builtin_amdgcn_mfma_f32_16x16x32_bf16(A0[ks], b, acc[cf], 0, 0, 0);
            }
        __syncthreads();
        short* hw = Wa + wave * 2176;
#pragma unroll
        for (int cf = 0; cf < 8; ++cf) {
            int col = (cf << 4) + colL;
            float bv = b1[col];
#pragma unroll
            for (int j = 0; j < 4; ++j)
                hw[(((lane >> 4) << 2) + j) * 136 + col] = (short)f2bf(lrelu02(acc[cf][j] + bv));
        }
        __syncthreads();
        bf16x8 h1f[4];
#pragma unroll
        for (int ks = 0; ks < 4; ++ks)
            h1f[ks] = *(const bf16x8*)(hw + colL * 136 + (ks << 5) + koff);
#pragma unroll
        for (int cf = 0; cf < 8; ++cf) acc[cf] = (f32x4){0.f, 0.f, 0.f, 0.f};
#pragma unroll
        for (int ks = 0; ks < 4; ++ks)
#pragma unroll
            for (int cf = 0; cf < 8; ++cf) {
                bf16x8 b = *(const bf16x8*)(Wb + ((cf << 4) + colL) * 136 + (ks << 5) + koff);
                acc[cf] = __builtin_amdgcn_mfma_f32_16x16x32_bf16(h1f[ks], b, acc[cf], 0, 0, 0);
            }
        float s0 = 0.f, s1 = 0.f, s2 = 0.f, s3 = 0.f;
#pragma unroll
        for (int cf = 0; cf < 8; ++cf) {
            int col = (cf << 4) + colL;
            float w3 = W3[col], bv = b2[col];
            s0 += lrelu02(acc[cf][0] + bv) * w3;
            s1 += lrelu02(acc[cf][1] + bv) * w3;
            s2 += lrelu02(acc[cf][2] + bv) * w3;
            s3 += lrelu02(acc[cf][3] + bv) * w3;
        }
#pragma unroll
        for (int mk = 1; mk < 16; mk <<= 1) {
            s0 += __shfl_xor(s0, mk); s1 += __shfl_xor(s1, mk);
            s2 += __shfl_xor(s2, mk); s3 += __shfl_xor(s3, mk);
        }
        float bb = b3[0];
        sout[0] = s0 + bb; sout[1] = s1 + bb; sout[2] = s2 + bb; sout[3] = s3 + bb;
    };

    run_head(za, W11, b11, W12, b12, W13, b13, sp1);
    run_head(za, W01, b01, W02, b02, W03, b03, sp0);
    run_head(ra, Wd1, bd1, Wd2, bd2, Wd3, bd3, sdd);

    if (colL == 0) {
#pragma unroll
        for (int j = 0; j < 4; ++j) {
            int row = row_base + ((lane >> 4) << 2) + j;
            if (row < M) {
                out[row] = 1.f / (1.f + __expf(-sdd[j]));           // pred_t
                out[M + row] = (t[row] > 0) ? sp1[j] : sp0[j];      // pred
            }
        }
    }
}

// ---------------- launcher ----------------

extern "C" void kernel_launch(void* const* d_in, const int* in_sizes, int n_in,
                              void* d_out, int out_size, void* d_ws, size_t ws_size,
                              hipStream_t stream) {
    const float* x     = (const float*)d_in[0];
    const int*   t     = (const int*)d_in[1];
    const int*   ei    = (const int*)d_in[3];
    const float* W_o   = (const float*)d_in[4];
    const float* b_o   = (const float*)d_in[5];
    const float* W_t   = (const float*)d_in[6];
    const float* b_t   = (const float*)d_in[7];
    const float* a_w   = (const float*)d_in[8];
    const float* a_b   = (const float*)d_in[9];
    const float* W_enc = (const float*)d_in[10];
    const float* b_enc = (const float*)d_in[11];
    const float* p1_W1 = (const float*)d_in[12]; const float* p1_b1 = (const float*)d_in[13];
    const float* p1_W2 = (const float*)d_in[14]; const float* p1_b2 = (const float*)d_in[15];
    const float* p1_W3 = (const float*)d_in[16]; const float* p1_b3 = (const float*)d_in[17];
    const float* p0_W1 = (const float*)d_in[18]; const float* p0_b1 = (const float*)d_in[19];
    const float* p0_W2 = (const float*)d_in[20]; const float* p0_b2 = (const float*)d_in[21];
    const float* p0_W3 = (const float*)d_in[22]; const float* p0_b3 = (const float*)d_in[23];
    const float* d_W1  = (const float*)d_in[24]; const float* d_b1  = (const float*)d_in[25];
    const float* d_W2  = (const float*)d_in[26]; const float* d_b2  = (const float*)d_in[27];
    const float* d_W3  = (const float*)d_in[28]; const float* d_b3  = (const float*)d_in[29];

    const int n = in_sizes[1];
    const int E = in_sizes[3] / 2;
    const int* src = ei;
    const int* dst = ei + E;

    float* out  = (float*)d_out;
    float* zenc = out + 2 * (size_t)n;   // output: pred_t[N], pred[N], z_enc[N,128]

    const int shift = 9;                               // 512 dst ids per bucket
    const int NB = (n + (1 << shift) - 1) >> shift;    // 196 for n=100000 (<=256)

    // ---- workspace layout ----
    char* base = (char*)d_ws;
    size_t o = 0;
    auto alloc = [&](size_t bytes) { char* p = base + o; o += (bytes + 255) & ~(size_t)255; return p; };
    unsigned short* xp_bf   = (unsigned short*)alloc((size_t)n * 128 * 2);  // dinv*x
    unsigned short* aggx_bf = (unsigned short*)alloc((size_t)n * 128 * 2);
    unsigned short* cat2_bf = (unsigned short*)alloc((size_t)n * 256 * 2);
    unsigned short* rt_bf   = (unsigned short*)alloc((size_t)n * 128 * 2);
    unsigned short* zenc_bf = (unsigned short*)alloc((size_t)n * 128 * 2);
    float* dinv = (float*)alloc((size_t)n * 4);
    float* evec = (float*)alloc((size_t)n * 4);
    unsigned short* Wcat_t = (unsigned short*)alloc(256 * 128 * 2);
    unsigned short* Wenc_t = (unsigned short*)alloc(128 * 256 * 2);
    unsigned short* Wp1a_t = (unsigned short*)alloc(128 * 128 * 2);
    unsigned short* Wp1b_t = (unsigned short*)alloc(128 * 128 * 2);
    unsigned short* Wp0a_t = (unsigned short*)alloc(128 * 128 * 2);
    unsigned short* Wp0b_t = (unsigned short*)alloc(128 * 128 * 2);
    unsigned short* Wda_t  = (unsigned short*)alloc(128 * 128 * 2);
    unsigned short* Wdb_t  = (unsigned short*)alloc(128 * 128 * 2);
    int* indptr     = (int*)alloc(((size_t)n + 1) * 4);
    int* indptr_m   = (int*)alloc(((size_t)n + 1) * 4);
    int* bhist      = (int*)alloc(257 * 4);
    int* bhist_m    = (int*)alloc(257 * 4);
    int* bbase      = (int*)alloc(257 * 4);
    int* bbase_m    = (int*)alloc(257 * 4);
    int* bcur       = (int*)alloc(257 * 4);
    int* src_sorted = (int*)alloc((size_t)E * 4);
    int* src_mask   = (int*)alloc((size_t)E * 4);
    int* ebuf       = (int*)alloc((size_t)E * 4);

    const int mt = (n + 63) / 64;

    // ---- CSR build: bucket hist -> partition -> per-bucket LDS counting sort
    k_zero_i32<<<1, 256, 0, stream>>>(bhist, 257);
    k_zero_i32<<<1, 256, 0, stream>>>(bhist_m, 257);
    k_bhist<<<1024, 256, 0, stream>>>(src, dst, t, bhist, bhist_m, E, shift);
    k_scanb<<<1, 256, 0, stream>>>(bhist, bbase, NB);
    k_scanb<<<1, 256, 0, stream>>>(bhist_m, bbase_m, NB);
    k_copy_i32<<<1, 256, 0, stream>>>(bbase, bcur, NB);
    k_fillB<<<(E + 4095) / 4096, 256, 0, stream>>>(src, dst, t, bcur, ebuf, E, shift);
    k_sortC<<<NB, 256, 0, stream>>>(ebuf, bbase, bbase_m, indptr, indptr_m, dinv,
                                    src_sorted, src_mask, n, shift, NB);

    // ---- prep ----
    k_cvt_pre<<<2048, 256, 0, stream>>>(x, dinv, xp_bf, n * 32);
    k_wcat_t<<<128, 256, 0, stream>>>(W_o, W_t, Wcat_t);
    k_wt<<<128, 256, 0, stream>>>(W_enc, Wenc_t, 256, 128);
    k_wt<<<64, 256, 0, stream>>>(p1_W1, Wp1a_t, 128, 128);
    k_wt<<<64, 256, 0, stream>>>(p1_W2, Wp1b_t, 128, 128);
    k_wt<<<64, 256, 0, stream>>>(p0_W1, Wp0a_t, 128, 128);
    k_wt<<<64, 256, 0, stream>>>(p0_W2, Wp0b_t, 128, 128);
    k_wt<<<64, 256, 0, stream>>>(d_W1, Wda_t, 128, 128);
    k_wt<<<64, 256, 0, stream>>>(d_W2, Wdb_t, 128, 128);

    // aggregate prescaled x over full CSR
    k_aggx<<<(n + 3) / 4, 256, 0, stream>>>(xp_bf, indptr, src_sorted, dinv, aggx_bf, n);

    // [r_o|r_t] = relu(aggx @ Wcat + bias); e fused
    k_gcn<<<mt, 256, 0, stream>>>(aggx_bf, Wcat_t, b_o, b_t, a_w, a_b,
                                  cat2_bf, rt_bf, evec, n);

    // attention -> h (masked CSR only)
    k_attn<<<(n + 3) / 4, 256, 0, stream>>>(rt_bf, indptr_m, src_mask, evec, cat2_bf, n);

    // z_enc = cat2 @ W_enc + b_enc  (coalesced epilogue)
    k_enc<<<mt, 256, 0, stream>>>(cat2_bf, Wenc_t, b_enc, zenc_bf, zenc, n);

    // fused heads + select + sigmoid
    k_heads<<<mt, 256, 0, stream>>>(zenc_bf, rt_bf,
                                    Wp1a_t, p1_b1, Wp1b_t, p1_b2, p1_W3, p1_b3,
                                    Wp0a_t, p0_b1, Wp0b_t, p0_b2, p0_W3, p0_b3,
                                    Wda_t, d_b1, Wdb_t, d_b2, d_W3, d_b3,
                                    t, out, n);
}

// Round 11
// 448.200 us; speedup vs baseline: 3.4704x; 1.0749x over previous
//
#include <hip/hip_runtime.h>
#include <hip/hip_bf16.h>
#include <math.h>

// ---------------------------------------------------------------------------
// SPNet: GCN(2x) -> masked edge attention -> encoder -> 3 MLP heads
// N=100000, E=1600000, F=H=128.
// Round 11:
//   - k_tail = fused z_enc GEMM + 3 MLP heads. z_enc parked in LDS (fp32),
//     linear float4 writeout of zenc, bf16 frags re-read from LDS. Kills the
//     51MB zenc_bf HBM round-trip (k_enc was 82us at 1.5TB/s, both pipes idle).
//   - k_gcn: row-linear short8 readout (256B contiguous segments).
//   - everything else unchanged from round 8-10.
// ---------------------------------------------------------------------------

using bf16x8 = __attribute__((ext_vector_type(8))) short;
using s16x8  = __attribute__((ext_vector_type(8))) short;
using f32x4  = __attribute__((ext_vector_type(4))) float;

static __device__ __forceinline__ float lrelu02(float x) { return x > 0.f ? x : 0.2f * x; }

static __device__ __forceinline__ unsigned short f2bf(float f) {
    unsigned u = __float_as_uint(f);
    unsigned r = u + 0x7FFF + ((u >> 16) & 1);   // round-to-nearest-even
    return (unsigned short)(r >> 16);
}
static __device__ __forceinline__ float bf2f(unsigned short h) {
    return __uint_as_float(((unsigned)h) << 16);
}
static __device__ __forceinline__ float bflo(unsigned u) { return __uint_as_float(u << 16); }
static __device__ __forceinline__ float bfhi(unsigned u) { return __uint_as_float(u & 0xFFFF0000u); }

// ---------------- CSR build ----------------

__global__ void k_zero_i32(int* __restrict__ p, int n) {
    int i = blockIdx.x * blockDim.x + threadIdx.x;
    int stride = gridDim.x * blockDim.x;
    for (; i < n; i += stride) p[i] = 0;
}

__global__ void k_copy_i32(const int* __restrict__ a, int* __restrict__ b, int n) {
    int i = blockIdx.x * blockDim.x + threadIdx.x;
    if (i < n) b[i] = a[i];
}

// bucket histograms only (256 bins, LDS-aggregated) — no per-dst atomics
__global__ __launch_bounds__(256) void k_bhist(const int* __restrict__ src,
                                               const int* __restrict__ dst,
                                               const int* __restrict__ t,
                                               int* __restrict__ bhist,
                                               int* __restrict__ bhist_m,
                                               int e, int shift) {
    __shared__ int h[256], hm[256];
    h[threadIdx.x] = 0; hm[threadIdx.x] = 0;
    __syncthreads();
    int i = blockIdx.x * blockDim.x + threadIdx.x;
    int stride = gridDim.x * blockDim.x;
    for (; i < e; i += stride) {
        int b = dst[i] >> shift;
        atomicAdd(&h[b], 1);
        if (t[src[i]] > 0) atomicAdd(&hm[b], 1);
    }
    __syncthreads();
    if (h[threadIdx.x]) atomicAdd(&bhist[threadIdx.x], h[threadIdx.x]);
    if (hm[threadIdx.x]) atomicAdd(&bhist_m[threadIdx.x], hm[threadIdx.x]);
}

// exclusive scan of <=256 values; also writes boff[nb] = total
__global__ __launch_bounds__(256) void k_scanb(const int* __restrict__ bsum,
                                               int* __restrict__ boff, int nb) {
    __shared__ int s[256];
    int t = threadIdx.x;
    int v = (t < nb) ? bsum[t] : 0;
    s[t] = v;
    __syncthreads();
    for (int off = 1; off < 256; off <<= 1) {
        int u = (t >= off) ? s[t - off] : 0;
        __syncthreads();
        s[t] += u;
        __syncthreads();
    }
    if (t < nb) boff[t] = s[t] - v;
    if (t == nb - 1) boff[nb] = s[t];
}

// pass B: partition edges into dst-buckets; payload = src | dlo<<20 | tbit<<29
__global__ __launch_bounds__(256) void k_fillB(const int* __restrict__ src,
                                               const int* __restrict__ dst,
                                               const int* __restrict__ t,
                                               int* __restrict__ bcur,
                                               int* __restrict__ ebuf,
                                               int e, int shift) {
    __shared__ int h[256];
    const int EPT = 16;
    int blk_base = blockIdx.x * 256 * EPT;
    h[threadIdx.x] = 0;
    __syncthreads();
    int pk[EPT], bk[EPT];
#pragma unroll
    for (int j = 0; j < EPT; ++j) {
        int i = blk_base + threadIdx.x + j * 256;
        if (i < e) {
            int s = src[i], d = dst[i];
            int b = d >> shift;
            bk[j] = b;
            int tb = (t[s] > 0) ? 1 : 0;
            pk[j] = s | ((d - (b << shift)) << 20) | (tb << 29);
            atomicAdd(&h[b], 1);
        } else bk[j] = -1;
    }
    __syncthreads();
    int cnt = h[threadIdx.x];
    int base = 0;
    if (cnt > 0) base = atomicAdd(&bcur[threadIdx.x], cnt);
    __syncthreads();
    h[threadIdx.x] = base;
    __syncthreads();
#pragma unroll
    for (int j = 0; j < EPT; ++j) {
        if (bk[j] >= 0) {
            int pos = atomicAdd(&h[bk[j]], 1);
            ebuf[pos] = pk[j];
        }
    }
}

// pass C: one block per bucket. LDS counting sort of the bucket slice.
__global__ __launch_bounds__(256) void k_sortC(const int* __restrict__ ebuf,
                                               const int* __restrict__ bbase,
                                               const int* __restrict__ bbase_m,
                                               int* __restrict__ indptr,
                                               int* __restrict__ indptr_m,
                                               float* __restrict__ dinv,
                                               int* __restrict__ out_all,
                                               int* __restrict__ out_m,
                                               int n, int shift, int NB) {
    __shared__ int cnt[512], cnt_m[512];
    __shared__ int cur[512], cur_m[512];
    __shared__ int tmp[256];
    int tid = threadIdx.x;
    int b = blockIdx.x;
    int lo = bbase[b], hi = bbase[b + 1];
    int lom = bbase_m[b];
    int dbase = b << shift;
    for (int j = tid; j < 512; j += 256) { cnt[j] = 0; cnt_m[j] = 0; }
    __syncthreads();
    for (int i = lo + tid; i < hi; i += 256) {
        int pk = ebuf[i];
        int dlo = (pk >> 20) & 511;
        atomicAdd(&cnt[dlo], 1);
        if (pk >> 29) atomicAdd(&cnt_m[dlo], 1);
    }
    __syncthreads();
    int c0 = cnt[2 * tid], c1 = cnt[2 * tid + 1];
    int ps = c0 + c1;
    tmp[tid] = ps;
    __syncthreads();
    for (int off = 1; off < 256; off <<= 1) {
        int u = (tid >= off) ? tmp[tid - off] : 0;
        __syncthreads();
        tmp[tid] += u;
        __syncthreads();
    }
    int pre = tmp[tid] - ps;
    cur[2 * tid] = pre;
    cur[2 * tid + 1] = pre + c0;
    __syncthreads();
    int m0 = cnt_m[2 * tid], m1 = cnt_m[2 * tid + 1];
    int psm = m0 + m1;
    tmp[tid] = psm;
    __syncthreads();
    for (int off = 1; off < 256; off <<= 1) {
        int u = (tid >= off) ? tmp[tid - off] : 0;
        __syncthreads();
        tmp[tid] += u;
        __syncthreads();
    }
    int prem = tmp[tid] - psm;
    cur_m[2 * tid] = prem;
    cur_m[2 * tid + 1] = prem + m0;
    __syncthreads();
    int nd = n - dbase; if (nd > 512) nd = 512;
    for (int j = tid; j < nd; j += 256) {
        indptr[dbase + j] = lo + cur[j];
        indptr_m[dbase + j] = lom + cur_m[j];
        dinv[dbase + j] = rsqrtf((float)cnt[j] + 1.0f);   // self-loop adds 1
    }
    if (b == 0 && tid == 0) {
        indptr[n] = bbase[NB];
        indptr_m[n] = bbase_m[NB];
    }
    __syncthreads();
    for (int i = lo + tid; i < hi; i += 256) {
        int pk = ebuf[i];
        int s = pk & 0xFFFFF;
        int dlo = (pk >> 20) & 511;
        int pos = lo + atomicAdd(&cur[dlo], 1);
        out_all[pos] = s;
        if (pk >> 29) {
            int pm = lom + atomicAdd(&cur_m[dlo], 1);
            out_m[pm] = s;
        }
    }
}

// ---------------- prep ----------------

__global__ void k_cvt_pre(const float* __restrict__ x, const float* __restrict__ dinv,
                          unsigned short* __restrict__ xp, int total4) {
    int i = blockIdx.x * blockDim.x + threadIdx.x;
    int stride = gridDim.x * blockDim.x;
    for (; i < total4; i += stride) {
        float dv = dinv[i >> 5];
        float4 v = ((const float4*)x)[i];
        ushort4 o;
        o.x = f2bf(v.x * dv); o.y = f2bf(v.y * dv);
        o.z = f2bf(v.z * dv); o.w = f2bf(v.w * dv);
        ((ushort4*)xp)[i] = o;
    }
}

__global__ void k_wt(const float* __restrict__ W, unsigned short* __restrict__ Wt,
                     int K, int Nc) {
    int i = blockIdx.x * blockDim.x + threadIdx.x;
    if (i >= K * Nc) return;
    int k = i / Nc, j = i % Nc;
    Wt[(size_t)j * K + k] = f2bf(W[i]);
}

__global__ void k_wcat_t(const float* __restrict__ Wo, const float* __restrict__ Wt_in,
                         unsigned short* __restrict__ Wt) {
    int i = blockIdx.x * blockDim.x + threadIdx.x;
    if (i >= 256 * 128) return;
    int j = i >> 7, k = i & 127;
    float v = (j < 128) ? Wo[(k << 7) + j] : Wt_in[(k << 7) + j - 128];
    Wt[i] = f2bf(v);
}

// ---------------- graph: aggregate x_pre ----------------
__global__ __launch_bounds__(256) void k_aggx(const unsigned short* __restrict__ xp,
                                              const int* __restrict__ indptr,
                                              const int* __restrict__ srcs,
                                              const float* __restrict__ dinv,
                                              unsigned short* __restrict__ aggx, int n) {
    int wv = threadIdx.x >> 6, lane = threadIdx.x & 63;
    int v = blockIdx.x * 4 + wv;
    if (v >= n) return;
    const unsigned* xp2 = (const unsigned*)xp;
    int beg = indptr[v], end = indptr[v + 1];
    unsigned sv = xp2[(size_t)v * 64 + lane];
    float a0 = bflo(sv), a1 = bfhi(sv);
    int i = beg;
    for (; i + 8 <= end; i += 8) {
        int s0 = srcs[i], s1 = srcs[i + 1], s2 = srcs[i + 2], s3 = srcs[i + 3];
        int s4 = srcs[i + 4], s5 = srcs[i + 5], s6 = srcs[i + 6], s7 = srcs[i + 7];
        unsigned u0 = xp2[(size_t)s0 * 64 + lane];
        unsigned u1 = xp2[(size_t)s1 * 64 + lane];
        unsigned u2 = xp2[(size_t)s2 * 64 + lane];
        unsigned u3 = xp2[(size_t)s3 * 64 + lane];
        unsigned u4 = xp2[(size_t)s4 * 64 + lane];
        unsigned u5 = xp2[(size_t)s5 * 64 + lane];
        unsigned u6 = xp2[(size_t)s6 * 64 + lane];
        unsigned u7 = xp2[(size_t)s7 * 64 + lane];
        a0 += bflo(u0) + bflo(u1) + bflo(u2) + bflo(u3)
            + bflo(u4) + bflo(u5) + bflo(u6) + bflo(u7);
        a1 += bfhi(u0) + bfhi(u1) + bfhi(u2) + bfhi(u3)
            + bfhi(u4) + bfhi(u5) + bfhi(u6) + bfhi(u7);
    }
    for (; i + 4 <= end; i += 4) {
        int s0 = srcs[i], s1 = srcs[i + 1], s2 = srcs[i + 2], s3 = srcs[i + 3];
        unsigned u0 = xp2[(size_t)s0 * 64 + lane];
        unsigned u1 = xp2[(size_t)s1 * 64 + lane];
        unsigned u2 = xp2[(size_t)s2 * 64 + lane];
        unsigned u3 = xp2[(size_t)s3 * 64 + lane];
        a0 += bflo(u0) + bflo(u1) + bflo(u2) + bflo(u3);
        a1 += bfhi(u0) + bfhi(u1) + bfhi(u2) + bfhi(u3);
    }
    for (; i < end; ++i) {
        unsigned u = xp2[(size_t)srcs[i] * 64 + lane];
        a0 += bflo(u); a1 += bfhi(u);
    }
    float dv = dinv[v];
    a0 *= dv; a1 *= dv;
    unsigned o = (unsigned)f2bf(a0) | ((unsigned)f2bf(a1) << 16);
    ((unsigned*)aggx)[(size_t)v * 64 + lane] = o;
}

// ---------------- GCN gemm: [r_o|r_t] = relu(aggx @ Wcat + [b_o|b_t]), e fused
// Epilogue via LDS transpose -> row-linear short8 stores.
__global__ __launch_bounds__(256) void k_gcn(const unsigned short* __restrict__ aggx,
                                             const unsigned short* __restrict__ Wcat,
                                             const float* __restrict__ b_o,
                                             const float* __restrict__ b_t,
                                             const float* __restrict__ a_w,
                                             const float* __restrict__ a_b,
                                             unsigned short* __restrict__ cat2,
                                             unsigned short* __restrict__ rt,
                                             float* __restrict__ e, int M) {
    __shared__ short ct[64][264];   // 64 rows x 256 cols bf16 (+8 pad)
    int wave = threadIdx.x >> 6, lane = threadIdx.x & 63;
    int row_base = blockIdx.x * 64 + wave * 16;
    int rA = row_base + (lane & 15);
    if (rA >= M) rA = M - 1;
    int koff = (lane >> 4) << 3;
    int colL = lane & 15;

    bf16x8 a[4];
#pragma unroll
    for (int ks = 0; ks < 4; ++ks)
        a[ks] = *(const bf16x8*)((const short*)aggx + (size_t)rA * 128 + (ks << 5) + koff);

    f32x4 acc[16];
#pragma unroll
    for (int cf = 0; cf < 16; ++cf) acc[cf] = (f32x4){0.f, 0.f, 0.f, 0.f};
#pragma unroll
    for (int ks = 0; ks < 4; ++ks)
#pragma unroll
        for (int cf = 0; cf < 16; ++cf) {
            bf16x8 b = *(const bf16x8*)((const short*)Wcat + (size_t)((cf << 4) + colL) * 128 + (ks << 5) + koff);
            acc[cf] = __builtin_amdgcn_mfma_f32_16x16x32_bf16(a[ks], b, acc[cf], 0, 0, 0);
        }

    float ep0 = 0.f, ep1 = 0.f, ep2 = 0.f, ep3 = 0.f;
    int rl0 = wave * 16 + ((lane >> 4) << 2);
#pragma unroll
    for (int cf = 0; cf < 16; ++cf) {
        int col = (cf << 4) + colL;
        float bv = (col < 128) ? b_o[col] : b_t[col - 128];
        float aw = a_w[col];
#pragma unroll
        for (int j = 0; j < 4; ++j) {
            float v = fmaxf(acc[cf][j] + bv, 0.f);
            if (j == 0) ep0 += v * aw;
            else if (j == 1) ep1 += v * aw;
            else if (j == 2) ep2 += v * aw;
            else ep3 += v * aw;
            ct[rl0 + j][col] = (short)f2bf(v);
        }
    }
#pragma unroll
    for (int mk = 1; mk < 16; mk <<= 1) {
        ep0 += __shfl_xor(ep0, mk); ep1 += __shfl_xor(ep1, mk);
        ep2 += __shfl_xor(ep2, mk); ep3 += __shfl_xor(ep3, mk);
    }
    if (colL == 0) {
        float ab = a_b[0];
        int r0 = row_base + ((lane >> 4) << 2);
        if (r0 + 0 < M) e[r0 + 0] = ep0 + ab;
        if (r0 + 1 < M) e[r0 + 1] = ep1 + ab;
        if (r0 + 2 < M) e[r0 + 2] = ep2 + ab;
        if (r0 + 3 < M) e[r0 + 3] = ep3 + ab;
    }
    __syncthreads();
    // row-linear readout: cat2 half (256B contiguous per row), rt half
    int base64 = blockIdx.x * 64;
    short* cp = (short*)cat2 + (size_t)base64 * 256;
    for (int j = threadIdx.x; j < 1024; j += 256) {   // 64 rows x 16 short8
        int row = j >> 4;
        if (base64 + row < M)
            *(s16x8*)(cp + (size_t)row * 256 + ((j & 15) << 3)) =
                *(const s16x8*)&ct[row][(j & 15) << 3];
    }
    short* rp = (short*)rt + (size_t)base64 * 128;
    for (int j = threadIdx.x; j < 1024; j += 256) {
        int row = j >> 4;
        if (base64 + row < M)
            *(s16x8*)(rp + (size_t)row * 128 + ((j & 15) << 3)) =
                *(const s16x8*)&ct[row][128 + ((j & 15) << 3)];
    }
}

// ---------------- masked attention (masked CSR only) ----------------
__global__ __launch_bounds__(256) void k_attn(const unsigned short* __restrict__ rt,
                                              const int* __restrict__ indptr_m,
                                              const int* __restrict__ srcs_m,
                                              const float* __restrict__ e,
                                              unsigned short* __restrict__ cat2, int n) {
    int wv = threadIdx.x >> 6, lane = threadIdx.x & 63;
    int v = blockIdx.x * 4 + wv;
    if (v >= n) return;
    float ev = e[v];
    int bm = indptr_m[v], em = indptr_m[v + 1];
    float m = -INFINITY;
    for (int i = bm + lane; i < em; i += 64)
        m = fmaxf(m, lrelu02(ev + e[srcs_m[i]]));
    for (int off = 32; off; off >>= 1) m = fmaxf(m, __shfl_xor(m, off));
    if (bm == em) m = 0.f;
    float h0 = 0.f, h1 = 0.f, wsum = 0.f;
    const unsigned* rt2 = (const unsigned*)rt;
    int i = bm;
    for (; i + 8 <= em; i += 8) {
        int s0 = srcs_m[i], s1 = srcs_m[i + 1], s2 = srcs_m[i + 2], s3 = srcs_m[i + 3];
        int s4 = srcs_m[i + 4], s5 = srcs_m[i + 5], s6 = srcs_m[i + 6], s7 = srcs_m[i + 7];
        float w0 = __expf(lrelu02(ev + e[s0]) - m);
        float w1 = __expf(lrelu02(ev + e[s1]) - m);
        float w2 = __expf(lrelu02(ev + e[s2]) - m);
        float w3 = __expf(lrelu02(ev + e[s3]) - m);
        float w4 = __expf(lrelu02(ev + e[s4]) - m);
        float w5 = __expf(lrelu02(ev + e[s5]) - m);
        float w6 = __expf(lrelu02(ev + e[s6]) - m);
        float w7 = __expf(lrelu02(ev + e[s7]) - m);
        unsigned u0 = rt2[(size_t)s0 * 64 + lane];
        unsigned u1 = rt2[(size_t)s1 * 64 + lane];
        unsigned u2 = rt2[(size_t)s2 * 64 + lane];
        unsigned u3 = rt2[(size_t)s3 * 64 + lane];
        unsigned u4 = rt2[(size_t)s4 * 64 + lane];
        unsigned u5 = rt2[(size_t)s5 * 64 + lane];
        unsigned u6 = rt2[(size_t)s6 * 64 + lane];
        unsigned u7 = rt2[(size_t)s7 * 64 + lane];
        wsum += w0 + w1 + w2 + w3 + w4 + w5 + w6 + w7;
        h0 += w0 * bflo(u0) + w1 * bflo(u1) + w2 * bflo(u2) + w3 * bflo(u3)
            + w4 * bflo(u4) + w5 * bflo(u5) + w6 * bflo(u6) + w7 * bflo(u7);
        h1 += w0 * bfhi(u0) + w1 * bfhi(u1) + w2 * bfhi(u2) + w3 * bfhi(u3)
            + w4 * bfhi(u4) + w5 * bfhi(u5) + w6 * bfhi(u6) + w7 * bfhi(u7);
    }
    for (; i < em; ++i) {
        int s = srcs_m[i];
        float w = __expf(lrelu02(ev + e[s]) - m);
        unsigned u = rt2[(size_t)s * 64 + lane];
        wsum += w;
        h0 += w * bflo(u);
        h1 += w * bfhi(u);
    }
    float inv = 1.f / (wsum + 1e-16f);
    unsigned o = (unsigned)f2bf(h0 * inv) | ((unsigned)f2bf(h1 * inv) << 16);
    ((unsigned*)(cat2 + (size_t)v * 256 + 128))[lane] = o;
}

// ---------------- fused tail: z_enc GEMM + 3 MLP heads + select/sigmoid ----
// Phase 1: z_enc = cat2 @ Wenc + b_enc -> LDS fp32 -> linear fp32 writeout
//          + bf16 A-frags re-read from LDS (no zenc_bf HBM round-trip).
// Phase 2: 3 heads with LDS-staged weights (Wa/Wb overlay the zt buffer).
__global__ __launch_bounds__(256) void k_tail(
    const unsigned short* __restrict__ cat2, const unsigned short* __restrict__ rt_bf,
    const unsigned short* __restrict__ Wenc, const float* __restrict__ b_enc,
    const unsigned short* __restrict__ W11, const float* __restrict__ b11,
    const unsigned short* __restrict__ W12, const float* __restrict__ b12,
    const float* __restrict__ W13, const float* __restrict__ b13,
    const unsigned short* __restrict__ W01, const float* __restrict__ b01,
    const unsigned short* __restrict__ W02, const float* __restrict__ b02,
    const float* __restrict__ W03, const float* __restrict__ b03,
    const unsigned short* __restrict__ Wd1, const float* __restrict__ bd1,
    const unsigned short* __restrict__ Wd2, const float* __restrict__ bd2,
    const float* __restrict__ Wd3, const float* __restrict__ bd3,
    const int* __restrict__ t, float* __restrict__ zenc,
    float* __restrict__ out, int M) {
    __shared__ __align__(16) char pool[2 * 128 * 136 * 2];   // 69632 B
    short* Wa = (short*)pool;                 // 34816 B
    short* Wb = (short*)(pool + 128 * 136 * 2);
    float* zt = (float*)pool;                 // [64][132] fp32 = 33792 B (overlays Wa)

    int wave = threadIdx.x >> 6, lane = threadIdx.x & 63;
    int row_base = blockIdx.x * 64 + wave * 16;
    int rA = row_base + (lane & 15);
    if (rA >= M) rA = M - 1;
    int koff = (lane >> 4) << 3;
    int colL = lane & 15;
    int base64 = blockIdx.x * 64;

    // ra frags (discriminator input) — load early, hides under phase 1
    bf16x8 ra[4];
#pragma unroll
    for (int ks = 0; ks < 4; ++ks)
        ra[ks] = *(const bf16x8*)((const short*)rt_bf + (size_t)rA * 128 + (ks << 5) + koff);

    // ---- phase 1: z_enc (K=256, Ncols=128), B-frags from L2 ----
    {
        const short* Ap = (const short*)cat2 + (size_t)rA * 256 + koff;
        const short* Bp = (const short*)Wenc + (size_t)colL * 256 + koff;
        f32x4 acc[8];
#pragma unroll
        for (int cf = 0; cf < 8; ++cf) acc[cf] = (f32x4){0.f, 0.f, 0.f, 0.f};
#pragma unroll
        for (int ks = 0; ks < 8; ++ks) {
            bf16x8 a = *(const bf16x8*)(Ap + (ks << 5));
#pragma unroll
            for (int cf = 0; cf < 8; ++cf) {
                bf16x8 b = *(const bf16x8*)(Bp + (size_t)(cf << 4) * 256 + (ks << 5));
                acc[cf] = __builtin_amdgcn_mfma_f32_16x16x32_bf16(a, b, acc[cf], 0, 0, 0);
            }
        }
        int rl0 = wave * 16 + ((lane >> 4) << 2);
#pragma unroll
        for (int cf = 0; cf < 8; ++cf) {
            int col = (cf << 4) + colL;
            float bv = b_enc[col];
#pragma unroll
            for (int j = 0; j < 4; ++j)
                zt[(rl0 + j) * 132 + col] = acc[cf][j] + bv;
        }
    }
    __syncthreads();
    // linear fp32 writeout: block's 64x128 region is contiguous
    {
        float* zp = zenc + (size_t)base64 * 128;
        for (int j = threadIdx.x; j < 2048; j += 256) {
            int row = j >> 5;
            if (base64 + row < M)
                *(float4*)(zp + (size_t)j * 4) = *(const float4*)&zt[row * 132 + ((j & 31) << 2)];
        }
    }
    // za frags from LDS (bit-identical to f2bf(acc+bias))
    bf16x8 za[4];
    {
        int rAl = wave * 16 + (lane & 15);
#pragma unroll
        for (int ks = 0; ks < 4; ++ks) {
            const float* zr = &zt[rAl * 132 + (ks << 5) + koff];
#pragma unroll
            for (int q = 0; q < 8; ++q) za[ks][q] = (short)f2bf(zr[q]);
        }
    }

    float sp1[4], sp0[4], sdd[4];

    auto stage = [&](const unsigned short* W, short* L) {
        for (int i = threadIdx.x; i < 2048; i += 256) {
            int r = i >> 4, c = (i & 15) << 3;
            bf16x8 v = *(const bf16x8*)((const short*)W + (r << 7) + c);
            *(bf16x8*)(L + r * 136 + c) = v;
        }
    };

    auto run_head = [&](const bf16x8* A0,
                        const unsigned short* W1, const float* b1,
                        const unsigned short* W2, const float* b2,
                        const float* W3, const float* b3, float* sout) {
        __syncthreads();   // protects zt reads (first call) / prev head reads
        stage(W1, Wa);
        stage(W2, Wb);
        __syncthreads();
        f32x4 acc[8];
#pragma unroll
        for (int cf = 0; cf < 8; ++cf) acc[cf] = (f32x4){0.f, 0.f, 0.f, 0.f};
#pragma unroll
        for (int ks = 0; ks < 4; ++ks)
#pragma unroll
            for (int cf = 0; cf < 8; ++cf) {
                bf16x8 b = *(const bf16x8*)(Wa + ((cf << 4) + colL) * 136 + (ks << 5) + koff);
                acc[cf] = __builtin_amdgcn_mfma_f32_16x16x32_bf16(A0[ks], b, acc[cf], 0, 0, 0);
            }
        __syncthreads();
        short* hw = Wa + wave * 2176;
#pragma unroll
        for (int cf = 0; cf < 8; ++cf) {
            int col = (cf << 4) + colL;
            float bv = b1[col];
#pragma unroll
            for (int j = 0; j < 4; ++j)
                hw[(((lane >> 4) << 2) + j) * 136 + col] = (short)f2bf(lrelu02(acc[cf][j] + bv));
        }
        __syncthreads();
        bf16x8 h1f[4];
#pragma unroll
        for (int ks = 0; ks < 4; ++ks)
            h1f[ks] = *(const bf16x8*)(hw + colL * 136 + (ks << 5) + koff);
#pragma unroll
        for (int cf = 0; cf < 8; ++cf) acc[cf] = (f32x4){0.f, 0.f, 0.f, 0.f};
#pragma unroll
        for (int ks = 0; ks < 4; ++ks)
#pragma unroll
            for (int cf = 0; cf < 8; ++cf) {
                bf16x8 b = *(const bf16x8*)(Wb + ((cf << 4) + colL) * 136 + (ks << 5) + koff);
                acc[cf] = __builtin_amdgcn_mfma_f32_16x16x32_bf16(h1f[ks], b, acc[cf], 0, 0, 0);
            }
        float s0 = 0.f, s1 = 0.f, s2 = 0.f, s3 = 0.f;
#pragma unroll
        for (int cf = 0; cf < 8; ++cf) {
            int col = (cf << 4) + colL;
            float w3 = W3[col], bv = b2[col];
            s0 += lrelu02(acc[cf][0] + bv) * w3;
            s1 += lrelu02(acc[cf][1] + bv) * w3;
            s2 += lrelu02(acc[cf][2] + bv) * w3;
            s3 += lrelu02(acc[cf][3] + bv) * w3;
        }
#pragma unroll
        for (int mk = 1; mk < 16; mk <<= 1) {
            s0 += __shfl_xor(s0, mk); s1 += __shfl_xor(s1, mk);
            s2 += __shfl_xor(s2, mk); s3 += __shfl_xor(s3, mk);
        }
        float bb = b3[0];
        sout[0] = s0 + bb; sout[1] = s1 + bb; sout[2] = s2 + bb; sout[3] = s3 + bb;
    };

    run_head(za, W11, b11, W12, b12, W13, b13, sp1);
    run_head(za, W01, b01, W02, b02, W03, b03, sp0);
    run_head(ra, Wd1, bd1, Wd2, bd2, Wd3, bd3, sdd);

    if (colL == 0) {
#pragma unroll
        for (int j = 0; j < 4; ++j) {
            int row = row_base + ((lane >> 4) << 2) + j;
            if (row < M) {
                out[row] = 1.f / (1.f + __expf(-sdd[j]));           // pred_t
                out[M + row] = (t[row] > 0) ? sp1[j] : sp0[j];      // pred
            }
        }
    }
}

// ---------------- launcher ----------------

extern "C" void kernel_launch(void* const* d_in, const int* in_sizes, int n_in,
                              void* d_out, int out_size, void* d_ws, size_t ws_size,
                              hipStream_t stream) {
    const float* x     = (const float*)d_in[0];
    const int*   t     = (const int*)d_in[1];
    const int*   ei    = (const int*)d_in[3];
    const float* W_o   = (const float*)d_in[4];
    const float* b_o   = (const float*)d_in[5];
    const float* W_t   = (const float*)d_in[6];
    const float* b_t   = (const float*)d_in[7];
    const float* a_w   = (const float*)d_in[8];
    const float* a_b   = (const float*)d_in[9];
    const float* W_enc = (const float*)d_in[10];
    const float* b_enc = (const float*)d_in[11];
    const float* p1_W1 = (const float*)d_in[12]; const float* p1_b1 = (const float*)d_in[13];
    const float* p1_W2 = (const float*)d_in[14]; const float* p1_b2 = (const float*)d_in[15];
    const float* p1_W3 = (const float*)d_in[16]; const float* p1_b3 = (const float*)d_in[17];
    const float* p0_W1 = (const float*)d_in[18]; const float* p0_b1 = (const float*)d_in[19];
    const float* p0_W2 = (const float*)d_in[20]; const float* p0_b2 = (const float*)d_in[21];
    const float* p0_W3 = (const float*)d_in[22]; const float* p0_b3 = (const float*)d_in[23];
    const float* d_W1  = (const float*)d_in[24]; const float* d_b1  = (const float*)d_in[25];
    const float* d_W2  = (const float*)d_in[26]; const float* d_b2  = (const float*)d_in[27];
    const float* d_W3  = (const float*)d_in[28]; const float* d_b3  = (const float*)d_in[29];

    const int n = in_sizes[1];
    const int E = in_sizes[3] / 2;
    const int* src = ei;
    const int* dst = ei + E;

    float* out  = (float*)d_out;
    float* zenc = out + 2 * (size_t)n;   // output: pred_t[N], pred[N], z_enc[N,128]

    const int shift = 9;                               // 512 dst ids per bucket
    const int NB = (n + (1 << shift) - 1) >> shift;    // 196 for n=100000 (<=256)

    // ---- workspace layout ----
    char* base = (char*)d_ws;
    size_t o = 0;
    auto alloc = [&](size_t bytes) { char* p = base + o; o += (bytes + 255) & ~(size_t)255; return p; };
    unsigned short* xp_bf   = (unsigned short*)alloc((size_t)n * 128 * 2);  // dinv*x
    unsigned short* aggx_bf = (unsigned short*)alloc((size_t)n * 128 * 2);
    unsigned short* cat2_bf = (unsigned short*)alloc((size_t)n * 256 * 2);
    unsigned short* rt_bf   = (unsigned short*)alloc((size_t)n * 128 * 2);
    float* dinv = (float*)alloc((size_t)n * 4);
    float* evec = (float*)alloc((size_t)n * 4);
    unsigned short* Wcat_t = (unsigned short*)alloc(256 * 128 * 2);
    unsigned short* Wenc_t = (unsigned short*)alloc(128 * 256 * 2);
    unsigned short* Wp1a_t = (unsigned short*)alloc(128 * 128 * 2);
    unsigned short* Wp1b_t = (unsigned short*)alloc(128 * 128 * 2);
    unsigned short* Wp0a_t = (unsigned short*)alloc(128 * 128 * 2);
    unsigned short* Wp0b_t = (unsigned short*)alloc(128 * 128 * 2);
    unsigned short* Wda_t  = (unsigned short*)alloc(128 * 128 * 2);
    unsigned short* Wdb_t  = (unsigned short*)alloc(128 * 128 * 2);
    int* indptr     = (int*)alloc(((size_t)n + 1) * 4);
    int* indptr_m   = (int*)alloc(((size_t)n + 1) * 4);
    int* bhist      = (int*)alloc(257 * 4);
    int* bhist_m    = (int*)alloc(257 * 4);
    int* bbase      = (int*)alloc(257 * 4);
    int* bbase_m    = (int*)alloc(257 * 4);
    int* bcur       = (int*)alloc(257 * 4);
    int* src_sorted = (int*)alloc((size_t)E * 4);
    int* src_mask   = (int*)alloc((size_t)E * 4);
    int* ebuf       = (int*)alloc((size_t)E * 4);

    const int mt = (n + 63) / 64;

    // ---- CSR build: bucket hist -> partition -> per-bucket LDS counting sort
    k_zero_i32<<<1, 256, 0, stream>>>(bhist, 257);
    k_zero_i32<<<1, 256, 0, stream>>>(bhist_m, 257);
    k_bhist<<<1024, 256, 0, stream>>>(src, dst, t, bhist, bhist_m, E, shift);
    k_scanb<<<1, 256, 0, stream>>>(bhist, bbase, NB);
    k_scanb<<<1, 256, 0, stream>>>(bhist_m, bbase_m, NB);
    k_copy_i32<<<1, 256, 0, stream>>>(bbase, bcur, NB);
    k_fillB<<<(E + 4095) / 4096, 256, 0, stream>>>(src, dst, t, bcur, ebuf, E, shift);
    k_sortC<<<NB, 256, 0, stream>>>(ebuf, bbase, bbase_m, indptr, indptr_m, dinv,
                                    src_sorted, src_mask, n, shift, NB);

    // ---- prep ----
    k_cvt_pre<<<2048, 256, 0, stream>>>(x, dinv, xp_bf, n * 32);
    k_wcat_t<<<128, 256, 0, stream>>>(W_o, W_t, Wcat_t);
    k_wt<<<128, 256, 0, stream>>>(W_enc, Wenc_t, 256, 128);
    k_wt<<<64, 256, 0, stream>>>(p1_W1, Wp1a_t, 128, 128);
    k_wt<<<64, 256, 0, stream>>>(p1_W2, Wp1b_t, 128, 128);
    k_wt<<<64, 256, 0, stream>>>(p0_W1, Wp0a_t, 128, 128);
    k_wt<<<64, 256, 0, stream>>>(p0_W2, Wp0b_t, 128, 128);
    k_wt<<<64, 256, 0, stream>>>(d_W1, Wda_t, 128, 128);
    k_wt<<<64, 256, 0, stream>>>(d_W2, Wdb_t, 128, 128);

    // aggregate prescaled x over full CSR
    k_aggx<<<(n + 3) / 4, 256, 0, stream>>>(xp_bf, indptr, src_sorted, dinv, aggx_bf, n);

    // [r_o|r_t] = relu(aggx @ Wcat + bias); e fused
    k_gcn<<<mt, 256, 0, stream>>>(aggx_bf, Wcat_t, b_o, b_t, a_w, a_b,
                                  cat2_bf, rt_bf, evec, n);

    // attention -> h (masked CSR only)
    k_attn<<<(n + 3) / 4, 256, 0, stream>>>(rt_bf, indptr_m, src_mask, evec, cat2_bf, n);

    // fused: z_enc + 3 heads + select/sigmoid
    k_tail<<<mt, 256, 0, stream>>>(cat2_bf, rt_bf, Wenc_t, b_enc,
                                   Wp1a_t, p1_b1, Wp1b_t, p1_b2, p1_W3, p1_b3,
                                   Wp0a_t, p0_b1, Wp0b_t, p0_b2, p0_W3, p0_b3,
                                   Wda_t, d_b1, Wdb_t, d_b2, d_W3, d_b3,
                                   t, zenc, out, n);
}

// Round 12
// 443.630 us; speedup vs baseline: 3.5062x; 1.0103x over previous
//
#include <hip/hip_runtime.h>
#include <hip/hip_bf16.h>
#include <math.h>

// ---------------------------------------------------------------------------
// SPNet: GCN(2x) -> masked edge attention -> encoder -> 3 MLP heads
// N=100000, E=1600000, F=H=128.
// Round 12:
//   - k_tail v2: LDS 69.6KB -> 52.2KB (3 blocks/CU, was 2; occ 19%).
//     Single weight buffer Wa, W2 double-staged after layer1; hl transpose
//     in separate hb buffer; za extraction via float4 LDS reads.
//   - everything else unchanged from round 11.
// ---------------------------------------------------------------------------

using bf16x8 = __attribute__((ext_vector_type(8))) short;
using s16x8  = __attribute__((ext_vector_type(8))) short;
using f32x4  = __attribute__((ext_vector_type(4))) float;

static __device__ __forceinline__ float lrelu02(float x) { return x > 0.f ? x : 0.2f * x; }

static __device__ __forceinline__ unsigned short f2bf(float f) {
    unsigned u = __float_as_uint(f);
    unsigned r = u + 0x7FFF + ((u >> 16) & 1);   // round-to-nearest-even
    return (unsigned short)(r >> 16);
}
static __device__ __forceinline__ float bf2f(unsigned short h) {
    return __uint_as_float(((unsigned)h) << 16);
}
static __device__ __forceinline__ float bflo(unsigned u) { return __uint_as_float(u << 16); }
static __device__ __forceinline__ float bfhi(unsigned u) { return __uint_as_float(u & 0xFFFF0000u); }

// ---------------- CSR build ----------------

__global__ void k_zero_i32(int* __restrict__ p, int n) {
    int i = blockIdx.x * blockDim.x + threadIdx.x;
    int stride = gridDim.x * blockDim.x;
    for (; i < n; i += stride) p[i] = 0;
}

__global__ void k_copy_i32(const int* __restrict__ a, int* __restrict__ b, int n) {
    int i = blockIdx.x * blockDim.x + threadIdx.x;
    if (i < n) b[i] = a[i];
}

// bucket histograms only (256 bins, LDS-aggregated) — no per-dst atomics
__global__ __launch_bounds__(256) void k_bhist(const int* __restrict__ src,
                                               const int* __restrict__ dst,
                                               const int* __restrict__ t,
                                               int* __restrict__ bhist,
                                               int* __restrict__ bhist_m,
                                               int e, int shift) {
    __shared__ int h[256], hm[256];
    h[threadIdx.x] = 0; hm[threadIdx.x] = 0;
    __syncthreads();
    int i = blockIdx.x * blockDim.x + threadIdx.x;
    int stride = gridDim.x * blockDim.x;
    for (; i < e; i += stride) {
        int b = dst[i] >> shift;
        atomicAdd(&h[b], 1);
        if (t[src[i]] > 0) atomicAdd(&hm[b], 1);
    }
    __syncthreads();
    if (h[threadIdx.x]) atomicAdd(&bhist[threadIdx.x], h[threadIdx.x]);
    if (hm[threadIdx.x]) atomicAdd(&bhist_m[threadIdx.x], hm[threadIdx.x]);
}

// exclusive scan of <=256 values; also writes boff[nb] = total
__global__ __launch_bounds__(256) void k_scanb(const int* __restrict__ bsum,
                                               int* __restrict__ boff, int nb) {
    __shared__ int s[256];
    int t = threadIdx.x;
    int v = (t < nb) ? bsum[t] : 0;
    s[t] = v;
    __syncthreads();
    for (int off = 1; off < 256; off <<= 1) {
        int u = (t >= off) ? s[t - off] : 0;
        __syncthreads();
        s[t] += u;
        __syncthreads();
    }
    if (t < nb) boff[t] = s[t] - v;
    if (t == nb - 1) boff[nb] = s[t];
}

// pass B: partition edges into dst-buckets; payload = src | dlo<<20 | tbit<<29
__global__ __launch_bounds__(256) void k_fillB(const int* __restrict__ src,
                                               const int* __restrict__ dst,
                                               const int* __restrict__ t,
                                               int* __restrict__ bcur,
                                               int* __restrict__ ebuf,
                                               int e, int shift) {
    __shared__ int h[256];
    const int EPT = 16;
    int blk_base = blockIdx.x * 256 * EPT;
    h[threadIdx.x] = 0;
    __syncthreads();
    int pk[EPT], bk[EPT];
#pragma unroll
    for (int j = 0; j < EPT; ++j) {
        int i = blk_base + threadIdx.x + j * 256;
        if (i < e) {
            int s = src[i], d = dst[i];
            int b = d >> shift;
            bk[j] = b;
            int tb = (t[s] > 0) ? 1 : 0;
            pk[j] = s | ((d - (b << shift)) << 20) | (tb << 29);
            atomicAdd(&h[b], 1);
        } else bk[j] = -1;
    }
    __syncthreads();
    int cnt = h[threadIdx.x];
    int base = 0;
    if (cnt > 0) base = atomicAdd(&bcur[threadIdx.x], cnt);
    __syncthreads();
    h[threadIdx.x] = base;
    __syncthreads();
#pragma unroll
    for (int j = 0; j < EPT; ++j) {
        if (bk[j] >= 0) {
            int pos = atomicAdd(&h[bk[j]], 1);
            ebuf[pos] = pk[j];
        }
    }
}

// pass C: one block per bucket. LDS counting sort of the bucket slice.
__global__ __launch_bounds__(256) void k_sortC(const int* __restrict__ ebuf,
                                               const int* __restrict__ bbase,
                                               const int* __restrict__ bbase_m,
                                               int* __restrict__ indptr,
                                               int* __restrict__ indptr_m,
                                               float* __restrict__ dinv,
                                               int* __restrict__ out_all,
                                               int* __restrict__ out_m,
                                               int n, int shift, int NB) {
    __shared__ int cnt[512], cnt_m[512];
    __shared__ int cur[512], cur_m[512];
    __shared__ int tmp[256];
    int tid = threadIdx.x;
    int b = blockIdx.x;
    int lo = bbase[b], hi = bbase[b + 1];
    int lom = bbase_m[b];
    int dbase = b << shift;
    for (int j = tid; j < 512; j += 256) { cnt[j] = 0; cnt_m[j] = 0; }
    __syncthreads();
    for (int i = lo + tid; i < hi; i += 256) {
        int pk = ebuf[i];
        int dlo = (pk >> 20) & 511;
        atomicAdd(&cnt[dlo], 1);
        if (pk >> 29) atomicAdd(&cnt_m[dlo], 1);
    }
    __syncthreads();
    int c0 = cnt[2 * tid], c1 = cnt[2 * tid + 1];
    int ps = c0 + c1;
    tmp[tid] = ps;
    __syncthreads();
    for (int off = 1; off < 256; off <<= 1) {
        int u = (tid >= off) ? tmp[tid - off] : 0;
        __syncthreads();
        tmp[tid] += u;
        __syncthreads();
    }
    int pre = tmp[tid] - ps;
    cur[2 * tid] = pre;
    cur[2 * tid + 1] = pre + c0;
    __syncthreads();
    int m0 = cnt_m[2 * tid], m1 = cnt_m[2 * tid + 1];
    int psm = m0 + m1;
    tmp[tid] = psm;
    __syncthreads();
    for (int off = 1; off < 256; off <<= 1) {
        int u = (tid >= off) ? tmp[tid - off] : 0;
        __syncthreads();
        tmp[tid] += u;
        __syncthreads();
    }
    int prem = tmp[tid] - psm;
    cur_m[2 * tid] = prem;
    cur_m[2 * tid + 1] = prem + m0;
    __syncthreads();
    int nd = n - dbase; if (nd > 512) nd = 512;
    for (int j = tid; j < nd; j += 256) {
        indptr[dbase + j] = lo + cur[j];
        indptr_m[dbase + j] = lom + cur_m[j];
        dinv[dbase + j] = rsqrtf((float)cnt[j] + 1.0f);   // self-loop adds 1
    }
    if (b == 0 && tid == 0) {
        indptr[n] = bbase[NB];
        indptr_m[n] = bbase_m[NB];
    }
    __syncthreads();
    for (int i = lo + tid; i < hi; i += 256) {
        int pk = ebuf[i];
        int s = pk & 0xFFFFF;
        int dlo = (pk >> 20) & 511;
        int pos = lo + atomicAdd(&cur[dlo], 1);
        out_all[pos] = s;
        if (pk >> 29) {
            int pm = lom + atomicAdd(&cur_m[dlo], 1);
            out_m[pm] = s;
        }
    }
}

// ---------------- prep ----------------

__global__ void k_cvt_pre(const float* __restrict__ x, const float* __restrict__ dinv,
                          unsigned short* __restrict__ xp, int total4) {
    int i = blockIdx.x * blockDim.x + threadIdx.x;
    int stride = gridDim.x * blockDim.x;
    for (; i < total4; i += stride) {
        float dv = dinv[i >> 5];
        float4 v = ((const float4*)x)[i];
        ushort4 o;
        o.x = f2bf(v.x * dv); o.y = f2bf(v.y * dv);
        o.z = f2bf(v.z * dv); o.w = f2bf(v.w * dv);
        ((ushort4*)xp)[i] = o;
    }
}

__global__ void k_wt(const float* __restrict__ W, unsigned short* __restrict__ Wt,
                     int K, int Nc) {
    int i = blockIdx.x * blockDim.x + threadIdx.x;
    if (i >= K * Nc) return;
    int k = i / Nc, j = i % Nc;
    Wt[(size_t)j * K + k] = f2bf(W[i]);
}

__global__ void k_wcat_t(const float* __restrict__ Wo, const float* __restrict__ Wt_in,
                         unsigned short* __restrict__ Wt) {
    int i = blockIdx.x * blockDim.x + threadIdx.x;
    if (i >= 256 * 128) return;
    int j = i >> 7, k = i & 127;
    float v = (j < 128) ? Wo[(k << 7) + j] : Wt_in[(k << 7) + j - 128];
    Wt[i] = f2bf(v);
}

// ---------------- graph: aggregate x_pre ----------------
__global__ __launch_bounds__(256) void k_aggx(const unsigned short* __restrict__ xp,
                                              const int* __restrict__ indptr,
                                              const int* __restrict__ srcs,
                                              const float* __restrict__ dinv,
                                              unsigned short* __restrict__ aggx, int n) {
    int wv = threadIdx.x >> 6, lane = threadIdx.x & 63;
    int v = blockIdx.x * 4 + wv;
    if (v >= n) return;
    const unsigned* xp2 = (const unsigned*)xp;
    int beg = indptr[v], end = indptr[v + 1];
    unsigned sv = xp2[(size_t)v * 64 + lane];
    float a0 = bflo(sv), a1 = bfhi(sv);
    int i = beg;
    for (; i + 8 <= end; i += 8) {
        int s0 = srcs[i], s1 = srcs[i + 1], s2 = srcs[i + 2], s3 = srcs[i + 3];
        int s4 = srcs[i + 4], s5 = srcs[i + 5], s6 = srcs[i + 6], s7 = srcs[i + 7];
        unsigned u0 = xp2[(size_t)s0 * 64 + lane];
        unsigned u1 = xp2[(size_t)s1 * 64 + lane];
        unsigned u2 = xp2[(size_t)s2 * 64 + lane];
        unsigned u3 = xp2[(size_t)s3 * 64 + lane];
        unsigned u4 = xp2[(size_t)s4 * 64 + lane];
        unsigned u5 = xp2[(size_t)s5 * 64 + lane];
        unsigned u6 = xp2[(size_t)s6 * 64 + lane];
        unsigned u7 = xp2[(size_t)s7 * 64 + lane];
        a0 += bflo(u0) + bflo(u1) + bflo(u2) + bflo(u3)
            + bflo(u4) + bflo(u5) + bflo(u6) + bflo(u7);
        a1 += bfhi(u0) + bfhi(u1) + bfhi(u2) + bfhi(u3)
            + bfhi(u4) + bfhi(u5) + bfhi(u6) + bfhi(u7);
    }
    for (; i + 4 <= end; i += 4) {
        int s0 = srcs[i], s1 = srcs[i + 1], s2 = srcs[i + 2], s3 = srcs[i + 3];
        unsigned u0 = xp2[(size_t)s0 * 64 + lane];
        unsigned u1 = xp2[(size_t)s1 * 64 + lane];
        unsigned u2 = xp2[(size_t)s2 * 64 + lane];
        unsigned u3 = xp2[(size_t)s3 * 64 + lane];
        a0 += bflo(u0) + bflo(u1) + bflo(u2) + bflo(u3);
        a1 += bfhi(u0) + bfhi(u1) + bfhi(u2) + bfhi(u3);
    }
    for (; i < end; ++i) {
        unsigned u = xp2[(size_t)srcs[i] * 64 + lane];
        a0 += bflo(u); a1 += bfhi(u);
    }
    float dv = dinv[v];
    a0 *= dv; a1 *= dv;
    unsigned o = (unsigned)f2bf(a0) | ((unsigned)f2bf(a1) << 16);
    ((unsigned*)aggx)[(size_t)v * 64 + lane] = o;
}

// ---------------- GCN gemm: [r_o|r_t] = relu(aggx @ Wcat + [b_o|b_t]), e fused
__global__ __launch_bounds__(256) void k_gcn(const unsigned short* __restrict__ aggx,
                                             const unsigned short* __restrict__ Wcat,
                                             const float* __restrict__ b_o,
                                             const float* __restrict__ b_t,
                                             const float* __restrict__ a_w,
                                             const float* __restrict__ a_b,
                                             unsigned short* __restrict__ cat2,
                                             unsigned short* __restrict__ rt,
                                             float* __restrict__ e, int M) {
    __shared__ short ct[64][264];   // 64 rows x 256 cols bf16 (+8 pad)
    int wave = threadIdx.x >> 6, lane = threadIdx.x & 63;
    int row_base = blockIdx.x * 64 + wave * 16;
    int rA = row_base + (lane & 15);
    if (rA >= M) rA = M - 1;
    int koff = (lane >> 4) << 3;
    int colL = lane & 15;

    bf16x8 a[4];
#pragma unroll
    for (int ks = 0; ks < 4; ++ks)
        a[ks] = *(const bf16x8*)((const short*)aggx + (size_t)rA * 128 + (ks << 5) + koff);

    f32x4 acc[16];
#pragma unroll
    for (int cf = 0; cf < 16; ++cf) acc[cf] = (f32x4){0.f, 0.f, 0.f, 0.f};
#pragma unroll
    for (int ks = 0; ks < 4; ++ks)
#pragma unroll
        for (int cf = 0; cf < 16; ++cf) {
            bf16x8 b = *(const bf16x8*)((const short*)Wcat + (size_t)((cf << 4) + colL) * 128 + (ks << 5) + koff);
            acc[cf] = __builtin_amdgcn_mfma_f32_16x16x32_bf16(a[ks], b, acc[cf], 0, 0, 0);
        }

    float ep0 = 0.f, ep1 = 0.f, ep2 = 0.f, ep3 = 0.f;
    int rl0 = wave * 16 + ((lane >> 4) << 2);
#pragma unroll
    for (int cf = 0; cf < 16; ++cf) {
        int col = (cf << 4) + colL;
        float bv = (col < 128) ? b_o[col] : b_t[col - 128];
        float aw = a_w[col];
#pragma unroll
        for (int j = 0; j < 4; ++j) {
            float v = fmaxf(acc[cf][j] + bv, 0.f);
            if (j == 0) ep0 += v * aw;
            else if (j == 1) ep1 += v * aw;
            else if (j == 2) ep2 += v * aw;
            else ep3 += v * aw;
            ct[rl0 + j][col] = (short)f2bf(v);
        }
    }
#pragma unroll
    for (int mk = 1; mk < 16; mk <<= 1) {
        ep0 += __shfl_xor(ep0, mk); ep1 += __shfl_xor(ep1, mk);
        ep2 += __shfl_xor(ep2, mk); ep3 += __shfl_xor(ep3, mk);
    }
    if (colL == 0) {
        float ab = a_b[0];
        int r0 = row_base + ((lane >> 4) << 2);
        if (r0 + 0 < M) e[r0 + 0] = ep0 + ab;
        if (r0 + 1 < M) e[r0 + 1] = ep1 + ab;
        if (r0 + 2 < M) e[r0 + 2] = ep2 + ab;
        if (r0 + 3 < M) e[r0 + 3] = ep3 + ab;
    }
    __syncthreads();
    // row-linear readout: cat2 half (256B contiguous per row), rt half
    int base64 = blockIdx.x * 64;
    short* cp = (short*)cat2 + (size_t)base64 * 256;
    for (int j = threadIdx.x; j < 1024; j += 256) {   // 64 rows x 16 short8
        int row = j >> 4;
        if (base64 + row < M)
            *(s16x8*)(cp + (size_t)row * 256 + ((j & 15) << 3)) =
                *(const s16x8*)&ct[row][(j & 15) << 3];
    }
    short* rp = (short*)rt + (size_t)base64 * 128;
    for (int j = threadIdx.x; j < 1024; j += 256) {
        int row = j >> 4;
        if (base64 + row < M)
            *(s16x8*)(rp + (size_t)row * 128 + ((j & 15) << 3)) =
                *(const s16x8*)&ct[row][128 + ((j & 15) << 3)];
    }
}

// ---------------- masked attention (masked CSR only) ----------------
__global__ __launch_bounds__(256) void k_attn(const unsigned short* __restrict__ rt,
                                              const int* __restrict__ indptr_m,
                                              const int* __restrict__ srcs_m,
                                              const float* __restrict__ e,
                                              unsigned short* __restrict__ cat2, int n) {
    int wv = threadIdx.x >> 6, lane = threadIdx.x & 63;
    int v = blockIdx.x * 4 + wv;
    if (v >= n) return;
    float ev = e[v];
    int bm = indptr_m[v], em = indptr_m[v + 1];
    float m = -INFINITY;
    for (int i = bm + lane; i < em; i += 64)
        m = fmaxf(m, lrelu02(ev + e[srcs_m[i]]));
    for (int off = 32; off; off >>= 1) m = fmaxf(m, __shfl_xor(m, off));
    if (bm == em) m = 0.f;
    float h0 = 0.f, h1 = 0.f, wsum = 0.f;
    const unsigned* rt2 = (const unsigned*)rt;
    int i = bm;
    for (; i + 8 <= em; i += 8) {
        int s0 = srcs_m[i], s1 = srcs_m[i + 1], s2 = srcs_m[i + 2], s3 = srcs_m[i + 3];
        int s4 = srcs_m[i + 4], s5 = srcs_m[i + 5], s6 = srcs_m[i + 6], s7 = srcs_m[i + 7];
        float w0 = __expf(lrelu02(ev + e[s0]) - m);
        float w1 = __expf(lrelu02(ev + e[s1]) - m);
        float w2 = __expf(lrelu02(ev + e[s2]) - m);
        float w3 = __expf(lrelu02(ev + e[s3]) - m);
        float w4 = __expf(lrelu02(ev + e[s4]) - m);
        float w5 = __expf(lrelu02(ev + e[s5]) - m);
        float w6 = __expf(lrelu02(ev + e[s6]) - m);
        float w7 = __expf(lrelu02(ev + e[s7]) - m);
        unsigned u0 = rt2[(size_t)s0 * 64 + lane];
        unsigned u1 = rt2[(size_t)s1 * 64 + lane];
        unsigned u2 = rt2[(size_t)s2 * 64 + lane];
        unsigned u3 = rt2[(size_t)s3 * 64 + lane];
        unsigned u4 = rt2[(size_t)s4 * 64 + lane];
        unsigned u5 = rt2[(size_t)s5 * 64 + lane];
        unsigned u6 = rt2[(size_t)s6 * 64 + lane];
        unsigned u7 = rt2[(size_t)s7 * 64 + lane];
        wsum += w0 + w1 + w2 + w3 + w4 + w5 + w6 + w7;
        h0 += w0 * bflo(u0) + w1 * bflo(u1) + w2 * bflo(u2) + w3 * bflo(u3)
            + w4 * bflo(u4) + w5 * bflo(u5) + w6 * bflo(u6) + w7 * bflo(u7);
        h1 += w0 * bfhi(u0) + w1 * bfhi(u1) + w2 * bfhi(u2) + w3 * bfhi(u3)
            + w4 * bfhi(u4) + w5 * bfhi(u5) + w6 * bfhi(u6) + w7 * bfhi(u7);
    }
    for (; i < em; ++i) {
        int s = srcs_m[i];
        float w = __expf(lrelu02(ev + e[s]) - m);
        unsigned u = rt2[(size_t)s * 64 + lane];
        wsum += w;
        h0 += w * bflo(u);
        h1 += w * bfhi(u);
    }
    float inv = 1.f / (wsum + 1e-16f);
    unsigned o = (unsigned)f2bf(h0 * inv) | ((unsigned)f2bf(h1 * inv) << 16);
    ((unsigned*)(cat2 + (size_t)v * 256 + 128))[lane] = o;
}

// ---------------- fused tail: z_enc GEMM + 3 MLP heads + select/sigmoid ----
// LDS budget 52224 B -> 3 blocks/CU: Wa [128][136] shorts (34816 B, single
// weight buffer, W2 double-staged), hb [64][136] shorts (17408 B, layer1->2
// transpose). zt [64][132] fp32 (33792 B) overlays Wa.
__global__ __launch_bounds__(256) void k_tail(
    const unsigned short* __restrict__ cat2, const unsigned short* __restrict__ rt_bf,
    const unsigned short* __restrict__ Wenc, const float* __restrict__ b_enc,
    const unsigned short* __restrict__ W11, const float* __restrict__ b11,
    const unsigned short* __restrict__ W12, const float* __restrict__ b12,
    const float* __restrict__ W13, const float* __restrict__ b13,
    const unsigned short* __restrict__ W01, const float* __restrict__ b01,
    const unsigned short* __restrict__ W02, const float* __restrict__ b02,
    const float* __restrict__ W03, const float* __restrict__ b03,
    const unsigned short* __restrict__ Wd1, const float* __restrict__ bd1,
    const unsigned short* __restrict__ Wd2, const float* __restrict__ bd2,
    const float* __restrict__ Wd3, const float* __restrict__ bd3,
    const int* __restrict__ t, float* __restrict__ zenc,
    float* __restrict__ out, int M) {
    __shared__ __align__(16) char pool[128 * 136 * 2 + 64 * 136 * 2];   // 52224 B
    short* Wa = (short*)pool;                       // 34816 B (weights / zt overlay)
    short* hb = (short*)(pool + 128 * 136 * 2);     // 17408 B (hl transpose)
    float* zt = (float*)pool;                       // [64][132] fp32 = 33792 B

    int wave = threadIdx.x >> 6, lane = threadIdx.x & 63;
    int row_base = blockIdx.x * 64 + wave * 16;
    int rA = row_base + (lane & 15);
    if (rA >= M) rA = M - 1;
    int koff = (lane >> 4) << 3;
    int colL = lane & 15;
    int base64 = blockIdx.x * 64;

    // ra frags (discriminator input) — load early, hides under phase 1
    bf16x8 ra[4];
#pragma unroll
    for (int ks = 0; ks < 4; ++ks)
        ra[ks] = *(const bf16x8*)((const short*)rt_bf + (size_t)rA * 128 + (ks << 5) + koff);

    // ---- phase 1: z_enc (K=256, Ncols=128), B-frags from L2 ----
    {
        const short* Ap = (const short*)cat2 + (size_t)rA * 256 + koff;
        const short* Bp = (const short*)Wenc + (size_t)colL * 256 + koff;
        f32x4 acc[8];
#pragma unroll
        for (int cf = 0; cf < 8; ++cf) acc[cf] = (f32x4){0.f, 0.f, 0.f, 0.f};
#pragma unroll
        for (int ks = 0; ks < 8; ++ks) {
            bf16x8 a = *(const bf16x8*)(Ap + (ks << 5));
#pragma unroll
            for (int cf = 0; cf < 8; ++cf) {
                bf16x8 b = *(const bf16x8*)(Bp + (size_t)(cf << 4) * 256 + (ks << 5));
                acc[cf] = __builtin_amdgcn_mfma_f32_16x16x32_bf16(a, b, acc[cf], 0, 0, 0);
            }
        }
        int rl0 = wave * 16 + ((lane >> 4) << 2);
#pragma unroll
        for (int cf = 0; cf < 8; ++cf) {
            int col = (cf << 4) + colL;
            float bv = b_enc[col];
#pragma unroll
            for (int j = 0; j < 4; ++j)
                zt[(rl0 + j) * 132 + col] = acc[cf][j] + bv;
        }
    }
    __syncthreads();
    // linear fp32 writeout: block's 64x128 region is contiguous
    {
        float* zp = zenc + (size_t)base64 * 128;
        for (int j = threadIdx.x; j < 2048; j += 256) {
            int row = j >> 5;
            if (base64 + row < M)
                *(float4*)(zp + (size_t)j * 4) = *(const float4*)&zt[row * 132 + ((j & 31) << 2)];
        }
    }
    // za frags from LDS, vectorized (bit-identical to f2bf(acc+bias))
    bf16x8 za[4];
    {
        int rAl = wave * 16 + (lane & 15);
#pragma unroll
        for (int ks = 0; ks < 4; ++ks) {
            float4 v0 = *(const float4*)&zt[rAl * 132 + (ks << 5) + koff];
            float4 v1 = *(const float4*)&zt[rAl * 132 + (ks << 5) + koff + 4];
            za[ks][0] = (short)f2bf(v0.x); za[ks][1] = (short)f2bf(v0.y);
            za[ks][2] = (short)f2bf(v0.z); za[ks][3] = (short)f2bf(v0.w);
            za[ks][4] = (short)f2bf(v1.x); za[ks][5] = (short)f2bf(v1.y);
            za[ks][6] = (short)f2bf(v1.z); za[ks][7] = (short)f2bf(v1.w);
        }
    }

    float sp1[4], sp0[4], sdd[4];

    auto stage = [&](const unsigned short* W) {
        for (int i = threadIdx.x; i < 2048; i += 256) {
            int r = i >> 4, c = (i & 15) << 3;
            bf16x8 v = *(const bf16x8*)((const short*)W + (r << 7) + c);
            *(bf16x8*)(Wa + r * 136 + c) = v;
        }
    };

    auto run_head = [&](const bf16x8* A0,
                        const unsigned short* W1, const float* b1,
                        const unsigned short* W2, const float* b2,
                        const float* W3, const float* b3, float* sout) {
        __syncthreads();   // zt reads done (1st call) / Wa+hb reads done (later)
        stage(W1);
        __syncthreads();
        f32x4 acc[8];
#pragma unroll
        for (int cf = 0; cf < 8; ++cf) acc[cf] = (f32x4){0.f, 0.f, 0.f, 0.f};
#pragma unroll
        for (int ks = 0; ks < 4; ++ks)
#pragma unroll
            for (int cf = 0; cf < 8; ++cf) {
                bf16x8 b = *(const bf16x8*)(Wa + ((cf << 4) + colL) * 136 + (ks << 5) + koff);
                acc[cf] = __builtin_amdgcn_mfma_f32_16x16x32_bf16(A0[ks], b, acc[cf], 0, 0, 0);
            }
        // hl -> hb (per-wave 16 rows)
        short* hw = hb + wave * 2176;
#pragma unroll
        for (int cf = 0; cf < 8; ++cf) {
            int col = (cf << 4) + colL;
            float bv = b1[col];
#pragma unroll
            for (int j = 0; j < 4; ++j)
                hw[(((lane >> 4) << 2) + j) * 136 + col] = (short)f2bf(lrelu02(acc[cf][j] + bv));
        }
        __syncthreads();   // all MFMA1 reads of Wa done; hb written
        stage(W2);
        __syncthreads();
        bf16x8 h1f[4];
#pragma unroll
        for (int ks = 0; ks < 4; ++ks)
            h1f[ks] = *(const bf16x8*)(hw + colL * 136 + (ks << 5) + koff);
#pragma unroll
        for (int cf = 0; cf < 8; ++cf) acc[cf] = (f32x4){0.f, 0.f, 0.f, 0.f};
#pragma unroll
        for (int ks = 0; ks < 4; ++ks)
#pragma unroll
            for (int cf = 0; cf < 8; ++cf) {
                bf16x8 b = *(const bf16x8*)(Wa + ((cf << 4) + colL) * 136 + (ks << 5) + koff);
                acc[cf] = __builtin_amdgcn_mfma_f32_16x16x32_bf16(h1f[ks], b, acc[cf], 0, 0, 0);
            }
        float s0 = 0.f, s1 = 0.f, s2 = 0.f, s3 = 0.f;
#pragma unroll
        for (int cf = 0; cf < 8; ++cf) {
            int col = (cf << 4) + colL;
            float w3 = W3[col], bv = b2[col];
            s0 += lrelu02(acc[cf][0] + bv) * w3;
            s1 += lrelu02(acc[cf][1] + bv) * w3;
            s2 += lrelu02(acc[cf][2] + bv) * w3;
            s3 += lrelu02(acc[cf][3] + bv) * w3;
        }
#pragma unroll
        for (int mk = 1; mk < 16; mk <<= 1) {
            s0 += __shfl_xor(s0, mk); s1 += __shfl_xor(s1, mk);
            s2 += __shfl_xor(s2, mk); s3 += __shfl_xor(s3, mk);
        }
        float bb = b3[0];
        sout[0] = s0 + bb; sout[1] = s1 + bb; sout[2] = s2 + bb; sout[3] = s3 + bb;
    };

    run_head(za, W11, b11, W12, b12, W13, b13, sp1);
    run_head(za, W01, b01, W02, b02, W03, b03, sp0);
    run_head(ra, Wd1, bd1, Wd2, bd2, Wd3, bd3, sdd);

    if (colL == 0) {
#pragma unroll
        for (int j = 0; j < 4; ++j) {
            int row = row_base + ((lane >> 4) << 2) + j;
            if (row < M) {
                out[row] = 1.f / (1.f + __expf(-sdd[j]));           // pred_t
                out[M + row] = (t[row] > 0) ? sp1[j] : sp0[j];      // pred
            }
        }
    }
}

// ---------------- launcher ----------------

extern "C" void kernel_launch(void* const* d_in, const int* in_sizes, int n_in,
                              void* d_out, int out_size, void* d_ws, size_t ws_size,
                              hipStream_t stream) {
    const float* x     = (const float*)d_in[0];
    const int*   t     = (const int*)d_in[1];
    const int*   ei    = (const int*)d_in[3];
    const float* W_o   = (const float*)d_in[4];
    const float* b_o   = (const float*)d_in[5];
    const float* W_t   = (const float*)d_in[6];
    const float* b_t   = (const float*)d_in[7];
    const float* a_w   = (const float*)d_in[8];
    const float* a_b   = (const float*)d_in[9];
    const float* W_enc = (const float*)d_in[10];
    const float* b_enc = (const float*)d_in[11];
    const float* p1_W1 = (const float*)d_in[12]; const float* p1_b1 = (const float*)d_in[13];
    const float* p1_W2 = (const float*)d_in[14]; const float* p1_b2 = (const float*)d_in[15];
    const float* p1_W3 = (const float*)d_in[16]; const float* p1_b3 = (const float*)d_in[17];
    const float* p0_W1 = (const float*)d_in[18]; const float* p0_b1 = (const float*)d_in[19];
    const float* p0_W2 = (const float*)d_in[20]; const float* p0_b2 = (const float*)d_in[21];
    const float* p0_W3 = (const float*)d_in[22]; const float* p0_b3 = (const float*)d_in[23];
    const float* d_W1  = (const float*)d_in[24]; const float* d_b1  = (const float*)d_in[25];
    const float* d_W2  = (const float*)d_in[26]; const float* d_b2  = (const float*)d_in[27];
    const float* d_W3  = (const float*)d_in[28]; const float* d_b3  = (const float*)d_in[29];

    const int n = in_sizes[1];
    const int E = in_sizes[3] / 2;
    const int* src = ei;
    const int* dst = ei + E;

    float* out  = (float*)d_out;
    float* zenc = out + 2 * (size_t)n;   // output: pred_t[N], pred[N], z_enc[N,128]

    const int shift = 9;                               // 512 dst ids per bucket
    const int NB = (n + (1 << shift) - 1) >> shift;    // 196 for n=100000 (<=256)

    // ---- workspace layout ----
    char* base = (char*)d_ws;
    size_t o = 0;
    auto alloc = [&](size_t bytes) { char* p = base + o; o += (bytes + 255) & ~(size_t)255; return p; };
    unsigned short* xp_bf   = (unsigned short*)alloc((size_t)n * 128 * 2);  // dinv*x
    unsigned short* aggx_bf = (unsigned short*)alloc((size_t)n * 128 * 2);
    unsigned short* cat2_bf = (unsigned short*)alloc((size_t)n * 256 * 2);
    unsigned short* rt_bf   = (unsigned short*)alloc((size_t)n * 128 * 2);
    float* dinv = (float*)alloc((size_t)n * 4);
    float* evec = (float*)alloc((size_t)n * 4);
    unsigned short* Wcat_t = (unsigned short*)alloc(256 * 128 * 2);
    unsigned short* Wenc_t = (unsigned short*)alloc(128 * 256 * 2);
    unsigned short* Wp1a_t = (unsigned short*)alloc(128 * 128 * 2);
    unsigned short* Wp1b_t = (unsigned short*)alloc(128 * 128 * 2);
    unsigned short* Wp0a_t = (unsigned short*)alloc(128 * 128 * 2);
    unsigned short* Wp0b_t = (unsigned short*)alloc(128 * 128 * 2);
    unsigned short* Wda_t  = (unsigned short*)alloc(128 * 128 * 2);
    unsigned short* Wdb_t  = (unsigned short*)alloc(128 * 128 * 2);
    int* indptr     = (int*)alloc(((size_t)n + 1) * 4);
    int* indptr_m   = (int*)alloc(((size_t)n + 1) * 4);
    int* bhist      = (int*)alloc(257 * 4);
    int* bhist_m    = (int*)alloc(257 * 4);
    int* bbase      = (int*)alloc(257 * 4);
    int* bbase_m    = (int*)alloc(257 * 4);
    int* bcur       = (int*)alloc(257 * 4);
    int* src_sorted = (int*)alloc((size_t)E * 4);
    int* src_mask   = (int*)alloc((size_t)E * 4);
    int* ebuf       = (int*)alloc((size_t)E * 4);

    const int mt = (n + 63) / 64;

    // ---- CSR build: bucket hist -> partition -> per-bucket LDS counting sort
    k_zero_i32<<<1, 256, 0, stream>>>(bhist, 257);
    k_zero_i32<<<1, 256, 0, stream>>>(bhist_m, 257);
    k_bhist<<<1024, 256, 0, stream>>>(src, dst, t, bhist, bhist_m, E, shift);
    k_scanb<<<1, 256, 0, stream>>>(bhist, bbase, NB);
    k_scanb<<<1, 256, 0, stream>>>(bhist_m, bbase_m, NB);
    k_copy_i32<<<1, 256, 0, stream>>>(bbase, bcur, NB);
    k_fillB<<<(E + 4095) / 4096, 256, 0, stream>>>(src, dst, t, bcur, ebuf, E, shift);
    k_sortC<<<NB, 256, 0, stream>>>(ebuf, bbase, bbase_m, indptr, indptr_m, dinv,
                                    src_sorted, src_mask, n, shift, NB);

    // ---- prep ----
    k_cvt_pre<<<2048, 256, 0, stream>>>(x, dinv, xp_bf, n * 32);
    k_wcat_t<<<128, 256, 0, stream>>>(W_o, W_t, Wcat_t);
    k_wt<<<128, 256, 0, stream>>>(W_enc, Wenc_t, 256, 128);
    k_wt<<<64, 256, 0, stream>>>(p1_W1, Wp1a_t, 128, 128);
    k_wt<<<64, 256, 0, stream>>>(p1_W2, Wp1b_t, 128, 128);
    k_wt<<<64, 256, 0, stream>>>(p0_W1, Wp0a_t, 128, 128);
    k_wt<<<64, 256, 0, stream>>>(p0_W2, Wp0b_t, 128, 128);
    k_wt<<<64, 256, 0, stream>>>(d_W1, Wda_t, 128, 128);
    k_wt<<<64, 256, 0, stream>>>(d_W2, Wdb_t, 128, 128);

    // aggregate prescaled x over full CSR
    k_aggx<<<(n + 3) / 4, 256, 0, stream>>>(xp_bf, indptr, src_sorted, dinv, aggx_bf, n);

    // [r_o|r_t] = relu(aggx @ Wcat + bias); e fused
    k_gcn<<<mt, 256, 0, stream>>>(aggx_bf, Wcat_t, b_o, b_t, a_w, a_b,
                                  cat2_bf, rt_bf, evec, n);

    // attention -> h (masked CSR only)
    k_attn<<<(n + 3) / 4, 256, 0, stream>>>(rt_bf, indptr_m, src_mask, evec, cat2_bf, n);

    // fused: z_enc + 3 heads + select/sigmoid
    k_tail<<<mt, 256, 0, stream>>>(cat2_bf, rt_bf, Wenc_t, b_enc,
                                   Wp1a_t, p1_b1, Wp1b_t, p1_b2, p1_W3, p1_b3,
                                   Wp0a_t, p0_b1, Wp0b_t, p0_b2, p0_W3, p0_b3,
                                   Wda_t, d_b1, Wdb_t, d_b2, d_W3, d_b3,
                                   t, zenc, out, n);
}